// Round 12
// baseline (1648.745 us; speedup 1.0000x reference)
//
#include <hip/hip_runtime.h>
#include <math.h>

#define NPROTO 8
#define KV_NCH 4
#define MSG_NCH 8
#define CAP 24576L            // compact rows per side (Mv ~= 19200 +- ~200)

typedef __attribute__((ext_vector_type(8))) short short8;
typedef __attribute__((ext_vector_type(4))) float floatx4;

static __device__ __forceinline__ ushort f2b(float f) {
    unsigned u = __builtin_bit_cast(unsigned, f);
    unsigned r = (u + 0x7fffu + ((u >> 16) & 1u)) >> 16;
    return (ushort)r;
}

static __device__ __forceinline__ float b2f(ushort u) {
    return __builtin_bit_cast(float, (unsigned)u << 16);
}

static __device__ __forceinline__ float elu1(float v) {
    return v > 0.f ? v + 1.f : __expf(v);
}

// async 16B global -> LDS (linear dest: wave base + lane*16B)
#define GLOAD16(gp, lp) __builtin_amdgcn_global_load_lds( \
    (const __attribute__((address_space(1))) void*)(gp),  \
    (__attribute__((address_space(3))) void*)(lp), 16, 0, 0)

// drain staging loads + retire LDS ops, then barrier (memory-fenced)
#define WAIT_BAR() asm volatile("s_waitcnt vmcnt(0) lgkmcnt(0)\n\ts_barrier" ::: "memory")

// swizzle of the 16B-group index within a 32-col bf16 row (4 groups/row)
static __device__ __forceinline__ int swz(int r) { return (r >> 1) & 3; }

// ---------------- prototype projection / argmax-class kernel ----------------
__global__ __launch_bounds__(256) void lft_class_kernel(
    const float* __restrict__ f0wo, const float* __restrict__ f1wo,
    const int* __restrict__ mask0, const int* __restrict__ mask1,
    const float* __restrict__ proto,
    float* out, int* cls0, int* cls1)
{
    __shared__ float pr[2048];          // proto [8][256]
    __shared__ float tile[128][68];     // [token][ch chunk], stride 68
    __shared__ float sm[128][8];
    int t = threadIdx.x;
    *(float4*)&pr[t * 4]        = *(const float4*)&proto[t * 4];
    *(float4*)&pr[1024 + t * 4] = *(const float4*)&proto[1024 + t * 4];
    long tok0 = (long)blockIdx.x * 128;
    const float* fsrc; const int* msrc; float* fpout; float* clsout; int* clsarr; long tbase;
    if (tok0 < 38400) {
        tbase = tok0; fsrc = f0wo; msrc = mask0;
        fpout = out + 19737600L; clsout = out + 19660800L; clsarr = cls0;
    } else {
        tbase = tok0 - 38400; fsrc = f1wo; msrc = mask1;
        fpout = out + 20044800L; clsout = out + 19699200L; clsarr = cls1;
    }
    int tok = t & 127, half = t >> 7;
    float s[4] = {};
    int r0 = t >> 4;            // 0..15
    int c4 = (t & 15) << 2;     // 0..60
    for (int ct = 0; ct < 4; ct++) {
        __syncthreads();
#pragma unroll
        for (int rr = 0; rr < 8; rr++) {
            int row = rr * 16 + r0;
            float4 v = *(const float4*)&fsrc[(tbase + row) * 256 + ct * 64 + c4];
            *(float4*)&tile[row][c4] = v;
        }
        __syncthreads();
#pragma unroll
        for (int cc = 0; cc < 16; cc++) {
            float4 f = *(const float4*)&tile[tok][cc << 2];
#pragma unroll
            for (int p = 0; p < 4; p++) {
                float4 pv = *(const float4*)&pr[(half * 4 + p) * 256 + ct * 64 + (cc << 2)];
                s[p] += f.x * pv.x + f.y * pv.y + f.z * pv.z + f.w * pv.w;
            }
        }
    }
#pragma unroll
    for (int p = 0; p < 4; p++) {
        fpout[(tbase + tok) * 8 + half * 4 + p] = s[p];
        sm[tok][half * 4 + p] = s[p];
    }
    __syncthreads();
    if (t < 128) {
        int best = 0; float bv = sm[t][0];
#pragma unroll
        for (int p = 1; p < 8; p++) { if (sm[t][p] > bv) { bv = sm[t][p]; best = p; } }
        clsout[tbase + t] = (float)best;
        clsarr[tbase + t] = msrc[tbase + t] ? best : -1;
    }
}

// ---------------- copy ONLY invalid-token rows of feat into out --------------
__global__ __launch_bounds__(256) void lft_invcopy_kernel(
    const float* __restrict__ f0, const float* __restrict__ f1,
    const int* __restrict__ cls0, const int* __restrict__ cls1,
    float* out)
{
    int w = blockIdx.x * 4 + (threadIdx.x >> 6);   // 0..4799
    int lane = threadIdx.x & 63;
    for (long row = w; row < 76800; row += 4800) {
        int side = row >= 38400;
        long r = row - (long)side * 38400;
        int c = side ? cls1[r] : cls0[r];
        if (c < 0) {
            const float* src = side ? f1 : f0;
            float4 v = *(const float4*)&src[r * 256 + lane * 4];
            *(float4*)&out[(long)side * 9830400L + r * 256 + lane * 4] = v;
        }
    }
}

// ---------------- per-(L,b) class counts -> meta {base,cnt} ------------------
__global__ __launch_bounds__(256) void lft_count_kernel(
    const int* __restrict__ cls0, const int* __restrict__ cls1, int* meta)
{
    int g = blockIdx.x; int L = g >> 3, b = g & 7;
    const int* cls = (L ? cls1 : cls0) + b * 4800;
    int* mt = meta + (L * 8 + b) * 16;
    __shared__ int cnt[8];
    int t = threadIdx.x;
    if (t < 8) cnt[t] = 0;
    __syncthreads();
    for (int tok = t; tok < 4800; tok += 256) {
        int c = cls[tok];
        if (c >= 0) atomicAdd(&cnt[c], 1);
    }
    __syncthreads();
    if (t == 0) {
        int s = 0;
        for (int c = 0; c < 8; c++) { mt[c * 2] = s; mt[c * 2 + 1] = cnt[c]; s += cnt[c]; }
    }
}

// ---------------- cross-batch scan: minfo (Mv, boff) + compact cmeta ---------
__global__ __launch_bounds__(256) void lft_scan_kernel(
    const int* __restrict__ meta, int* minfo, int* cmeta)
{
    int t = threadIdx.x;
    __shared__ int nb[16];
    if (t < 16) {
        int s = 0;
        for (int c = 0; c < 8; c++) s += meta[t * 16 + c * 2 + 1];
        nb[t] = s;
    }
    __syncthreads();
    if (t == 0) {
        int off = 0;
        for (int b = 0; b < 8; b++) { minfo[4 + b] = off; off += nb[b]; }
        minfo[2] = off; minfo[0] = (off + 127) & ~127;
        off = 0;
        for (int b = 0; b < 8; b++) { minfo[12 + b] = off; off += nb[8 + b]; }
        minfo[3] = off; minfo[1] = (off + 127) & ~127;
    }
    __syncthreads();
    if (t < 128) {
        int L = t >> 6, b = (t >> 3) & 7, c = t & 7;
        cmeta[t * 2]     = minfo[4 + L * 8 + b] + meta[(L * 8 + b) * 16 + c * 2];
        cmeta[t * 2 + 1] = meta[(L * 8 + b) * 16 + c * 2 + 1];
    }
}

// ---------------- place valid tokens into compact gather lists ---------------
__global__ __launch_bounds__(256) void lft_place_kernel(
    const int* __restrict__ cls0, const int* __restrict__ cls1,
    const int* __restrict__ cmeta, int* gl)
{
    int g = blockIdx.x; int L = g >> 3, b = g & 7;
    const int* cls = (L ? cls1 : cls0) + b * 4800;
    int* glp = gl + L * CAP;
    __shared__ int pos[8];
    int t = threadIdx.x;
    if (t < 8) pos[t] = cmeta[(L * 64 + b * 8 + t) * 2];
    __syncthreads();
    for (int tok = t; tok < 4800; tok += 256) {
        int c = cls[tok];
        if (c >= 0) { int p = atomicAdd(&pos[c], 1); glp[p] = b * 4800 + tok; }
    }
}

// ---------------- gather-cast: compact bf16 x + compact fp32 resid -----------
__global__ __launch_bounds__(256) void lft_gcast_kernel(
    const float* __restrict__ f0, const float* __restrict__ f1,
    const int* __restrict__ gl, const int* __restrict__ minfo,
    ushort* xc, float* rc)
{
    int blk = blockIdx.x;
    int side = blk >= 600 ? 1 : 0;
    int i0 = (blk - side * 600) * 4 + (threadIdx.x >> 6);
    int mv = minfo[2 + side];
    const int* glp = gl + side * CAP;
    const float* f = side ? f1 : f0;
    ushort* xcp = xc + side * CAP * 256;
    float* rcp = rc + side * CAP * 256;
    int lane = threadIdx.x & 63;
    for (int i = i0; i < mv; i += 2400) {
        long src = (long)glp[i] * 256 + lane * 4;
        float4 v = *(const float4*)&f[src];
        long dst = (long)i * 256 + lane * 4;
        *(float4*)&rcp[dst] = v;
        ushort4 u; u.x = f2b(v.x); u.y = f2b(v.y); u.z = f2b(v.z); u.w = f2b(v.w);
        *(ushort4*)&xcp[dst] = u;
    }
}

// ---------------- weight convert + transpose: Wt[n*K+k] = bf16(W[k*N+n]) ----
__global__ __launch_bounds__(256) void lft_wconv_kernel(
    const float* W0, const float* W1p, const float* W2p, const float* W3p,
    int K, int N, int nTypes, ushort* dst)
{
    int z = blockIdx.z;
    int li = z / nTypes, mi = z % nTypes;
    const float* srcs[4] = {W0, W1p, W2p, W3p};
    const float* src = srcs[mi] + (size_t)li * K * N;
    ushort* outp = dst + (size_t)z * K * N;
    __shared__ float tile[32][33];
    int k0 = blockIdx.x * 32, n0 = blockIdx.y * 32;
    int t = threadIdx.x;
    int r = t >> 3, c4 = (t & 7) << 2;
    float4 v = *(const float4*)&src[(size_t)(k0 + r) * N + n0 + c4];
    tile[r][c4] = v.x; tile[r][c4 + 1] = v.y; tile[r][c4 + 2] = v.z; tile[r][c4 + 3] = v.w;
    __syncthreads();
    ushort4 o;
    o.x = f2b(tile[c4 + 0][r]);
    o.y = f2b(tile[c4 + 1][r]);
    o.z = f2b(tile[c4 + 2][r]);
    o.w = f2b(tile[c4 + 3][r]);
    *(ushort4*)&outp[(size_t)(n0 + r) * K + k0 + c4] = o;
}

// ---------------- bf16 MFMA GEMM over COMPACT rows, side = blockIdx.z --------
// A-fragments loaded DIRECTLY global->registers (row-major A == MFMA A layout:
// 16B at A[row][quad*8]); only B (n-major transpose) staged via global_load_lds
// into 2-buffer swizzled LDS (16KB -> ~6 blocks/CU). Full drain per K-step.
// act: 0 none, 1 elu+1, 2 relu; act 3 qkv N=768 (q/k/v bf16);
// act 4 kv N=512 (k/v bf16). k,v buffers are ushort (passed via Cf/Cv).
__global__ __launch_bounds__(256) void lft_mfma_gemm(
    const ushort* __restrict__ A0b, const ushort* __restrict__ A1b, int kSplit,
    const ushort* __restrict__ Wt,
    float* Cf, ushort* Cb, float* Cv, int N, int K, int act,
    const int* __restrict__ minfo, int side0)
{
    __shared__ ushort Bs[2][128 * 32];
    int side = side0 + blockIdx.z;
    int m0 = blockIdx.y << 7;
    if (m0 >= minfo[side]) return;
    const ushort* A0 = A0b + (long)side * CAP * kSplit;
    const ushort* A1 = A1b + (long)side * CAP * (K - kSplit);
    long so256 = (long)side * CAP * 256;
    long soN = (long)side * CAP * N;
    int t = threadIdx.x;
    int n0 = blockIdx.x << 7;
    int wv = t >> 6, lane = t & 63;
    int wm = wv >> 1, wn = wv & 1;
    int l16 = lane & 15, quad = lane >> 4;
    floatx4 acc[4][4] = {};

    int lrow = lane >> 2;
    int lcg = lane & 3;

    auto stageB = [&](int buf, int k0) {
        ushort* Bb = &Bs[buf][0];
#pragma unroll
        for (int s = 0; s < 2; s++) {
            int r = s * 64 + wv * 16 + lrow;
            int cg = (lcg ^ swz(r)) << 3;
            GLOAD16(&Wt[(size_t)(n0 + r) * K + k0 + cg], &Bb[(s * 64 + wv * 16) * 32]);
        }
    };

    auto compute = [&](int buf, int k0) {
        const ushort* Asrc; int kcol, ldA;
        if (k0 < kSplit) { Asrc = A0; kcol = k0;          ldA = kSplit; }
        else             { Asrc = A1; kcol = k0 - kSplit; ldA = K - kSplit; }
        const ushort* Bb = &Bs[buf][0];
        short8 af[4], bfr[4];
#pragma unroll
        for (int i = 0; i < 4; i++) {
            int rA = m0 + wm * 64 + i * 16 + l16;
            af[i]  = *(const short8*)&Asrc[(size_t)rA * ldA + kcol + quad * 8];
            int rB = wn * 64 + i * 16 + l16;
            bfr[i] = *(const short8*)&Bb[rB * 32 + ((quad ^ swz(rB)) << 3)];
        }
        __builtin_amdgcn_s_setprio(1);
#pragma unroll
        for (int i = 0; i < 4; i++)
#pragma unroll
            for (int j = 0; j < 4; j++)
                acc[i][j] = __builtin_amdgcn_mfma_f32_16x16x32_bf16(af[i], bfr[j], acc[i][j], 0, 0, 0);
        __builtin_amdgcn_s_setprio(0);
    };

    int nt = K >> 5;
    stageB(0, 0);
    WAIT_BAR();
    int cur = 0;
    for (int tt = 0; tt < nt; ++tt) {
        if (tt + 1 < nt) stageB(cur ^ 1, (tt + 1) << 5);
        compute(cur, tt << 5);
        if (tt + 1 < nt) { WAIT_BAR(); cur ^= 1; }
    }

#pragma unroll
    for (int i = 0; i < 4; i++) {
#pragma unroll
        for (int j = 0; j < 4; j++) {
#pragma unroll
            for (int r = 0; r < 4; r++) {
                float v = acc[i][j][r];
                long row = m0 + wm * 64 + i * 16 + quad * 4 + r;
                int col = n0 + wn * 64 + j * 16 + l16;
                if (act == 3) {
                    if (col < 256)      Cb[so256 + row * 256 + col] = f2b(elu1(v));
                    else if (col < 512) ((ushort*)Cf)[so256 + row * 256 + col - 256] = f2b(elu1(v));
                    else                ((ushort*)Cv)[so256 + row * 256 + col - 512] = f2b(v);
                } else if (act == 4) {
                    if (col < 256) ((ushort*)Cf)[so256 + row * 256 + col] = f2b(elu1(v));
                    else           ((ushort*)Cv)[so256 + row * 256 + col - 256] = f2b(v);
                } else {
                    if (act == 1)      v = elu1(v);
                    else if (act == 2) v = fmaxf(v, 0.f);
                    if (Cf) Cf[soN + row * N + col] = v;
                    if (Cb) Cb[soN + row * N + col] = f2b(v);
                }
            }
        }
    }
}

// ---------------- fused GEMM (N=256) + row-LN over COMPACT rows -------------
// M=32 tile (grid.x=768 per side, early-exit); side = side0 + blockIdx.z.
// A direct from global (registers); B 2-buffer LDS (32KB).
__global__ __launch_bounds__(256) void lft_gemm_ln(
    const ushort* __restrict__ A0b, const ushort* __restrict__ A1b, int kSplit,
    const ushort* __restrict__ Wt, int K,
    const float* __restrict__ g, const float* __restrict__ bb,
    const float* __restrict__ rcInB, float* rcOutB,
    const int* __restrict__ glB, const int* __restrict__ minfo,
    float* outScB, ushort* __restrict__ outBB, int side0)
{
    __shared__ ushort Bs[2][256 * 32];
    __shared__ float gs[256], bs[256];
    __shared__ float psum[4][32], psq[4][32];
    int side = side0 + blockIdx.z;
    long m0 = (long)blockIdx.x << 5;
    if (m0 >= minfo[side]) return;
    const ushort* A0 = A0b + (long)side * CAP * kSplit;
    const ushort* A1 = A1b + (long)side * CAP * (K - kSplit);
    long so = (long)side * CAP * 256;
    int t = threadIdx.x;
    int wv = t >> 6, lane = t & 63;
    int l16 = lane & 15, quad = lane >> 4;
    gs[t] = g[t]; bs[t] = bb[t];
    floatx4 acc[2][4] = {};

    int lrow = lane >> 2;
    int lcg = lane & 3;

    auto stageB = [&](int buf, int k0) {
#pragma unroll
        for (int s = 0; s < 4; s++) {
            int r = s * 64 + wv * 16 + lrow;
            int cg = (lcg ^ swz(r)) << 3;
            GLOAD16(&Wt[(size_t)r * K + k0 + cg], &Bs[buf][(s * 64 + wv * 16) * 32]);
        }
    };

    auto compute = [&](int buf, int k0) {
        const ushort* Asrc; int kcol, ldA;
        if (k0 < kSplit) { Asrc = A0; kcol = k0;          ldA = kSplit; }
        else             { Asrc = A1; kcol = k0 - kSplit; ldA = K - kSplit; }
        const ushort* Bb = &Bs[buf][0];
        short8 af[2], bfr[4];
#pragma unroll
        for (int i = 0; i < 2; i++) {
            long rA = m0 + i * 16 + l16;
            af[i] = *(const short8*)&Asrc[rA * ldA + kcol + quad * 8];
        }
#pragma unroll
        for (int j = 0; j < 4; j++) {
            int rB = wv * 64 + j * 16 + l16;
            bfr[j] = *(const short8*)&Bb[rB * 32 + ((quad ^ swz(rB)) << 3)];
        }
        __builtin_amdgcn_s_setprio(1);
#pragma unroll
        for (int i = 0; i < 2; i++)
#pragma unroll
            for (int j = 0; j < 4; j++)
                acc[i][j] = __builtin_amdgcn_mfma_f32_16x16x32_bf16(af[i], bfr[j], acc[i][j], 0, 0, 0);
        __builtin_amdgcn_s_setprio(0);
    };

    int nt = K >> 5;
    stageB(0, 0);
    WAIT_BAR();
    int cur = 0;
    for (int tt = 0; tt < nt; ++tt) {
        if (tt + 1 < nt) stageB(cur ^ 1, (tt + 1) << 5);
        compute(cur, tt << 5);
        if (tt + 1 < nt) { WAIT_BAR(); cur ^= 1; }
    }
#pragma unroll
    for (int i = 0; i < 2; i++) {
#pragma unroll
        for (int r = 0; r < 4; r++) {
            float s = 0.f, q = 0.f;
#pragma unroll
            for (int j = 0; j < 4; j++) { float v = acc[i][j][r]; s += v; q += v * v; }
#pragma unroll
            for (int o = 8; o >= 1; o >>= 1) {
                s += __shfl_xor(s, o, 64);
                q += __shfl_xor(q, o, 64);
            }
            if (l16 == 0) {
                int row = i * 16 + quad * 4 + r;
                psum[wv][row] = s; psq[wv][row] = q;
            }
        }
    }
    __syncthreads();
    if (t < 32) {
        float s = psum[0][t] + psum[1][t] + psum[2][t] + psum[3][t];
        float q = psq[0][t] + psq[1][t] + psq[2][t] + psq[3][t];
        float mean = s * (1.0f / 256.0f);
        float var = q * (1.0f / 256.0f) - mean * mean;
        psum[0][t] = mean;
        psq[0][t] = rsqrtf(var + 1e-5f);
    }
    __syncthreads();
    int mvE = minfo[2 + side];
    const float* rcIn = rcInB ? rcInB + so : nullptr;
    float* rcOut = rcOutB ? rcOutB + so : nullptr;
    const int* glp = glB + side * CAP;
    float* outSc = outScB ? outScB + (long)side * 9830400L : nullptr;
    ushort* outB = outBB ? outBB + so : nullptr;
#pragma unroll
    for (int i = 0; i < 2; i++) {
#pragma unroll
        for (int r = 0; r < 4; r++) {
            int rloc = i * 16 + quad * 4 + r;
            long grow = m0 + rloc;
            float mean = psum[0][rloc], rstd = psq[0][rloc];
#pragma unroll
            for (int j = 0; j < 4; j++) {
                int col = wv * 64 + j * 16 + l16;
                float y = (acc[i][j][r] - mean) * rstd * gs[col] + bs[col];
                if (rcIn) y += rcIn[grow * 256 + col];
                if (rcOut) rcOut[grow * 256 + col] = y;
                if (outSc && grow < mvE) outSc[(long)glp[grow] * 256 + col] = y;
                if (outB) outB[grow * 256 + col] = f2b(y);
            }
        }
    }
}

// ---------------- per-class KV / Ksum reduction (compact, bf16 inputs) -------
__global__ __launch_bounds__(256) void lft_kv_kernel(
    const ushort* __restrict__ kcB, const ushort* __restrict__ vcB,
    const int* __restrict__ cmetaB,
    float* kvbB, float* ksbB, int sideSrc0)
{
    int side = sideSrc0 + (blockIdx.z >> 6);
    int zz = blockIdx.z & 63;
    int chunk = blockIdx.x, c = blockIdx.y;
    int b = zz >> 3, h = zz & 7;
    const int* cmeta = cmetaB + side * 128;
    int cstart = cmeta[(b * 8 + c) * 2], n = cmeta[(b * 8 + c) * 2 + 1];
    int per = (n + KV_NCH - 1) / KV_NCH;
    int s0 = chunk * per;
    int s1 = min(s0 + per, n);
    if (s0 >= s1) return;
    const ushort* phik = kcB + (long)side * CAP * 256;
    const ushort* vmat = vcB + (long)side * CAP * 256;
    float* kv = kvbB + (long)side * 524288;
    float* ksum = ksbB + (long)side * 16384;
    int t = threadIdx.x;
    __shared__ float kb[8][32];
    __shared__ float vb[8][32];
    int od = t >> 3, oe = (t & 7) << 2;
    int lt = t >> 5, ld = t & 31;
    float a0 = 0.f, a1 = 0.f, a2 = 0.f, a3 = 0.f, ak = 0.f;
    for (int s = s0; s < s1; s += 8) {
        float kval = 0.f, vval = 0.f;
        if (s + lt < s1) {
            long bse = (long)(cstart + s + lt) * 256 + h * 32 + ld;
            kval = b2f(phik[bse]);
            vval = b2f(vmat[bse]);
        }
        __syncthreads();
        kb[lt][ld] = kval;
        vb[lt][ld] = vval;
        __syncthreads();
#pragma unroll
        for (int j = 0; j < 8; j++) {
            float kd = kb[j][od];
            float4 vv = *(const float4*)&vb[j][oe];
            a0 += kd * vv.x; a1 += kd * vv.y; a2 += kd * vv.z; a3 += kd * vv.w;
            ak += kd;
        }
    }
    float* dst = kv + (((long)(b * NPROTO + c) * 8 + h) << 10) + od * 32 + oe;
    atomicAdd(dst + 0, a0);
    atomicAdd(dst + 1, a1);
    atomicAdd(dst + 2, a2);
    atomicAdd(dst + 3, a3);
    if ((t & 7) == 0)
        atomicAdd(ksum + (((long)(b * NPROTO + c) * 8 + h) << 5) + od, ak);
}

// ---------------- msg via MFMA over compact rows; kv fragments from fp32 -----
__global__ __launch_bounds__(256) void lft_msg_kernel(
    const ushort* __restrict__ qcB, const float* __restrict__ kvbB,
    const float* __restrict__ ksbB, const int* __restrict__ cmetaB,
    ushort* __restrict__ msgcB, int sideX0, int sideKV0)
{
    int add = blockIdx.z >> 3, b = blockIdx.z & 7;
    int sideX = sideX0 + add, sideKV = sideKV0 + add;
    int chunk = blockIdx.x, c = blockIdx.y;
    const int* cmeta = cmetaB + sideX * 128;
    int cstart = cmeta[(b * 8 + c) * 2], n = cmeta[(b * 8 + c) * 2 + 1];
    int per = (n + MSG_NCH - 1) / MSG_NCH;
    int s0 = chunk * per, s1 = min(s0 + per, n);
    if (s0 >= s1) return;
    const ushort* pq = qcB + (long)sideX * CAP * 256;
    ushort* msg = msgcB + (long)sideX * CAP * 256;
    int t = threadIdx.x;
    int wave = t >> 6, lane = t & 63;
    int l16 = lane & 15, quad = lane >> 4;
    int bc = b * 8 + c;
    short8 bfr[2][3];
#pragma unroll
    for (int hh = 0; hh < 2; hh++) {
        int h = wave * 2 + hh;
        const float* kvsrc = kvbB + (long)sideKV * 524288 + ((long)bc * 8 + h) * 1024;
        const float* kssrc = ksbB + (long)sideKV * 16384 + ((long)bc * 8 + h) * 32;
#pragma unroll
        for (int nt = 0; nt < 2; nt++)
#pragma unroll
            for (int j = 0; j < 8; j++)
                bfr[hh][nt][j] = (short)f2b(kvsrc[(quad * 8 + j) * 32 + nt * 16 + l16]);
#pragma unroll
        for (int j = 0; j < 8; j++)
            bfr[hh][2][j] = (l16 == 0) ? (short)f2b(kssrc[quad * 8 + j]) : (short)0;
    }
    for (int s = s0; s < s1; s += 16) {
        long rowA = cstart + min(s + l16, s1 - 1);
#pragma unroll
        for (int hh = 0; hh < 2; hh++) {
            int h = wave * 2 + hh;
            short8 a = *(const short8*)&pq[rowA * 256 + h * 32 + quad * 8];
            floatx4 n0 = {}, n1 = {}, dd = {};
            n0 = __builtin_amdgcn_mfma_f32_16x16x32_bf16(a, bfr[hh][0], n0, 0, 0, 0);
            n1 = __builtin_amdgcn_mfma_f32_16x16x32_bf16(a, bfr[hh][1], n1, 0, 0, 0);
            dd = __builtin_amdgcn_mfma_f32_16x16x32_bf16(a, bfr[hh][2], dd, 0, 0, 0);
#pragma unroll
            for (int r = 0; r < 4; r++) {
                int rowi = s + quad * 4 + r;
                float den = __shfl(dd[r], lane & 48, 64);
                float inv = 1.f / (den + 1e-6f);
                if (rowi < s1) {
                    long base = (long)(cstart + rowi) * 256 + h * 32;
                    msg[base + l16]      = f2b(n0[r] * inv);
                    msg[base + 16 + l16] = f2b(n1[r] * inv);
                }
            }
        }
    }
}

extern "C" void kernel_launch(void* const* d_in, const int* in_sizes, int n_in,
                              void* d_out, int out_size, void* d_ws, size_t ws_size,
                              hipStream_t stream)
{
    (void)in_sizes; (void)n_in; (void)out_size; (void)ws_size;
    const float* feat0 = (const float*)d_in[0];
    const float* feat1 = (const float*)d_in[1];
    const int*   mask0 = (const int*)d_in[2];
    const int*   mask1 = (const int*)d_in[3];
    const float* f0wo  = (const float*)d_in[4];
    const float* f1wo  = (const float*)d_in[5];
    const float* proto = (const float*)d_in[6];
    const float* Wq = (const float*)d_in[7];
    const float* Wk = (const float*)d_in[8];
    const float* Wv = (const float*)d_in[9];
    const float* Wm = (const float*)d_in[10];
    const float* W1 = (const float*)d_in[11];
    const float* W2 = (const float*)d_in[12];
    const float* g1 = (const float*)d_in[13];
    const float* b1 = (const float*)d_in[14];
    const float* g2 = (const float*)d_in[15];
    const float* b2 = (const float*)d_in[16];
    float* out = (float*)d_out;
    float* ws = (float*)d_ws;

    // ---- workspace layout (side-strided compact buffers, CAP rows/side) ----
    const long FSZ = 9830400L;
    float* rc = ws;                               // 2*CAP*256 f
    ushort* kc = (ushort*)(rc + 2 * CAP * 256);   // 2*CAP*256 us  bf16
    ushort* vc = kc + 2 * CAP * 256;              // 2*CAP*256 us  bf16
    ushort* hid = vc + 2 * CAP * 256;             // 2*CAP*512 us
    ushort* xc   = hid + 2 * CAP * 512;
    ushort* msgc = xc + 2 * CAP * 256;
    ushort* qc   = msgc + 2 * CAP * 256;
    ushort* wb   = qc + 2 * CAP * 256;
    ushort* wb1  = wb + 16 * 65536;
    ushort* wb2  = wb1 + 4 * 262144;
    float* kvb = (float*)(wb2 + 4 * 131072);      // 2*524288 f
    float* ksb = kvb + 2 * 524288;                // 2*16384 f
    int* cls0 = (int*)(ksb + 2 * 16384);
    int* cls1 = cls0 + 38400;
    int* gl   = cls1 + 38400;                     // 2*CAP ints
    int* meta = gl + 2 * CAP;
    int* minfo = meta + 256;
    int* cmeta = minfo + 20;

    lft_wconv_kernel<<<dim3(8, 8, 16), 256, 0, stream>>>(Wq, Wk, Wv, Wm, 256, 256, 4, wb);
    lft_wconv_kernel<<<dim3(16, 16, 4), 256, 0, stream>>>(W1, W1, W1, W1, 512, 512, 1, wb1);
    lft_wconv_kernel<<<dim3(16, 8, 4), 256, 0, stream>>>(W2, W2, W2, W2, 512, 256, 1, wb2);
    hipMemcpyAsync(out + 20352000L, proto, 2048 * 4, hipMemcpyDeviceToDevice, stream);
    lft_class_kernel<<<600, 256, 0, stream>>>(f0wo, f1wo, mask0, mask1, proto,
                                              out, cls0, cls1);
    lft_invcopy_kernel<<<1200, 256, 0, stream>>>(feat0, feat1, cls0, cls1, out);
    lft_count_kernel<<<16, 256, 0, stream>>>(cls0, cls1, meta);
    lft_scan_kernel<<<1, 256, 0, stream>>>(meta, minfo, cmeta);
    lft_place_kernel<<<16, 256, 0, stream>>>(cls0, cls1, cmeta, gl);
    lft_gcast_kernel<<<1200, 256, 0, stream>>>(feat0, feat1, gl, minfo, xc, rc);

    dim3 blk(256);
    for (int li = 0; li < 4; li++) {
        const ushort* wq = wb + (size_t)(li * 4 + 0) * 65536;   // [wq|wk|wv|wm]
        const ushort* wk = wb + (size_t)(li * 4 + 1) * 65536;
        const ushort* wm = wb + (size_t)(li * 4 + 3) * 65536;
        const ushort* w1 = wb1 + (size_t)li * 262144;
        const ushort* w2 = wb2 + (size_t)li * 131072;
        const float* g1p = g1 + li * 256; const float* b1p = b1 + li * 256;
        const float* g2p = g2 + li * 256; const float* b2p = b2 + li * 256;
        bool last = (li == 3);

        if ((li & 1) == 0) {
            // ---- self-self, both sides combined (z=2) ----
            lft_mfma_gemm<<<dim3(6, 192, 2), blk, 0, stream>>>(
                xc, xc, 256, wq, (float*)kc, qc, (float*)vc, 768, 256, 3, minfo, 0);
            hipMemsetAsync(kvb, 0, (2 * 524288 + 2 * 16384) * 4, stream);
            lft_kv_kernel<<<dim3(KV_NCH, 8, 128), blk, 0, stream>>>(kc, vc, cmeta, kvb, ksb, 0);
            lft_msg_kernel<<<dim3(MSG_NCH, 8, 16), blk, 0, stream>>>(qc, kvb, ksb, cmeta, msgc, 0, 0);
            lft_gemm_ln<<<dim3(768, 1, 2), blk, 0, stream>>>(
                msgc, msgc, 256, wm, 256, g1p, b1p,
                nullptr, nullptr, gl, minfo, nullptr, msgc, 0);
            lft_mfma_gemm<<<dim3(4, 192, 2), blk, 0, stream>>>(
                xc, msgc, 256, w1, nullptr, hid, nullptr, 512, 512, 2, minfo, 0);
            lft_gemm_ln<<<dim3(768, 1, 2), blk, 0, stream>>>(
                hid, hid, 512, w2, 512, g2p, b2p,
                rc, rc, gl, minfo, nullptr, xc, 0);
        } else {
            // ---- cross-self: q for both sides from OLD features ----
            lft_mfma_gemm<<<dim3(2, 192, 2), blk, 0, stream>>>(
                xc, xc, 256, wq, nullptr, qc, nullptr, 256, 256, 1, minfo, 0);
            // k|v from side1 (old) -> kc/vc side1
            lft_mfma_gemm<<<dim3(4, 192, 1), blk, 0, stream>>>(
                xc, xc, 256, wk, (float*)kc, nullptr, (float*)vc, 512, 256, 4, minfo, 1);
            hipMemsetAsync(kvb, 0, (2 * 524288 + 2 * 16384) * 4, stream);
            lft_kv_kernel<<<dim3(KV_NCH, 8, 64), blk, 0, stream>>>(kc, vc, cmeta, kvb, ksb, 1);
            lft_msg_kernel<<<dim3(MSG_NCH, 8, 8), blk, 0, stream>>>(qc, kvb, ksb, cmeta, msgc, 0, 1);
            lft_gemm_ln<<<dim3(768, 1, 1), blk, 0, stream>>>(
                msgc, msgc, 256, wm, 256, g1p, b1p,
                nullptr, nullptr, gl, minfo, nullptr, msgc, 0);
            lft_mfma_gemm<<<dim3(4, 192, 1), blk, 0, stream>>>(
                xc, msgc, 256, w1, nullptr, hid, nullptr, 512, 512, 2, minfo, 0);
            lft_gemm_ln<<<dim3(768, 1, 1), blk, 0, stream>>>(
                hid, hid, 512, w2, 512, g2p, b2p,
                rc, last ? nullptr : rc, gl, minfo, last ? out : nullptr, xc, 0);
            // ---- side1 attends UPDATED side0 ----
            lft_mfma_gemm<<<dim3(4, 192, 1), blk, 0, stream>>>(
                xc, xc, 256, wk, (float*)kc, nullptr, (float*)vc, 512, 256, 4, minfo, 0);
            hipMemsetAsync(kvb, 0, (2 * 524288 + 2 * 16384) * 4, stream);
            lft_kv_kernel<<<dim3(KV_NCH, 8, 64), blk, 0, stream>>>(kc, vc, cmeta, kvb, ksb, 0);
            lft_msg_kernel<<<dim3(MSG_NCH, 8, 8), blk, 0, stream>>>(qc, kvb, ksb, cmeta, msgc, 1, 0);
            lft_gemm_ln<<<dim3(768, 1, 1), blk, 0, stream>>>(
                msgc, msgc, 256, wm, 256, g1p, b1p,
                nullptr, nullptr, gl, minfo, nullptr, msgc, 1);
            lft_mfma_gemm<<<dim3(4, 192, 1), blk, 0, stream>>>(
                xc, msgc, 256, w1, nullptr, hid, nullptr, 512, 512, 2, minfo, 1);
            lft_gemm_ln<<<dim3(768, 1, 1), blk, 0, stream>>>(
                hid, hid, 512, w2, 512, g2p, b2p,
                rc, last ? nullptr : rc, gl, minfo, last ? out : nullptr,
                last ? nullptr : xc, 1);
        }
    }
}

// Round 13
// 1448.003 us; speedup vs baseline: 1.1386x; 1.1386x over previous
//
#include <hip/hip_runtime.h>
#include <math.h>

#define NPROTO 8
#define KV_NCH 4
#define MSG_NCH 8
#define CAP 24576L            // compact rows per side (Mv ~= 19200 +- ~200)

typedef __attribute__((ext_vector_type(8))) short short8;
typedef __attribute__((ext_vector_type(4))) float floatx4;

static __device__ __forceinline__ ushort f2b(float f) {
    unsigned u = __builtin_bit_cast(unsigned, f);
    unsigned r = (u + 0x7fffu + ((u >> 16) & 1u)) >> 16;
    return (ushort)r;
}

static __device__ __forceinline__ float b2f(ushort u) {
    return __builtin_bit_cast(float, (unsigned)u << 16);
}

static __device__ __forceinline__ float elu1(float v) {
    return v > 0.f ? v + 1.f : __expf(v);
}

// async 16B global -> LDS (linear dest: wave base + lane*16B)
#define GLOAD16(gp, lp) __builtin_amdgcn_global_load_lds( \
    (const __attribute__((address_space(1))) void*)(gp),  \
    (__attribute__((address_space(3))) void*)(lp), 16, 0, 0)

// full drain + barrier (gemm_ln's proven 2-phase structure)
#define WAIT_BAR() asm volatile("s_waitcnt vmcnt(0) lgkmcnt(0)\n\ts_barrier" ::: "memory")
// counted waits (mfma_gemm 3-buffer pipeline; 4 loads/thread/tile)
#define VMWAIT(N) asm volatile("s_waitcnt vmcnt(" #N ")" ::: "memory")
#define BAR() __builtin_amdgcn_s_barrier()

// swizzle of the 16B-group index within a 32-col bf16 row (4 groups/row)
static __device__ __forceinline__ int swz(int r) { return (r >> 1) & 3; }

// ---------------- prototype projection / argmax-class kernel ----------------
__global__ __launch_bounds__(256) void lft_class_kernel(
    const float* __restrict__ f0wo, const float* __restrict__ f1wo,
    const int* __restrict__ mask0, const int* __restrict__ mask1,
    const float* __restrict__ proto,
    float* out, int* cls0, int* cls1)
{
    __shared__ float pr[2048];          // proto [8][256]
    __shared__ float tile[128][68];     // [token][ch chunk], stride 68
    __shared__ float sm[128][8];
    int t = threadIdx.x;
    *(float4*)&pr[t * 4]        = *(const float4*)&proto[t * 4];
    *(float4*)&pr[1024 + t * 4] = *(const float4*)&proto[1024 + t * 4];
    long tok0 = (long)blockIdx.x * 128;
    const float* fsrc; const int* msrc; float* fpout; float* clsout; int* clsarr; long tbase;
    if (tok0 < 38400) {
        tbase = tok0; fsrc = f0wo; msrc = mask0;
        fpout = out + 19737600L; clsout = out + 19660800L; clsarr = cls0;
    } else {
        tbase = tok0 - 38400; fsrc = f1wo; msrc = mask1;
        fpout = out + 20044800L; clsout = out + 19699200L; clsarr = cls1;
    }
    int tok = t & 127, half = t >> 7;
    float s[4] = {};
    int r0 = t >> 4;            // 0..15
    int c4 = (t & 15) << 2;     // 0..60
    for (int ct = 0; ct < 4; ct++) {
        __syncthreads();
#pragma unroll
        for (int rr = 0; rr < 8; rr++) {
            int row = rr * 16 + r0;
            float4 v = *(const float4*)&fsrc[(tbase + row) * 256 + ct * 64 + c4];
            *(float4*)&tile[row][c4] = v;
        }
        __syncthreads();
#pragma unroll
        for (int cc = 0; cc < 16; cc++) {
            float4 f = *(const float4*)&tile[tok][cc << 2];
#pragma unroll
            for (int p = 0; p < 4; p++) {
                float4 pv = *(const float4*)&pr[(half * 4 + p) * 256 + ct * 64 + (cc << 2)];
                s[p] += f.x * pv.x + f.y * pv.y + f.z * pv.z + f.w * pv.w;
            }
        }
    }
#pragma unroll
    for (int p = 0; p < 4; p++) {
        fpout[(tbase + tok) * 8 + half * 4 + p] = s[p];
        sm[tok][half * 4 + p] = s[p];
    }
    __syncthreads();
    if (t < 128) {
        int best = 0; float bv = sm[t][0];
#pragma unroll
        for (int p = 1; p < 8; p++) { if (sm[t][p] > bv) { bv = sm[t][p]; best = p; } }
        clsout[tbase + t] = (float)best;
        clsarr[tbase + t] = msrc[tbase + t] ? best : -1;
    }
}

// ---------------- copy ONLY invalid-token rows of feat into out --------------
__global__ __launch_bounds__(256) void lft_invcopy_kernel(
    const float* __restrict__ f0, const float* __restrict__ f1,
    const int* __restrict__ cls0, const int* __restrict__ cls1,
    float* out)
{
    int w = blockIdx.x * 4 + (threadIdx.x >> 6);   // 0..4799
    int lane = threadIdx.x & 63;
    for (long row = w; row < 76800; row += 4800) {
        int side = row >= 38400;
        long r = row - (long)side * 38400;
        int c = side ? cls1[r] : cls0[r];
        if (c < 0) {
            const float* src = side ? f1 : f0;
            float4 v = *(const float4*)&src[r * 256 + lane * 4];
            *(float4*)&out[(long)side * 9830400L + r * 256 + lane * 4] = v;
        }
    }
}

// ---------------- per-(L,b) class counts -> meta {base,cnt} ------------------
__global__ __launch_bounds__(256) void lft_count_kernel(
    const int* __restrict__ cls0, const int* __restrict__ cls1, int* meta)
{
    int g = blockIdx.x; int L = g >> 3, b = g & 7;
    const int* cls = (L ? cls1 : cls0) + b * 4800;
    int* mt = meta + (L * 8 + b) * 16;
    __shared__ int cnt[8];
    int t = threadIdx.x;
    if (t < 8) cnt[t] = 0;
    __syncthreads();
    for (int tok = t; tok < 4800; tok += 256) {
        int c = cls[tok];
        if (c >= 0) atomicAdd(&cnt[c], 1);
    }
    __syncthreads();
    if (t == 0) {
        int s = 0;
        for (int c = 0; c < 8; c++) { mt[c * 2] = s; mt[c * 2 + 1] = cnt[c]; s += cnt[c]; }
    }
}

// ---------------- cross-batch scan: minfo (Mv, boff) + compact cmeta ---------
__global__ __launch_bounds__(256) void lft_scan_kernel(
    const int* __restrict__ meta, int* minfo, int* cmeta)
{
    int t = threadIdx.x;
    __shared__ int nb[16];
    if (t < 16) {
        int s = 0;
        for (int c = 0; c < 8; c++) s += meta[t * 16 + c * 2 + 1];
        nb[t] = s;
    }
    __syncthreads();
    if (t == 0) {
        int off = 0;
        for (int b = 0; b < 8; b++) { minfo[4 + b] = off; off += nb[b]; }
        minfo[2] = off; minfo[0] = (off + 127) & ~127;
        off = 0;
        for (int b = 0; b < 8; b++) { minfo[12 + b] = off; off += nb[8 + b]; }
        minfo[3] = off; minfo[1] = (off + 127) & ~127;
    }
    __syncthreads();
    if (t < 128) {
        int L = t >> 6, b = (t >> 3) & 7, c = t & 7;
        cmeta[t * 2]     = minfo[4 + L * 8 + b] + meta[(L * 8 + b) * 16 + c * 2];
        cmeta[t * 2 + 1] = meta[(L * 8 + b) * 16 + c * 2 + 1];
    }
}

// ---------------- place valid tokens into compact gather lists ---------------
__global__ __launch_bounds__(256) void lft_place_kernel(
    const int* __restrict__ cls0, const int* __restrict__ cls1,
    const int* __restrict__ cmeta, int* gl)
{
    int g = blockIdx.x; int L = g >> 3, b = g & 7;
    const int* cls = (L ? cls1 : cls0) + b * 4800;
    int* glp = gl + L * CAP;
    __shared__ int pos[8];
    int t = threadIdx.x;
    if (t < 8) pos[t] = cmeta[(L * 64 + b * 8 + t) * 2];
    __syncthreads();
    for (int tok = t; tok < 4800; tok += 256) {
        int c = cls[tok];
        if (c >= 0) { int p = atomicAdd(&pos[c], 1); glp[p] = b * 4800 + tok; }
    }
}

// ---------------- gather-cast: compact bf16 x + compact fp32 resid -----------
__global__ __launch_bounds__(256) void lft_gcast_kernel(
    const float* __restrict__ f0, const float* __restrict__ f1,
    const int* __restrict__ gl, const int* __restrict__ minfo,
    ushort* xc, float* rc)
{
    int blk = blockIdx.x;
    int side = blk >= 600 ? 1 : 0;
    int i0 = (blk - side * 600) * 4 + (threadIdx.x >> 6);
    int mv = minfo[2 + side];
    const int* glp = gl + side * CAP;
    const float* f = side ? f1 : f0;
    ushort* xcp = xc + side * CAP * 256;
    float* rcp = rc + side * CAP * 256;
    int lane = threadIdx.x & 63;
    for (int i = i0; i < mv; i += 2400) {
        long src = (long)glp[i] * 256 + lane * 4;
        float4 v = *(const float4*)&f[src];
        long dst = (long)i * 256 + lane * 4;
        *(float4*)&rcp[dst] = v;
        ushort4 u; u.x = f2b(v.x); u.y = f2b(v.y); u.z = f2b(v.z); u.w = f2b(v.w);
        *(ushort4*)&xcp[dst] = u;
    }
}

// ---------------- weight convert + transpose: Wt[n*K+k] = bf16(W[k*N+n]) ----
__global__ __launch_bounds__(256) void lft_wconv_kernel(
    const float* W0, const float* W1p, const float* W2p, const float* W3p,
    int K, int N, int nTypes, ushort* dst)
{
    int z = blockIdx.z;
    int li = z / nTypes, mi = z % nTypes;
    const float* srcs[4] = {W0, W1p, W2p, W3p};
    const float* src = srcs[mi] + (size_t)li * K * N;
    ushort* outp = dst + (size_t)z * K * N;
    __shared__ float tile[32][33];
    int k0 = blockIdx.x * 32, n0 = blockIdx.y * 32;
    int t = threadIdx.x;
    int r = t >> 3, c4 = (t & 7) << 2;
    float4 v = *(const float4*)&src[(size_t)(k0 + r) * N + n0 + c4];
    tile[r][c4] = v.x; tile[r][c4 + 1] = v.y; tile[r][c4 + 2] = v.z; tile[r][c4 + 3] = v.w;
    __syncthreads();
    ushort4 o;
    o.x = f2b(tile[c4 + 0][r]);
    o.y = f2b(tile[c4 + 1][r]);
    o.z = f2b(tile[c4 + 2][r]);
    o.w = f2b(tile[c4 + 3][r]);
    *(ushort4*)&outp[(size_t)(n0 + r) * K + k0 + c4] = o;
}

// ---------------- bf16 MFMA GEMM over COMPACT rows, side = blockIdx.z --------
// 3-buffer counted-vmcnt pipeline. 128x128 tile, 4 waves, LDS 48KB.
// act: 0 none, 1 elu+1, 2 relu; act 3 qkv N=768 (q/k/v bf16);
// act 4 kv N=512 (k/v bf16). k,v buffers are ushort (passed via Cf/Cv).
__global__ __launch_bounds__(256) void lft_mfma_gemm(
    const ushort* __restrict__ A0b, const ushort* __restrict__ A1b, int kSplit,
    const ushort* __restrict__ Wt,
    float* Cf, ushort* Cb, float* Cv, int N, int K, int act,
    const int* __restrict__ minfo, int side0)
{
    __shared__ ushort As[3][128 * 32];
    __shared__ ushort Bs[3][128 * 32];
    int side = side0 + blockIdx.z;
    int m0 = blockIdx.y << 7;
    if (m0 >= minfo[side]) return;
    const ushort* A0 = A0b + (long)side * CAP * kSplit;
    const ushort* A1 = A1b + (long)side * CAP * (K - kSplit);
    long so256 = (long)side * CAP * 256;
    long soN = (long)side * CAP * N;
    int t = threadIdx.x;
    int n0 = blockIdx.x << 7;
    int wv = t >> 6, lane = t & 63;
    int wm = wv >> 1, wn = wv & 1;
    int l16 = lane & 15, quad = lane >> 4;
    floatx4 acc[4][4] = {};

    int lrow = lane >> 2;
    int lcg = lane & 3;

    auto stage = [&](int buf, int k0) {
        const ushort* Asrc; int kcol, ldA;
        if (k0 < kSplit) { Asrc = A0; kcol = k0;          ldA = kSplit; }
        else             { Asrc = A1; kcol = k0 - kSplit; ldA = K - kSplit; }
        ushort* Ab = &As[buf][0];
        ushort* Bb = &Bs[buf][0];
#pragma unroll
        for (int s = 0; s < 2; s++) {
            int r = s * 64 + wv * 16 + lrow;
            int cgA = (lcg ^ swz(r)) << 3;
            GLOAD16(&Asrc[(size_t)(m0 + r) * ldA + kcol + cgA], &Ab[(s * 64 + wv * 16) * 32]);
            GLOAD16(&Wt[(size_t)(n0 + r) * K + k0 + cgA], &Bb[(s * 64 + wv * 16) * 32]);
        }
    };

    auto compute = [&](int buf) {
        const ushort* Ab = &As[buf][0];
        const ushort* Bb = &Bs[buf][0];
        short8 af[4], bfr[4];
#pragma unroll
        for (int i = 0; i < 4; i++) {
            int rA = wm * 64 + i * 16 + l16;
            int rB = wn * 64 + i * 16 + l16;
            af[i]  = *(const short8*)&Ab[rA * 32 + ((quad ^ swz(rA)) << 3)];
            bfr[i] = *(const short8*)&Bb[rB * 32 + ((quad ^ swz(rB)) << 3)];
        }
        __builtin_amdgcn_s_setprio(1);
#pragma unroll
        for (int i = 0; i < 4; i++)
#pragma unroll
            for (int j = 0; j < 4; j++)
                acc[i][j] = __builtin_amdgcn_mfma_f32_16x16x32_bf16(af[i], bfr[j], acc[i][j], 0, 0, 0);
        __builtin_amdgcn_s_setprio(0);
    };

    int nt = K >> 5;               // 8 or 16
    stage(0, 0);
    stage(1, 32);
    int cur = 0;
    for (int tt = 0; tt < nt; ++tt) {
        if (tt + 2 < nt) {
            int nb = cur + 2; if (nb >= 3) nb -= 3;
            stage(nb, (tt + 2) << 5);
            VMWAIT(8);             // tile tt done; tt+1, tt+2 in flight
        } else if (tt + 2 == nt) {
            VMWAIT(4);
        } else {
            VMWAIT(0);
        }
        BAR();
        compute(cur);
        if (tt + 1 < nt) BAR();
        cur = cur + 1 == 3 ? 0 : cur + 1;
    }

#pragma unroll
    for (int i = 0; i < 4; i++) {
#pragma unroll
        for (int j = 0; j < 4; j++) {
#pragma unroll
            for (int r = 0; r < 4; r++) {
                float v = acc[i][j][r];
                long row = m0 + wm * 64 + i * 16 + quad * 4 + r;
                int col = n0 + wn * 64 + j * 16 + l16;
                if (act == 3) {
                    if (col < 256)      Cb[so256 + row * 256 + col] = f2b(elu1(v));
                    else if (col < 512) ((ushort*)Cf)[so256 + row * 256 + col - 256] = f2b(elu1(v));
                    else                ((ushort*)Cv)[so256 + row * 256 + col - 512] = f2b(v);
                } else if (act == 4) {
                    if (col < 256) ((ushort*)Cf)[so256 + row * 256 + col] = f2b(elu1(v));
                    else           ((ushort*)Cv)[so256 + row * 256 + col - 256] = f2b(v);
                } else {
                    if (act == 1)      v = elu1(v);
                    else if (act == 2) v = fmaxf(v, 0.f);
                    if (Cf) Cf[soN + row * N + col] = v;
                    if (Cb) Cb[soN + row * N + col] = f2b(v);
                }
            }
        }
    }
}

// ---------------- fused GEMM (N=256) + row-LN over COMPACT rows -------------
// M=32 tile (grid.x=768 per side, early-exit); side = side0 + blockIdx.z.
// Proven 2-phase drain pipeline.
__global__ __launch_bounds__(256) void lft_gemm_ln(
    const ushort* __restrict__ A0b, const ushort* __restrict__ A1b, int kSplit,
    const ushort* __restrict__ Wt, int K,
    const float* __restrict__ g, const float* __restrict__ bb,
    const float* __restrict__ rcInB, float* rcOutB,
    const int* __restrict__ glB, const int* __restrict__ minfo,
    float* outScB, ushort* __restrict__ outBB, int side0)
{
    __shared__ ushort As[2][32 * 32];
    __shared__ ushort Bs[2][256 * 32];
    __shared__ float gs[256], bs[256];
    __shared__ float psum[4][32], psq[4][32];
    int side = side0 + blockIdx.z;
    long m0 = (long)blockIdx.x << 5;
    if (m0 >= minfo[side]) return;
    const ushort* A0 = A0b + (long)side * CAP * kSplit;
    const ushort* A1 = A1b + (long)side * CAP * (K - kSplit);
    long so = (long)side * CAP * 256;
    int t = threadIdx.x;
    int wv = t >> 6, lane = t & 63;
    int l16 = lane & 15, quad = lane >> 4;
    gs[t] = g[t]; bs[t] = bb[t];
    floatx4 acc[2][4] = {};

    int lrow = lane >> 2;
    int lcg = lane & 3;

    auto stage = [&](int buf, int k0) {
        const ushort* Asrc; int kcol, ldA;
        if (k0 < kSplit) { Asrc = A0; kcol = k0;          ldA = kSplit; }
        else             { Asrc = A1; kcol = k0 - kSplit; ldA = K - kSplit; }
        if (wv < 2) {
            int r = wv * 16 + lrow;
            int cgA = (lcg ^ swz(r)) << 3;
            GLOAD16(&Asrc[(m0 + r) * ldA + kcol + cgA], &As[buf][(wv * 16) * 32]);
        }
#pragma unroll
        for (int s = 0; s < 4; s++) {
            int r = s * 64 + wv * 16 + lrow;
            int cgB = (lcg ^ swz(r)) << 3;
            GLOAD16(&Wt[(size_t)r * K + k0 + cgB], &Bs[buf][(s * 64 + wv * 16) * 32]);
        }
    };

    int nt = K >> 5;
    stage(0, 0);
    WAIT_BAR();
    int cur = 0;
    for (int tt = 0; tt < nt; ++tt) {
        if (tt + 1 < nt) stage(cur ^ 1, (tt + 1) << 5);
        const ushort* Ab = &As[cur][0];
        const ushort* Bb = &Bs[cur][0];
        short8 af[2], bfr[4];
#pragma unroll
        for (int i = 0; i < 2; i++) {
            int rA = i * 16 + l16;
            af[i] = *(const short8*)&Ab[rA * 32 + ((quad ^ swz(rA)) << 3)];
        }
#pragma unroll
        for (int j = 0; j < 4; j++) {
            int rB = wv * 64 + j * 16 + l16;
            bfr[j] = *(const short8*)&Bb[rB * 32 + ((quad ^ swz(rB)) << 3)];
        }
#pragma unroll
        for (int i = 0; i < 2; i++)
#pragma unroll
            for (int j = 0; j < 4; j++)
                acc[i][j] = __builtin_amdgcn_mfma_f32_16x16x32_bf16(af[i], bfr[j], acc[i][j], 0, 0, 0);
        if (tt + 1 < nt) { WAIT_BAR(); cur ^= 1; }
    }
#pragma unroll
    for (int i = 0; i < 2; i++) {
#pragma unroll
        for (int r = 0; r < 4; r++) {
            float s = 0.f, q = 0.f;
#pragma unroll
            for (int j = 0; j < 4; j++) { float v = acc[i][j][r]; s += v; q += v * v; }
#pragma unroll
            for (int o = 8; o >= 1; o >>= 1) {
                s += __shfl_xor(s, o, 64);
                q += __shfl_xor(q, o, 64);
            }
            if (l16 == 0) {
                int row = i * 16 + quad * 4 + r;
                psum[wv][row] = s; psq[wv][row] = q;
            }
        }
    }
    __syncthreads();
    if (t < 32) {
        float s = psum[0][t] + psum[1][t] + psum[2][t] + psum[3][t];
        float q = psq[0][t] + psq[1][t] + psq[2][t] + psq[3][t];
        float mean = s * (1.0f / 256.0f);
        float var = q * (1.0f / 256.0f) - mean * mean;
        psum[0][t] = mean;
        psq[0][t] = rsqrtf(var + 1e-5f);
    }
    __syncthreads();
    int mvE = minfo[2 + side];
    const float* rcIn = rcInB ? rcInB + so : nullptr;
    float* rcOut = rcOutB ? rcOutB + so : nullptr;
    const int* glp = glB + side * CAP;
    float* outSc = outScB ? outScB + (long)side * 9830400L : nullptr;
    ushort* outB = outBB ? outBB + so : nullptr;
#pragma unroll
    for (int i = 0; i < 2; i++) {
#pragma unroll
        for (int r = 0; r < 4; r++) {
            int rloc = i * 16 + quad * 4 + r;
            long grow = m0 + rloc;
            float mean = psum[0][rloc], rstd = psq[0][rloc];
#pragma unroll
            for (int j = 0; j < 4; j++) {
                int col = wv * 64 + j * 16 + l16;
                float y = (acc[i][j][r] - mean) * rstd * gs[col] + bs[col];
                if (rcIn) y += rcIn[grow * 256 + col];
                if (rcOut) rcOut[grow * 256 + col] = y;
                if (outSc && grow < mvE) outSc[(long)glp[grow] * 256 + col] = y;
                if (outB) outB[grow * 256 + col] = f2b(y);
            }
        }
    }
}

// ---------------- per-class KV / Ksum reduction (compact, bf16 inputs) -------
__global__ __launch_bounds__(256) void lft_kv_kernel(
    const ushort* __restrict__ kcB, const ushort* __restrict__ vcB,
    const int* __restrict__ cmetaB,
    float* kvbB, float* ksbB, int sideSrc0)
{
    int side = sideSrc0 + (blockIdx.z >> 6);
    int zz = blockIdx.z & 63;
    int chunk = blockIdx.x, c = blockIdx.y;
    int b = zz >> 3, h = zz & 7;
    const int* cmeta = cmetaB + side * 128;
    int cstart = cmeta[(b * 8 + c) * 2], n = cmeta[(b * 8 + c) * 2 + 1];
    int per = (n + KV_NCH - 1) / KV_NCH;
    int s0 = chunk * per;
    int s1 = min(s0 + per, n);
    if (s0 >= s1) return;
    const ushort* phik = kcB + (long)side * CAP * 256;
    const ushort* vmat = vcB + (long)side * CAP * 256;
    float* kv = kvbB + (long)side * 524288;
    float* ksum = ksbB + (long)side * 16384;
    int t = threadIdx.x;
    __shared__ float kb[8][32];
    __shared__ float vb[8][32];
    int od = t >> 3, oe = (t & 7) << 2;
    int lt = t >> 5, ld = t & 31;
    float a0 = 0.f, a1 = 0.f, a2 = 0.f, a3 = 0.f, ak = 0.f;
    for (int s = s0; s < s1; s += 8) {
        float kval = 0.f, vval = 0.f;
        if (s + lt < s1) {
            long bse = (long)(cstart + s + lt) * 256 + h * 32 + ld;
            kval = b2f(phik[bse]);
            vval = b2f(vmat[bse]);
        }
        __syncthreads();
        kb[lt][ld] = kval;
        vb[lt][ld] = vval;
        __syncthreads();
#pragma unroll
        for (int j = 0; j < 8; j++) {
            float kd = kb[j][od];
            float4 vv = *(const float4*)&vb[j][oe];
            a0 += kd * vv.x; a1 += kd * vv.y; a2 += kd * vv.z; a3 += kd * vv.w;
            ak += kd;
        }
    }
    float* dst = kv + (((long)(b * NPROTO + c) * 8 + h) << 10) + od * 32 + oe;
    atomicAdd(dst + 0, a0);
    atomicAdd(dst + 1, a1);
    atomicAdd(dst + 2, a2);
    atomicAdd(dst + 3, a3);
    if ((t & 7) == 0)
        atomicAdd(ksum + (((long)(b * NPROTO + c) * 8 + h) << 5) + od, ak);
}

// ---------------- msg via MFMA over compact rows; kv fragments from fp32 -----
__global__ __launch_bounds__(256) void lft_msg_kernel(
    const ushort* __restrict__ qcB, const float* __restrict__ kvbB,
    const float* __restrict__ ksbB, const int* __restrict__ cmetaB,
    ushort* __restrict__ msgcB, int sideX0, int sideKV0)
{
    int add = blockIdx.z >> 3, b = blockIdx.z & 7;
    int sideX = sideX0 + add, sideKV = sideKV0 + add;
    int chunk = blockIdx.x, c = blockIdx.y;
    const int* cmeta = cmetaB + sideX * 128;
    int cstart = cmeta[(b * 8 + c) * 2], n = cmeta[(b * 8 + c) * 2 + 1];
    int per = (n + MSG_NCH - 1) / MSG_NCH;
    int s0 = chunk * per, s1 = min(s0 + per, n);
    if (s0 >= s1) return;
    const ushort* pq = qcB + (long)sideX * CAP * 256;
    ushort* msg = msgcB + (long)sideX * CAP * 256;
    int t = threadIdx.x;
    int wave = t >> 6, lane = t & 63;
    int l16 = lane & 15, quad = lane >> 4;
    int bc = b * 8 + c;
    short8 bfr[2][3];
#pragma unroll
    for (int hh = 0; hh < 2; hh++) {
        int h = wave * 2 + hh;
        const float* kvsrc = kvbB + (long)sideKV * 524288 + ((long)bc * 8 + h) * 1024;
        const float* kssrc = ksbB + (long)sideKV * 16384 + ((long)bc * 8 + h) * 32;
#pragma unroll
        for (int nt = 0; nt < 2; nt++)
#pragma unroll
            for (int j = 0; j < 8; j++)
                bfr[hh][nt][j] = (short)f2b(kvsrc[(quad * 8 + j) * 32 + nt * 16 + l16]);
#pragma unroll
        for (int j = 0; j < 8; j++)
            bfr[hh][2][j] = (l16 == 0) ? (short)f2b(kssrc[quad * 8 + j]) : (short)0;
    }
    for (int s = s0; s < s1; s += 16) {
        long rowA = cstart + min(s + l16, s1 - 1);
#pragma unroll
        for (int hh = 0; hh < 2; hh++) {
            int h = wave * 2 + hh;
            short8 a = *(const short8*)&pq[rowA * 256 + h * 32 + quad * 8];
            floatx4 n0 = {}, n1 = {}, dd = {};
            n0 = __builtin_amdgcn_mfma_f32_16x16x32_bf16(a, bfr[hh][0], n0, 0, 0, 0);
            n1 = __builtin_amdgcn_mfma_f32_16x16x32_bf16(a, bfr[hh][1], n1, 0, 0, 0);
            dd = __builtin_amdgcn_mfma_f32_16x16x32_bf16(a, bfr[hh][2], dd, 0, 0, 0);
#pragma unroll
            for (int r = 0; r < 4; r++) {
                int rowi = s + quad * 4 + r;
                float den = __shfl(dd[r], lane & 48, 64);
                float inv = 1.f / (den + 1e-6f);
                if (rowi < s1) {
                    long base = (long)(cstart + rowi) * 256 + h * 32;
                    msg[base + l16]      = f2b(n0[r] * inv);
                    msg[base + 16 + l16] = f2b(n1[r] * inv);
                }
            }
        }
    }
}

extern "C" void kernel_launch(void* const* d_in, const int* in_sizes, int n_in,
                              void* d_out, int out_size, void* d_ws, size_t ws_size,
                              hipStream_t stream)
{
    (void)in_sizes; (void)n_in; (void)out_size; (void)ws_size;
    const float* feat0 = (const float*)d_in[0];
    const float* feat1 = (const float*)d_in[1];
    const int*   mask0 = (const int*)d_in[2];
    const int*   mask1 = (const int*)d_in[3];
    const float* f0wo  = (const float*)d_in[4];
    const float* f1wo  = (const float*)d_in[5];
    const float* proto = (const float*)d_in[6];
    const float* Wq = (const float*)d_in[7];
    const float* Wk = (const float*)d_in[8];
    const float* Wv = (const float*)d_in[9];
    const float* Wm = (const float*)d_in[10];
    const float* W1 = (const float*)d_in[11];
    const float* W2 = (const float*)d_in[12];
    const float* g1 = (const float*)d_in[13];
    const float* b1 = (const float*)d_in[14];
    const float* g2 = (const float*)d_in[15];
    const float* b2 = (const float*)d_in[16];
    float* out = (float*)d_out;
    float* ws = (float*)d_ws;

    // ---- workspace layout (side-strided compact buffers, CAP rows/side) ----
    const long FSZ = 9830400L;
    float* rc = ws;                               // 2*CAP*256 f
    ushort* kc = (ushort*)(rc + 2 * CAP * 256);   // 2*CAP*256 us  bf16
    ushort* vc = kc + 2 * CAP * 256;              // 2*CAP*256 us  bf16
    ushort* hid = vc + 2 * CAP * 256;             // 2*CAP*512 us
    ushort* xc   = hid + 2 * CAP * 512;
    ushort* msgc = xc + 2 * CAP * 256;
    ushort* qc   = msgc + 2 * CAP * 256;
    ushort* wb   = qc + 2 * CAP * 256;
    ushort* wb1  = wb + 16 * 65536;
    ushort* wb2  = wb1 + 4 * 262144;
    float* kvb = (float*)(wb2 + 4 * 131072);      // 2*524288 f
    float* ksb = kvb + 2 * 524288;                // 2*16384 f
    int* cls0 = (int*)(ksb + 2 * 16384);
    int* cls1 = cls0 + 38400;
    int* gl   = cls1 + 38400;                     // 2*CAP ints
    int* meta = gl + 2 * CAP;
    int* minfo = meta + 256;
    int* cmeta = minfo + 20;

    lft_wconv_kernel<<<dim3(8, 8, 16), 256, 0, stream>>>(Wq, Wk, Wv, Wm, 256, 256, 4, wb);
    lft_wconv_kernel<<<dim3(16, 16, 4), 256, 0, stream>>>(W1, W1, W1, W1, 512, 512, 1, wb1);
    lft_wconv_kernel<<<dim3(16, 8, 4), 256, 0, stream>>>(W2, W2, W2, W2, 512, 256, 1, wb2);
    hipMemcpyAsync(out + 20352000L, proto, 2048 * 4, hipMemcpyDeviceToDevice, stream);
    lft_class_kernel<<<600, 256, 0, stream>>>(f0wo, f1wo, mask0, mask1, proto,
                                              out, cls0, cls1);
    lft_invcopy_kernel<<<1200, 256, 0, stream>>>(feat0, feat1, cls0, cls1, out);
    lft_count_kernel<<<16, 256, 0, stream>>>(cls0, cls1, meta);
    lft_scan_kernel<<<1, 256, 0, stream>>>(meta, minfo, cmeta);
    lft_place_kernel<<<16, 256, 0, stream>>>(cls0, cls1, cmeta, gl);
    lft_gcast_kernel<<<1200, 256, 0, stream>>>(feat0, feat1, gl, minfo, xc, rc);

    dim3 blk(256);
    for (int li = 0; li < 4; li++) {
        const ushort* wq = wb + (size_t)(li * 4 + 0) * 65536;   // [wq|wk|wv|wm]
        const ushort* wk = wb + (size_t)(li * 4 + 1) * 65536;
        const ushort* wm = wb + (size_t)(li * 4 + 3) * 65536;
        const ushort* w1 = wb1 + (size_t)li * 262144;
        const ushort* w2 = wb2 + (size_t)li * 131072;
        const float* g1p = g1 + li * 256; const float* b1p = b1 + li * 256;
        const float* g2p = g2 + li * 256; const float* b2p = b2 + li * 256;
        bool last = (li == 3);

        if ((li & 1) == 0) {
            // ---- self-self, both sides combined (z=2) ----
            lft_mfma_gemm<<<dim3(6, 192, 2), blk, 0, stream>>>(
                xc, xc, 256, wq, (float*)kc, qc, (float*)vc, 768, 256, 3, minfo, 0);
            hipMemsetAsync(kvb, 0, (2 * 524288 + 2 * 16384) * 4, stream);
            lft_kv_kernel<<<dim3(KV_NCH, 8, 128), blk, 0, stream>>>(kc, vc, cmeta, kvb, ksb, 0);
            lft_msg_kernel<<<dim3(MSG_NCH, 8, 16), blk, 0, stream>>>(qc, kvb, ksb, cmeta, msgc, 0, 0);
            lft_gemm_ln<<<dim3(768, 1, 2), blk, 0, stream>>>(
                msgc, msgc, 256, wm, 256, g1p, b1p,
                nullptr, nullptr, gl, minfo, nullptr, msgc, 0);
            lft_mfma_gemm<<<dim3(4, 192, 2), blk, 0, stream>>>(
                xc, msgc, 256, w1, nullptr, hid, nullptr, 512, 512, 2, minfo, 0);
            lft_gemm_ln<<<dim3(768, 1, 2), blk, 0, stream>>>(
                hid, hid, 512, w2, 512, g2p, b2p,
                rc, rc, gl, minfo, nullptr, xc, 0);
        } else {
            // ---- cross-self: q for both sides from OLD features ----
            lft_mfma_gemm<<<dim3(2, 192, 2), blk, 0, stream>>>(
                xc, xc, 256, wq, nullptr, qc, nullptr, 256, 256, 1, minfo, 0);
            // k|v from side1 (old) -> kc/vc side1
            lft_mfma_gemm<<<dim3(4, 192, 1), blk, 0, stream>>>(
                xc, xc, 256, wk, (float*)kc, nullptr, (float*)vc, 512, 256, 4, minfo, 1);
            hipMemsetAsync(kvb, 0, (2 * 524288 + 2 * 16384) * 4, stream);
            lft_kv_kernel<<<dim3(KV_NCH, 8, 64), blk, 0, stream>>>(kc, vc, cmeta, kvb, ksb, 1);
            lft_msg_kernel<<<dim3(MSG_NCH, 8, 8), blk, 0, stream>>>(qc, kvb, ksb, cmeta, msgc, 0, 1);
            lft_gemm_ln<<<dim3(768, 1, 1), blk, 0, stream>>>(
                msgc, msgc, 256, wm, 256, g1p, b1p,
                nullptr, nullptr, gl, minfo, nullptr, msgc, 0);
            lft_mfma_gemm<<<dim3(4, 192, 1), blk, 0, stream>>>(
                xc, msgc, 256, w1, nullptr, hid, nullptr, 512, 512, 2, minfo, 0);
            lft_gemm_ln<<<dim3(768, 1, 1), blk, 0, stream>>>(
                hid, hid, 512, w2, 512, g2p, b2p,
                rc, last ? nullptr : rc, gl, minfo, last ? out : nullptr, xc, 0);
            // ---- side1 attends UPDATED side0 ----
            lft_mfma_gemm<<<dim3(4, 192, 1), blk, 0, stream>>>(
                xc, xc, 256, wk, (float*)kc, nullptr, (float*)vc, 512, 256, 4, minfo, 0);
            hipMemsetAsync(kvb, 0, (2 * 524288 + 2 * 16384) * 4, stream);
            lft_kv_kernel<<<dim3(KV_NCH, 8, 64), blk, 0, stream>>>(kc, vc, cmeta, kvb, ksb, 0);
            lft_msg_kernel<<<dim3(MSG_NCH, 8, 8), blk, 0, stream>>>(qc, kvb, ksb, cmeta, msgc, 1, 0);
            lft_gemm_ln<<<dim3(768, 1, 1), blk, 0, stream>>>(
                msgc, msgc, 256, wm, 256, g1p, b1p,
                nullptr, nullptr, gl, minfo, nullptr, msgc, 1);
            lft_mfma_gemm<<<dim3(4, 192, 1), blk, 0, stream>>>(
                xc, msgc, 256, w1, nullptr, hid, nullptr, 512, 512, 2, minfo, 1);
            lft_gemm_ln<<<dim3(768, 1, 1), blk, 0, stream>>>(
                hid, hid, 512, w2, 512, g2p, b2p,
                rc, last ? nullptr : rc, gl, minfo, last ? out : nullptr,
                last ? nullptr : xc, 1);
        }
    }
}

// Round 14
// 1382.667 us; speedup vs baseline: 1.1924x; 1.0473x over previous
//
#include <hip/hip_runtime.h>
#include <math.h>

#define NPROTO 8
#define KV_NCH 4
#define MSG_NCH 8
#define CAP 24576L            // compact rows per side (Mv ~= 19200 +- ~200)

typedef __attribute__((ext_vector_type(8))) short short8;
typedef __attribute__((ext_vector_type(4))) float floatx4;

static __device__ __forceinline__ ushort f2b(float f) {
    unsigned u = __builtin_bit_cast(unsigned, f);
    unsigned r = (u + 0x7fffu + ((u >> 16) & 1u)) >> 16;
    return (ushort)r;
}

static __device__ __forceinline__ float b2f(ushort u) {
    return __builtin_bit_cast(float, (unsigned)u << 16);
}

static __device__ __forceinline__ float elu1(float v) {
    return v > 0.f ? v + 1.f : __expf(v);
}

// async 16B global -> LDS (linear dest: wave base + lane*16B)
#define GLOAD16(gp, lp) __builtin_amdgcn_global_load_lds( \
    (const __attribute__((address_space(1))) void*)(gp),  \
    (__attribute__((address_space(3))) void*)(lp), 16, 0, 0)

// full drain + barrier (gemm_ln's proven 2-phase structure)
#define WAIT_BAR() asm volatile("s_waitcnt vmcnt(0) lgkmcnt(0)\n\ts_barrier" ::: "memory")
// counted waits (mfma_gemm 3-buffer pipeline; 4 loads/thread/tile)
#define VMWAIT(N) asm volatile("s_waitcnt vmcnt(" #N ")" ::: "memory")
#define BAR() __builtin_amdgcn_s_barrier()

// swizzle of the 16B-group index within a 32-col bf16 row (4 groups/row)
static __device__ __forceinline__ int swz(int r) { return (r >> 1) & 3; }

// ---------------- prototype projection / argmax-class kernel ----------------
__global__ __launch_bounds__(256) void lft_class_kernel(
    const float* __restrict__ f0wo, const float* __restrict__ f1wo,
    const int* __restrict__ mask0, const int* __restrict__ mask1,
    const float* __restrict__ proto,
    float* out, int* cls0, int* cls1)
{
    __shared__ float pr[2048];          // proto [8][256]
    __shared__ float tile[128][68];     // [token][ch chunk], stride 68
    __shared__ float sm[128][8];
    int t = threadIdx.x;
    *(float4*)&pr[t * 4]        = *(const float4*)&proto[t * 4];
    *(float4*)&pr[1024 + t * 4] = *(const float4*)&proto[1024 + t * 4];
    long tok0 = (long)blockIdx.x * 128;
    const float* fsrc; const int* msrc; float* fpout; float* clsout; int* clsarr; long tbase;
    if (tok0 < 38400) {
        tbase = tok0; fsrc = f0wo; msrc = mask0;
        fpout = out + 19737600L; clsout = out + 19660800L; clsarr = cls0;
    } else {
        tbase = tok0 - 38400; fsrc = f1wo; msrc = mask1;
        fpout = out + 20044800L; clsout = out + 19699200L; clsarr = cls1;
    }
    int tok = t & 127, half = t >> 7;
    float s[4] = {};
    int r0 = t >> 4;            // 0..15
    int c4 = (t & 15) << 2;     // 0..60
    for (int ct = 0; ct < 4; ct++) {
        __syncthreads();
#pragma unroll
        for (int rr = 0; rr < 8; rr++) {
            int row = rr * 16 + r0;
            float4 v = *(const float4*)&fsrc[(tbase + row) * 256 + ct * 64 + c4];
            *(float4*)&tile[row][c4] = v;
        }
        __syncthreads();
#pragma unroll
        for (int cc = 0; cc < 16; cc++) {
            float4 f = *(const float4*)&tile[tok][cc << 2];
#pragma unroll
            for (int p = 0; p < 4; p++) {
                float4 pv = *(const float4*)&pr[(half * 4 + p) * 256 + ct * 64 + (cc << 2)];
                s[p] += f.x * pv.x + f.y * pv.y + f.z * pv.z + f.w * pv.w;
            }
        }
    }
#pragma unroll
    for (int p = 0; p < 4; p++) {
        fpout[(tbase + tok) * 8 + half * 4 + p] = s[p];
        sm[tok][half * 4 + p] = s[p];
    }
    __syncthreads();
    if (t < 128) {
        int best = 0; float bv = sm[t][0];
#pragma unroll
        for (int p = 1; p < 8; p++) { if (sm[t][p] > bv) { bv = sm[t][p]; best = p; } }
        clsout[tbase + t] = (float)best;
        clsarr[tbase + t] = msrc[tbase + t] ? best : -1;
    }
}

// ---------------- copy ONLY invalid-token rows of feat into out --------------
__global__ __launch_bounds__(256) void lft_invcopy_kernel(
    const float* __restrict__ f0, const float* __restrict__ f1,
    const int* __restrict__ cls0, const int* __restrict__ cls1,
    float* out)
{
    int w = blockIdx.x * 4 + (threadIdx.x >> 6);   // 0..4799
    int lane = threadIdx.x & 63;
    for (long row = w; row < 76800; row += 4800) {
        int side = row >= 38400;
        long r = row - (long)side * 38400;
        int c = side ? cls1[r] : cls0[r];
        if (c < 0) {
            const float* src = side ? f1 : f0;
            float4 v = *(const float4*)&src[r * 256 + lane * 4];
            *(float4*)&out[(long)side * 9830400L + r * 256 + lane * 4] = v;
        }
    }
}

// ---------------- per-(L,b) class counts -> meta {base,cnt} ------------------
__global__ __launch_bounds__(256) void lft_count_kernel(
    const int* __restrict__ cls0, const int* __restrict__ cls1, int* meta)
{
    int g = blockIdx.x; int L = g >> 3, b = g & 7;
    const int* cls = (L ? cls1 : cls0) + b * 4800;
    int* mt = meta + (L * 8 + b) * 16;
    __shared__ int cnt[8];
    int t = threadIdx.x;
    if (t < 8) cnt[t] = 0;
    __syncthreads();
    for (int tok = t; tok < 4800; tok += 256) {
        int c = cls[tok];
        if (c >= 0) atomicAdd(&cnt[c], 1);
    }
    __syncthreads();
    if (t == 0) {
        int s = 0;
        for (int c = 0; c < 8; c++) { mt[c * 2] = s; mt[c * 2 + 1] = cnt[c]; s += cnt[c]; }
    }
}

// ---------------- cross-batch scan: minfo (Mv, boff) + compact cmeta ---------
__global__ __launch_bounds__(256) void lft_scan_kernel(
    const int* __restrict__ meta, int* minfo, int* cmeta)
{
    int t = threadIdx.x;
    __shared__ int nb[16];
    if (t < 16) {
        int s = 0;
        for (int c = 0; c < 8; c++) s += meta[t * 16 + c * 2 + 1];
        nb[t] = s;
    }
    __syncthreads();
    if (t == 0) {
        int off = 0;
        for (int b = 0; b < 8; b++) { minfo[4 + b] = off; off += nb[b]; }
        minfo[2] = off; minfo[0] = (off + 127) & ~127;
        off = 0;
        for (int b = 0; b < 8; b++) { minfo[12 + b] = off; off += nb[8 + b]; }
        minfo[3] = off; minfo[1] = (off + 127) & ~127;
    }
    __syncthreads();
    if (t < 128) {
        int L = t >> 6, b = (t >> 3) & 7, c = t & 7;
        cmeta[t * 2]     = minfo[4 + L * 8 + b] + meta[(L * 8 + b) * 16 + c * 2];
        cmeta[t * 2 + 1] = meta[(L * 8 + b) * 16 + c * 2 + 1];
    }
}

// ---------------- place valid tokens into compact gather lists ---------------
__global__ __launch_bounds__(256) void lft_place_kernel(
    const int* __restrict__ cls0, const int* __restrict__ cls1,
    const int* __restrict__ cmeta, int* gl)
{
    int g = blockIdx.x; int L = g >> 3, b = g & 7;
    const int* cls = (L ? cls1 : cls0) + b * 4800;
    int* glp = gl + L * CAP;
    __shared__ int pos[8];
    int t = threadIdx.x;
    if (t < 8) pos[t] = cmeta[(L * 64 + b * 8 + t) * 2];
    __syncthreads();
    for (int tok = t; tok < 4800; tok += 256) {
        int c = cls[tok];
        if (c >= 0) { int p = atomicAdd(&pos[c], 1); glp[p] = b * 4800 + tok; }
    }
}

// ---------------- gather-cast: compact bf16 x + compact fp32 resid -----------
__global__ __launch_bounds__(256) void lft_gcast_kernel(
    const float* __restrict__ f0, const float* __restrict__ f1,
    const int* __restrict__ gl, const int* __restrict__ minfo,
    ushort* xc, float* rc)
{
    int blk = blockIdx.x;
    int side = blk >= 600 ? 1 : 0;
    int i0 = (blk - side * 600) * 4 + (threadIdx.x >> 6);
    int mv = minfo[2 + side];
    const int* glp = gl + side * CAP;
    const float* f = side ? f1 : f0;
    ushort* xcp = xc + side * CAP * 256;
    float* rcp = rc + side * CAP * 256;
    int lane = threadIdx.x & 63;
    for (int i = i0; i < mv; i += 2400) {
        long src = (long)glp[i] * 256 + lane * 4;
        float4 v = *(const float4*)&f[src];
        long dst = (long)i * 256 + lane * 4;
        *(float4*)&rcp[dst] = v;
        ushort4 u; u.x = f2b(v.x); u.y = f2b(v.y); u.z = f2b(v.z); u.w = f2b(v.w);
        *(ushort4*)&xcp[dst] = u;
    }
}

// ---------------- weight convert + transpose: Wt[n*K+k] = bf16(W[k*N+n]) ----
__global__ __launch_bounds__(256) void lft_wconv_kernel(
    const float* W0, const float* W1p, const float* W2p, const float* W3p,
    int K, int N, int nTypes, ushort* dst)
{
    int z = blockIdx.z;
    int li = z / nTypes, mi = z % nTypes;
    const float* srcs[4] = {W0, W1p, W2p, W3p};
    const float* src = srcs[mi] + (size_t)li * K * N;
    ushort* outp = dst + (size_t)z * K * N;
    __shared__ float tile[32][33];
    int k0 = blockIdx.x * 32, n0 = blockIdx.y * 32;
    int t = threadIdx.x;
    int r = t >> 3, c4 = (t & 7) << 2;
    float4 v = *(const float4*)&src[(size_t)(k0 + r) * N + n0 + c4];
    tile[r][c4] = v.x; tile[r][c4 + 1] = v.y; tile[r][c4 + 2] = v.z; tile[r][c4 + 3] = v.w;
    __syncthreads();
    ushort4 o;
    o.x = f2b(tile[c4 + 0][r]);
    o.y = f2b(tile[c4 + 1][r]);
    o.z = f2b(tile[c4 + 2][r]);
    o.w = f2b(tile[c4 + 3][r]);
    *(ushort4*)&outp[(size_t)(n0 + r) * K + k0 + c4] = o;
}

// ---------------- bf16 MFMA GEMM over COMPACT rows ---------------------------
// XCD-aware block swizzle (T1): wid = (orig&7)*(G/8) + orig>>3 gives each XCD
// a contiguous chunk of the grid = complete m-tiles (all n-blocks sharing an
// A-panel on ONE per-XCD L2; panel ~3.1MB + B fits 4MB L2). Requires G%8==0.
// 3-buffer counted-vmcnt pipeline. 128x128 tile, 4 waves, LDS 48KB.
// act: 0 none, 1 elu+1, 2 relu; act 3 qkv N=768 (q/k/v bf16);
// act 4 kv N=512 (k/v bf16). k,v buffers are ushort (passed via Cf/Cv).
__global__ __launch_bounds__(256) void lft_mfma_gemm(
    const ushort* __restrict__ A0b, const ushort* __restrict__ A1b, int kSplit,
    const ushort* __restrict__ Wt,
    float* Cf, ushort* Cb, float* Cv, int N, int K, int act,
    const int* __restrict__ minfo, int side0)
{
    __shared__ ushort As[3][128 * 32];
    __shared__ ushort Bs[3][128 * 32];
    int gx = gridDim.x, gy = gridDim.y;
    int G = gx * gy * gridDim.z;
    int orig = (blockIdx.z * gy + blockIdx.y) * gx + blockIdx.x;
    int wid = ((orig & 7) * (G >> 3)) + (orig >> 3);   // G % 8 == 0 (all grids)
    int bx = wid % gx; int rest = wid / gx;
    int by = rest % gy; int bz = rest / gy;
    int side = side0 + bz;
    int m0 = by << 7;
    if (m0 >= minfo[side]) return;
    int n0 = bx << 7;
    const ushort* A0 = A0b + (long)side * CAP * kSplit;
    const ushort* A1 = A1b + (long)side * CAP * (K - kSplit);
    long so256 = (long)side * CAP * 256;
    long soN = (long)side * CAP * N;
    int t = threadIdx.x;
    int wv = t >> 6, lane = t & 63;
    int wm = wv >> 1, wn = wv & 1;
    int l16 = lane & 15, quad = lane >> 4;
    floatx4 acc[4][4] = {};

    int lrow = lane >> 2;
    int lcg = lane & 3;

    auto stage = [&](int buf, int k0) {
        const ushort* Asrc; int kcol, ldA;
        if (k0 < kSplit) { Asrc = A0; kcol = k0;          ldA = kSplit; }
        else             { Asrc = A1; kcol = k0 - kSplit; ldA = K - kSplit; }
        ushort* Ab = &As[buf][0];
        ushort* Bb = &Bs[buf][0];
#pragma unroll
        for (int s = 0; s < 2; s++) {
            int r = s * 64 + wv * 16 + lrow;
            int cgA = (lcg ^ swz(r)) << 3;
            GLOAD16(&Asrc[(size_t)(m0 + r) * ldA + kcol + cgA], &Ab[(s * 64 + wv * 16) * 32]);
            GLOAD16(&Wt[(size_t)(n0 + r) * K + k0 + cgA], &Bb[(s * 64 + wv * 16) * 32]);
        }
    };

    auto compute = [&](int buf) {
        const ushort* Ab = &As[buf][0];
        const ushort* Bb = &Bs[buf][0];
        short8 af[4], bfr[4];
#pragma unroll
        for (int i = 0; i < 4; i++) {
            int rA = wm * 64 + i * 16 + l16;
            int rB = wn * 64 + i * 16 + l16;
            af[i]  = *(const short8*)&Ab[rA * 32 + ((quad ^ swz(rA)) << 3)];
            bfr[i] = *(const short8*)&Bb[rB * 32 + ((quad ^ swz(rB)) << 3)];
        }
        __builtin_amdgcn_s_setprio(1);
#pragma unroll
        for (int i = 0; i < 4; i++)
#pragma unroll
            for (int j = 0; j < 4; j++)
                acc[i][j] = __builtin_amdgcn_mfma_f32_16x16x32_bf16(af[i], bfr[j], acc[i][j], 0, 0, 0);
        __builtin_amdgcn_s_setprio(0);
    };

    int nt = K >> 5;               // 8 or 16
    stage(0, 0);
    stage(1, 32);
    int cur = 0;
    for (int tt = 0; tt < nt; ++tt) {
        if (tt + 2 < nt) {
            int nb = cur + 2; if (nb >= 3) nb -= 3;
            stage(nb, (tt + 2) << 5);
            VMWAIT(8);             // tile tt done; tt+1, tt+2 in flight
        } else if (tt + 2 == nt) {
            VMWAIT(4);
        } else {
            VMWAIT(0);
        }
        BAR();
        compute(cur);
        if (tt + 1 < nt) BAR();
        cur = cur + 1 == 3 ? 0 : cur + 1;
    }

#pragma unroll
    for (int i = 0; i < 4; i++) {
#pragma unroll
        for (int j = 0; j < 4; j++) {
#pragma unroll
            for (int r = 0; r < 4; r++) {
                float v = acc[i][j][r];
                long row = m0 + wm * 64 + i * 16 + quad * 4 + r;
                int col = n0 + wn * 64 + j * 16 + l16;
                if (act == 3) {
                    if (col < 256)      Cb[so256 + row * 256 + col] = f2b(elu1(v));
                    else if (col < 512) ((ushort*)Cf)[so256 + row * 256 + col - 256] = f2b(elu1(v));
                    else                ((ushort*)Cv)[so256 + row * 256 + col - 512] = f2b(v);
                } else if (act == 4) {
                    if (col < 256) ((ushort*)Cf)[so256 + row * 256 + col] = f2b(elu1(v));
                    else           ((ushort*)Cv)[so256 + row * 256 + col - 256] = f2b(v);
                } else {
                    if (act == 1)      v = elu1(v);
                    else if (act == 2) v = fmaxf(v, 0.f);
                    if (Cf) Cf[soN + row * N + col] = v;
                    if (Cb) Cb[soN + row * N + col] = f2b(v);
                }
            }
        }
    }
}

// ---------------- fused GEMM (N=256) + row-LN over COMPACT rows -------------
// M=32 tile (grid.x=768 per side, early-exit); side = side0 + blockIdx.z.
// Proven 2-phase drain pipeline (unchanged).
__global__ __launch_bounds__(256) void lft_gemm_ln(
    const ushort* __restrict__ A0b, const ushort* __restrict__ A1b, int kSplit,
    const ushort* __restrict__ Wt, int K,
    const float* __restrict__ g, const float* __restrict__ bb,
    const float* __restrict__ rcInB, float* rcOutB,
    const int* __restrict__ glB, const int* __restrict__ minfo,
    float* outScB, ushort* __restrict__ outBB, int side0)
{
    __shared__ ushort As[2][32 * 32];
    __shared__ ushort Bs[2][256 * 32];
    __shared__ float gs[256], bs[256];
    __shared__ float psum[4][32], psq[4][32];
    int side = side0 + blockIdx.z;
    long m0 = (long)blockIdx.x << 5;
    if (m0 >= minfo[side]) return;
    const ushort* A0 = A0b + (long)side * CAP * kSplit;
    const ushort* A1 = A1b + (long)side * CAP * (K - kSplit);
    long so = (long)side * CAP * 256;
    int t = threadIdx.x;
    int wv = t >> 6, lane = t & 63;
    int l16 = lane & 15, quad = lane >> 4;
    gs[t] = g[t]; bs[t] = bb[t];
    floatx4 acc[2][4] = {};

    int lrow = lane >> 2;
    int lcg = lane & 3;

    auto stage = [&](int buf, int k0) {
        const ushort* Asrc; int kcol, ldA;
        if (k0 < kSplit) { Asrc = A0; kcol = k0;          ldA = kSplit; }
        else             { Asrc = A1; kcol = k0 - kSplit; ldA = K - kSplit; }
        if (wv < 2) {
            int r = wv * 16 + lrow;
            int cgA = (lcg ^ swz(r)) << 3;
            GLOAD16(&Asrc[(m0 + r) * ldA + kcol + cgA], &As[buf][(wv * 16) * 32]);
        }
#pragma unroll
        for (int s = 0; s < 4; s++) {
            int r = s * 64 + wv * 16 + lrow;
            int cgB = (lcg ^ swz(r)) << 3;
            GLOAD16(&Wt[(size_t)r * K + k0 + cgB], &Bs[buf][(s * 64 + wv * 16) * 32]);
        }
    };

    int nt = K >> 5;
    stage(0, 0);
    WAIT_BAR();
    int cur = 0;
    for (int tt = 0; tt < nt; ++tt) {
        if (tt + 1 < nt) stage(cur ^ 1, (tt + 1) << 5);
        const ushort* Ab = &As[cur][0];
        const ushort* Bb = &Bs[cur][0];
        short8 af[2], bfr[4];
#pragma unroll
        for (int i = 0; i < 2; i++) {
            int rA = i * 16 + l16;
            af[i] = *(const short8*)&Ab[rA * 32 + ((quad ^ swz(rA)) << 3)];
        }
#pragma unroll
        for (int j = 0; j < 4; j++) {
            int rB = wv * 64 + j * 16 + l16;
            bfr[j] = *(const short8*)&Bb[rB * 32 + ((quad ^ swz(rB)) << 3)];
        }
#pragma unroll
        for (int i = 0; i < 2; i++)
#pragma unroll
            for (int j = 0; j < 4; j++)
                acc[i][j] = __builtin_amdgcn_mfma_f32_16x16x32_bf16(af[i], bfr[j], acc[i][j], 0, 0, 0);
        if (tt + 1 < nt) { WAIT_BAR(); cur ^= 1; }
    }
#pragma unroll
    for (int i = 0; i < 2; i++) {
#pragma unroll
        for (int r = 0; r < 4; r++) {
            float s = 0.f, q = 0.f;
#pragma unroll
            for (int j = 0; j < 4; j++) { float v = acc[i][j][r]; s += v; q += v * v; }
#pragma unroll
            for (int o = 8; o >= 1; o >>= 1) {
                s += __shfl_xor(s, o, 64);
                q += __shfl_xor(q, o, 64);
            }
            if (l16 == 0) {
                int row = i * 16 + quad * 4 + r;
                psum[wv][row] = s; psq[wv][row] = q;
            }
        }
    }
    __syncthreads();
    if (t < 32) {
        float s = psum[0][t] + psum[1][t] + psum[2][t] + psum[3][t];
        float q = psq[0][t] + psq[1][t] + psq[2][t] + psq[3][t];
        float mean = s * (1.0f / 256.0f);
        float var = q * (1.0f / 256.0f) - mean * mean;
        psum[0][t] = mean;
        psq[0][t] = rsqrtf(var + 1e-5f);
    }
    __syncthreads();
    int mvE = minfo[2 + side];
    const float* rcIn = rcInB ? rcInB + so : nullptr;
    float* rcOut = rcOutB ? rcOutB + so : nullptr;
    const int* glp = glB + side * CAP;
    float* outSc = outScB ? outScB + (long)side * 9830400L : nullptr;
    ushort* outB = outBB ? outBB + so : nullptr;
#pragma unroll
    for (int i = 0; i < 2; i++) {
#pragma unroll
        for (int r = 0; r < 4; r++) {
            int rloc = i * 16 + quad * 4 + r;
            long grow = m0 + rloc;
            float mean = psum[0][rloc], rstd = psq[0][rloc];
#pragma unroll
            for (int j = 0; j < 4; j++) {
                int col = wv * 64 + j * 16 + l16;
                float y = (acc[i][j][r] - mean) * rstd * gs[col] + bs[col];
                if (rcIn) y += rcIn[grow * 256 + col];
                if (rcOut) rcOut[grow * 256 + col] = y;
                if (outSc && grow < mvE) outSc[(long)glp[grow] * 256 + col] = y;
                if (outB) outB[grow * 256 + col] = f2b(y);
            }
        }
    }
}

// ---------------- per-class KV / Ksum reduction (compact, bf16 inputs) -------
// Per-chunk private slots (plain stores, no memset/atomics): slot index
// (side*KV_NCH + chunk). Chunks with no work store zeros.
__global__ __launch_bounds__(256) void lft_kv_kernel(
    const ushort* __restrict__ kcB, const ushort* __restrict__ vcB,
    const int* __restrict__ cmetaB,
    float* kvbB, float* ksbB, int sideSrc0)
{
    int side = sideSrc0 + (blockIdx.z >> 6);
    int zz = blockIdx.z & 63;
    int chunk = blockIdx.x, c = blockIdx.y;
    int b = zz >> 3, h = zz & 7;
    const int* cmeta = cmetaB + side * 128;
    int cstart = cmeta[(b * 8 + c) * 2], n = cmeta[(b * 8 + c) * 2 + 1];
    int per = (n + KV_NCH - 1) / KV_NCH;
    int s0 = chunk * per;
    int s1 = min(s0 + per, n);
    const ushort* phik = kcB + (long)side * CAP * 256;
    const ushort* vmat = vcB + (long)side * CAP * 256;
    int slot = side * KV_NCH + chunk;
    float* kv = kvbB + (long)slot * 524288;
    float* ksum = ksbB + (long)slot * 16384;
    int t = threadIdx.x;
    __shared__ float kb[8][32];
    __shared__ float vb[8][32];
    int od = t >> 3, oe = (t & 7) << 2;
    int lt = t >> 5, ld = t & 31;
    float a0 = 0.f, a1 = 0.f, a2 = 0.f, a3 = 0.f, ak = 0.f;
    for (int s = s0; s < s1; s += 8) {
        float kval = 0.f, vval = 0.f;
        if (s + lt < s1) {
            long bse = (long)(cstart + s + lt) * 256 + h * 32 + ld;
            kval = b2f(phik[bse]);
            vval = b2f(vmat[bse]);
        }
        __syncthreads();
        kb[lt][ld] = kval;
        vb[lt][ld] = vval;
        __syncthreads();
#pragma unroll
        for (int j = 0; j < 8; j++) {
            float kd = kb[j][od];
            float4 vv = *(const float4*)&vb[j][oe];
            a0 += kd * vv.x; a1 += kd * vv.y; a2 += kd * vv.z; a3 += kd * vv.w;
            ak += kd;
        }
    }
    float* dst = kv + (((long)(b * NPROTO + c) * 8 + h) << 10) + od * 32 + oe;
    dst[0] = a0; dst[1] = a1; dst[2] = a2; dst[3] = a3;
    if ((t & 7) == 0)
        ksum[(((long)(b * NPROTO + c) * 8 + h) << 5) + od] = ak;
}

// ---------------- msg via MFMA; kv fragments = sum of KV_NCH chunk slots -----
__global__ __launch_bounds__(256) void lft_msg_kernel(
    const ushort* __restrict__ qcB, const float* __restrict__ kvbB,
    const float* __restrict__ ksbB, const int* __restrict__ cmetaB,
    ushort* __restrict__ msgcB, int sideX0, int sideKV0)
{
    int add = blockIdx.z >> 3, b = blockIdx.z & 7;
    int sideX = sideX0 + add, sideKV = sideKV0 + add;
    int chunk = blockIdx.x, c = blockIdx.y;
    const int* cmeta = cmetaB + sideX * 128;
    int cstart = cmeta[(b * 8 + c) * 2], n = cmeta[(b * 8 + c) * 2 + 1];
    int per = (n + MSG_NCH - 1) / MSG_NCH;
    int s0 = chunk * per, s1 = min(s0 + per, n);
    if (s0 >= s1) return;
    const ushort* pq = qcB + (long)sideX * CAP * 256;
    ushort* msg = msgcB + (long)sideX * CAP * 256;
    int t = threadIdx.x;
    int wave = t >> 6, lane = t & 63;
    int l16 = lane & 15, quad = lane >> 4;
    int bc = b * 8 + c;
    short8 bfr[2][3];
#pragma unroll
    for (int hh = 0; hh < 2; hh++) {
        int h = wave * 2 + hh;
        long kvoff = ((long)bc * 8 + h) * 1024;
        long ksoff = ((long)bc * 8 + h) * 32;
#pragma unroll
        for (int nt = 0; nt < 2; nt++)
#pragma unroll
            for (int j = 0; j < 8; j++) {
                float v = 0.f;
#pragma unroll
                for (int ch = 0; ch < KV_NCH; ch++)
                    v += kvbB[(long)(sideKV * KV_NCH + ch) * 524288 + kvoff
                              + (quad * 8 + j) * 32 + nt * 16 + l16];
                bfr[hh][nt][j] = (short)f2b(v);
            }
#pragma unroll
        for (int j = 0; j < 8; j++) {
            float v = 0.f;
#pragma unroll
            for (int ch = 0; ch < KV_NCH; ch++)
                v += ksbB[(long)(sideKV * KV_NCH + ch) * 16384 + ksoff + quad * 8 + j];
            bfr[hh][2][j] = (l16 == 0) ? (short)f2b(v) : (short)0;
        }
    }
    for (int s = s0; s < s1; s += 16) {
        long rowA = cstart + min(s + l16, s1 - 1);
#pragma unroll
        for (int hh = 0; hh < 2; hh++) {
            int h = wave * 2 + hh;
            short8 a = *(const short8*)&pq[rowA * 256 + h * 32 + quad * 8];
            floatx4 n0 = {}, n1 = {}, dd = {};
            n0 = __builtin_amdgcn_mfma_f32_16x16x32_bf16(a, bfr[hh][0], n0, 0, 0, 0);
            n1 = __builtin_amdgcn_mfma_f32_16x16x32_bf16(a, bfr[hh][1], n1, 0, 0, 0);
            dd = __builtin_amdgcn_mfma_f32_16x16x32_bf16(a, bfr[hh][2], dd, 0, 0, 0);
#pragma unroll
            for (int r = 0; r < 4; r++) {
                int rowi = s + quad * 4 + r;
                float den = __shfl(dd[r], lane & 48, 64);
                float inv = 1.f / (den + 1e-6f);
                if (rowi < s1) {
                    long base = (long)(cstart + rowi) * 256 + h * 32;
                    msg[base + l16]      = f2b(n0[r] * inv);
                    msg[base + 16 + l16] = f2b(n1[r] * inv);
                }
            }
        }
    }
}

extern "C" void kernel_launch(void* const* d_in, const int* in_sizes, int n_in,
                              void* d_out, int out_size, void* d_ws, size_t ws_size,
                              hipStream_t stream)
{
    (void)in_sizes; (void)n_in; (void)out_size; (void)ws_size;
    const float* feat0 = (const float*)d_in[0];
    const float* feat1 = (const float*)d_in[1];
    const int*   mask0 = (const int*)d_in[2];
    const int*   mask1 = (const int*)d_in[3];
    const float* f0wo  = (const float*)d_in[4];
    const float* f1wo  = (const float*)d_in[5];
    const float* proto = (const float*)d_in[6];
    const float* Wq = (const float*)d_in[7];
    const float* Wk = (const float*)d_in[8];
    const float* Wv = (const float*)d_in[9];
    const float* Wm = (const float*)d_in[10];
    const float* W1 = (const float*)d_in[11];
    const float* W2 = (const float*)d_in[12];
    const float* g1 = (const float*)d_in[13];
    const float* b1 = (const float*)d_in[14];
    const float* g2 = (const float*)d_in[15];
    const float* b2 = (const float*)d_in[16];
    float* out = (float*)d_out;
    float* ws = (float*)d_ws;

    // ---- workspace layout (side-strided compact buffers, CAP rows/side) ----
    const long FSZ = 9830400L;
    float* rc = ws;                               // 2*CAP*256 f
    ushort* kc = (ushort*)(rc + 2 * CAP * 256);   // 2*CAP*256 us  bf16
    ushort* vc = kc + 2 * CAP * 256;              // 2*CAP*256 us  bf16
    ushort* hid = vc + 2 * CAP * 256;             // 2*CAP*512 us
    ushort* xc   = hid + 2 * CAP * 512;
    ushort* msgc = xc + 2 * CAP * 256;
    ushort* qc   = msgc + 2 * CAP * 256;
    ushort* wb   = qc + 2 * CAP * 256;
    ushort* wb1  = wb + 16 * 65536;
    ushort* wb2  = wb1 + 4 * 262144;
    float* ksb = (float*)(wb2 + 4 * 131072);      // 2*KV_NCH*16384 f
    int* cls0 = (int*)(ksb + 2 * KV_NCH * 16384);
    int* cls1 = cls0 + 38400;
    int* gl   = cls1 + 38400;                     // 2*CAP ints
    int* meta = gl + 2 * CAP;
    int* minfo = meta + 256;
    int* cmeta = minfo + 20;
    // kvb aliases hid (dead between kv_kernel and w1-GEMM): 2*KV_NCH*524288 f
    // = 16.8MB < hid's 50.3MB; hid[side1] region (offset 25.2MB) untouched.
    float* kvb = (float*)hid;

    lft_wconv_kernel<<<dim3(8, 8, 16), 256, 0, stream>>>(Wq, Wk, Wv, Wm, 256, 256, 4, wb);
    lft_wconv_kernel<<<dim3(16, 16, 4), 256, 0, stream>>>(W1, W1, W1, W1, 512, 512, 1, wb1);
    lft_wconv_kernel<<<dim3(16, 8, 4), 256, 0, stream>>>(W2, W2, W2, W2, 512, 256, 1, wb2);
    hipMemcpyAsync(out + 20352000L, proto, 2048 * 4, hipMemcpyDeviceToDevice, stream);
    lft_class_kernel<<<600, 256, 0, stream>>>(f0wo, f1wo, mask0, mask1, proto,
                                              out, cls0, cls1);
    lft_invcopy_kernel<<<1200, 256, 0, stream>>>(feat0, feat1, cls0, cls1, out);
    lft_count_kernel<<<16, 256, 0, stream>>>(cls0, cls1, meta);
    lft_scan_kernel<<<1, 256, 0, stream>>>(meta, minfo, cmeta);
    lft_place_kernel<<<16, 256, 0, stream>>>(cls0, cls1, cmeta, gl);
    lft_gcast_kernel<<<1200, 256, 0, stream>>>(feat0, feat1, gl, minfo, xc, rc);

    dim3 blk(256);
    for (int li = 0; li < 4; li++) {
        const ushort* wq = wb + (size_t)(li * 4 + 0) * 65536;   // [wq|wk|wv|wm]
        const ushort* wk = wb + (size_t)(li * 4 + 1) * 65536;
        const ushort* wm = wb + (size_t)(li * 4 + 3) * 65536;
        const ushort* w1 = wb1 + (size_t)li * 262144;
        const ushort* w2 = wb2 + (size_t)li * 131072;
        const float* g1p = g1 + li * 256; const float* b1p = b1 + li * 256;
        const float* g2p = g2 + li * 256; const float* b2p = b2 + li * 256;
        bool last = (li == 3);

        if ((li & 1) == 0) {
            // ---- self-self, both sides combined (z=2) ----
            lft_mfma_gemm<<<dim3(6, 192, 2), blk, 0, stream>>>(
                xc, xc, 256, wq, (float*)kc, qc, (float*)vc, 768, 256, 3, minfo, 0);
            lft_kv_kernel<<<dim3(KV_NCH, 8, 128), blk, 0, stream>>>(kc, vc, cmeta, kvb, ksb, 0);
            lft_msg_kernel<<<dim3(MSG_NCH, 8, 16), blk, 0, stream>>>(qc, kvb, ksb, cmeta, msgc, 0, 0);
            lft_gemm_ln<<<dim3(768, 1, 2), blk, 0, stream>>>(
                msgc, msgc, 256, wm, 256, g1p, b1p,
                nullptr, nullptr, gl, minfo, nullptr, msgc, 0);
            lft_mfma_gemm<<<dim3(4, 192, 2), blk, 0, stream>>>(
                xc, msgc, 256, w1, nullptr, hid, nullptr, 512, 512, 2, minfo, 0);
            lft_gemm_ln<<<dim3(768, 1, 2), blk, 0, stream>>>(
                hid, hid, 512, w2, 512, g2p, b2p,
                rc, rc, gl, minfo, nullptr, xc, 0);
        } else {
            // ---- cross-self: q for both sides from OLD features ----
            lft_mfma_gemm<<<dim3(2, 192, 2), blk, 0, stream>>>(
                xc, xc, 256, wq, nullptr, qc, nullptr, 256, 256, 1, minfo, 0);
            // k|v from side1 (old) -> kc/vc side1
            lft_mfma_gemm<<<dim3(4, 192, 1), blk, 0, stream>>>(
                xc, xc, 256, wk, (float*)kc, nullptr, (float*)vc, 512, 256, 4, minfo, 1);
            lft_kv_kernel<<<dim3(KV_NCH, 8, 64), blk, 0, stream>>>(kc, vc, cmeta, kvb, ksb, 1);
            lft_msg_kernel<<<dim3(MSG_NCH, 8, 8), blk, 0, stream>>>(qc, kvb, ksb, cmeta, msgc, 0, 1);
            lft_gemm_ln<<<dim3(768, 1, 1), blk, 0, stream>>>(
                msgc, msgc, 256, wm, 256, g1p, b1p,
                nullptr, nullptr, gl, minfo, nullptr, msgc, 0);
            lft_mfma_gemm<<<dim3(4, 192, 1), blk, 0, stream>>>(
                xc, msgc, 256, w1, nullptr, hid, nullptr, 512, 512, 2, minfo, 0);
            lft_gemm_ln<<<dim3(768, 1, 1), blk, 0, stream>>>(
                hid, hid, 512, w2, 512, g2p, b2p,
                rc, last ? nullptr : rc, gl, minfo, last ? out : nullptr, xc, 0);
            // ---- side1 attends UPDATED side0 ----
            lft_mfma_gemm<<<dim3(4, 192, 1), blk, 0, stream>>>(
                xc, xc, 256, wk, (float*)kc, nullptr, (float*)vc, 512, 256, 4, minfo, 0);
            lft_kv_kernel<<<dim3(KV_NCH, 8, 64), blk, 0, stream>>>(kc, vc, cmeta, kvb, ksb, 0);
            lft_msg_kernel<<<dim3(MSG_NCH, 8, 8), blk, 0, stream>>>(qc, kvb, ksb, cmeta, msgc, 1, 0);
            lft_gemm_ln<<<dim3(768, 1, 1), blk, 0, stream>>>(
                msgc, msgc, 256, wm, 256, g1p, b1p,
                nullptr, nullptr, gl, minfo, nullptr, msgc, 1);
            lft_mfma_gemm<<<dim3(4, 192, 1), blk, 0, stream>>>(
                xc, msgc, 256, w1, nullptr, hid, nullptr, 512, 512, 2, minfo, 1);
            lft_gemm_ln<<<dim3(768, 1, 1), blk, 0, stream>>>(
                hid, hid, 512, w2, 512, g2p, b2p,
                rc, last ? nullptr : rc, gl, minfo, last ? out : nullptr,
                last ? nullptr : xc, 1);
        }
    }
}

// Round 15
// 1351.053 us; speedup vs baseline: 1.2203x; 1.0234x over previous
//
#include <hip/hip_runtime.h>
#include <math.h>

#define NPROTO 8
#define KV_NCH 4
#define MSG_NCH 8
#define CAP 24576L            // compact rows per side (Mv ~= 19200 +- ~200)

typedef __attribute__((ext_vector_type(8))) short short8;
typedef __attribute__((ext_vector_type(4))) float floatx4;

static __device__ __forceinline__ ushort f2b(float f) {
    unsigned u = __builtin_bit_cast(unsigned, f);
    unsigned r = (u + 0x7fffu + ((u >> 16) & 1u)) >> 16;
    return (ushort)r;
}

static __device__ __forceinline__ float b2f(ushort u) {
    return __builtin_bit_cast(float, (unsigned)u << 16);
}

static __device__ __forceinline__ float elu1(float v) {
    return v > 0.f ? v + 1.f : __expf(v);
}

// async 16B global -> LDS (linear dest: wave base + lane*16B)
#define GLOAD16(gp, lp) __builtin_amdgcn_global_load_lds( \
    (const __attribute__((address_space(1))) void*)(gp),  \
    (__attribute__((address_space(3))) void*)(lp), 16, 0, 0)

// full drain + barrier (gemm_ln's proven 2-phase structure)
#define WAIT_BAR() asm volatile("s_waitcnt vmcnt(0) lgkmcnt(0)\n\ts_barrier" ::: "memory")
// counted waits (mfma_gemm 3-buffer pipeline; 4 loads/thread/tile)
#define VMWAIT(N) asm volatile("s_waitcnt vmcnt(" #N ")" ::: "memory")
#define BAR() __builtin_amdgcn_s_barrier()

// swizzle of the 16B-group index within a 32-col bf16 row (4 groups/row)
static __device__ __forceinline__ int swz(int r) { return (r >> 1) & 3; }

// ---------------- prototype projection / argmax-class kernel ----------------
__global__ __launch_bounds__(256) void lft_class_kernel(
    const float* __restrict__ f0wo, const float* __restrict__ f1wo,
    const int* __restrict__ mask0, const int* __restrict__ mask1,
    const float* __restrict__ proto,
    float* out, int* cls0, int* cls1)
{
    __shared__ float pr[2048];          // proto [8][256]
    __shared__ float tile[128][68];     // [token][ch chunk], stride 68
    __shared__ float sm[128][8];
    int t = threadIdx.x;
    *(float4*)&pr[t * 4]        = *(const float4*)&proto[t * 4];
    *(float4*)&pr[1024 + t * 4] = *(const float4*)&proto[1024 + t * 4];
    long tok0 = (long)blockIdx.x * 128;
    const float* fsrc; const int* msrc; float* fpout; float* clsout; int* clsarr; long tbase;
    if (tok0 < 38400) {
        tbase = tok0; fsrc = f0wo; msrc = mask0;
        fpout = out + 19737600L; clsout = out + 19660800L; clsarr = cls0;
    } else {
        tbase = tok0 - 38400; fsrc = f1wo; msrc = mask1;
        fpout = out + 20044800L; clsout = out + 19699200L; clsarr = cls1;
    }
    int tok = t & 127, half = t >> 7;
    float s[4] = {};
    int r0 = t >> 4;            // 0..15
    int c4 = (t & 15) << 2;     // 0..60
    for (int ct = 0; ct < 4; ct++) {
        __syncthreads();
#pragma unroll
        for (int rr = 0; rr < 8; rr++) {
            int row = rr * 16 + r0;
            float4 v = *(const float4*)&fsrc[(tbase + row) * 256 + ct * 64 + c4];
            *(float4*)&tile[row][c4] = v;
        }
        __syncthreads();
#pragma unroll
        for (int cc = 0; cc < 16; cc++) {
            float4 f = *(const float4*)&tile[tok][cc << 2];
#pragma unroll
            for (int p = 0; p < 4; p++) {
                float4 pv = *(const float4*)&pr[(half * 4 + p) * 256 + ct * 64 + (cc << 2)];
                s[p] += f.x * pv.x + f.y * pv.y + f.z * pv.z + f.w * pv.w;
            }
        }
    }
#pragma unroll
    for (int p = 0; p < 4; p++) {
        fpout[(tbase + tok) * 8 + half * 4 + p] = s[p];
        sm[tok][half * 4 + p] = s[p];
    }
    __syncthreads();
    if (t < 128) {
        int best = 0; float bv = sm[t][0];
#pragma unroll
        for (int p = 1; p < 8; p++) { if (sm[t][p] > bv) { bv = sm[t][p]; best = p; } }
        clsout[tbase + t] = (float)best;
        clsarr[tbase + t] = msrc[tbase + t] ? best : -1;
    }
}

// ---------------- copy ONLY invalid-token rows of feat into out --------------
__global__ __launch_bounds__(256) void lft_invcopy_kernel(
    const float* __restrict__ f0, const float* __restrict__ f1,
    const int* __restrict__ cls0, const int* __restrict__ cls1,
    float* out)
{
    int w = blockIdx.x * 4 + (threadIdx.x >> 6);   // 0..4799
    int lane = threadIdx.x & 63;
    for (long row = w; row < 76800; row += 4800) {
        int side = row >= 38400;
        long r = row - (long)side * 38400;
        int c = side ? cls1[r] : cls0[r];
        if (c < 0) {
            const float* src = side ? f1 : f0;
            float4 v = *(const float4*)&src[r * 256 + lane * 4];
            *(float4*)&out[(long)side * 9830400L + r * 256 + lane * 4] = v;
        }
    }
}

// ---------------- per-(L,b) class counts -> meta {base,cnt} ------------------
__global__ __launch_bounds__(256) void lft_count_kernel(
    const int* __restrict__ cls0, const int* __restrict__ cls1, int* meta)
{
    int g = blockIdx.x; int L = g >> 3, b = g & 7;
    const int* cls = (L ? cls1 : cls0) + b * 4800;
    int* mt = meta + (L * 8 + b) * 16;
    __shared__ int cnt[8];
    int t = threadIdx.x;
    if (t < 8) cnt[t] = 0;
    __syncthreads();
    for (int tok = t; tok < 4800; tok += 256) {
        int c = cls[tok];
        if (c >= 0) atomicAdd(&cnt[c], 1);
    }
    __syncthreads();
    if (t == 0) {
        int s = 0;
        for (int c = 0; c < 8; c++) { mt[c * 2] = s; mt[c * 2 + 1] = cnt[c]; s += cnt[c]; }
    }
}

// ---------------- cross-batch scan: minfo (Mv, boff) + compact cmeta ---------
__global__ __launch_bounds__(256) void lft_scan_kernel(
    const int* __restrict__ meta, int* minfo, int* cmeta)
{
    int t = threadIdx.x;
    __shared__ int nb[16];
    if (t < 16) {
        int s = 0;
        for (int c = 0; c < 8; c++) s += meta[t * 16 + c * 2 + 1];
        nb[t] = s;
    }
    __syncthreads();
    if (t == 0) {
        int off = 0;
        for (int b = 0; b < 8; b++) { minfo[4 + b] = off; off += nb[b]; }
        minfo[2] = off; minfo[0] = (off + 127) & ~127;
        off = 0;
        for (int b = 0; b < 8; b++) { minfo[12 + b] = off; off += nb[8 + b]; }
        minfo[3] = off; minfo[1] = (off + 127) & ~127;
    }
    __syncthreads();
    if (t < 128) {
        int L = t >> 6, b = (t >> 3) & 7, c = t & 7;
        cmeta[t * 2]     = minfo[4 + L * 8 + b] + meta[(L * 8 + b) * 16 + c * 2];
        cmeta[t * 2 + 1] = meta[(L * 8 + b) * 16 + c * 2 + 1];
    }
}

// ---------------- place valid tokens into compact gather lists ---------------
__global__ __launch_bounds__(256) void lft_place_kernel(
    const int* __restrict__ cls0, const int* __restrict__ cls1,
    const int* __restrict__ cmeta, int* gl)
{
    int g = blockIdx.x; int L = g >> 3, b = g & 7;
    const int* cls = (L ? cls1 : cls0) + b * 4800;
    int* glp = gl + L * CAP;
    __shared__ int pos[8];
    int t = threadIdx.x;
    if (t < 8) pos[t] = cmeta[(L * 64 + b * 8 + t) * 2];
    __syncthreads();
    for (int tok = t; tok < 4800; tok += 256) {
        int c = cls[tok];
        if (c >= 0) { int p = atomicAdd(&pos[c], 1); glp[p] = b * 4800 + tok; }
    }
}

// ---------------- gather-cast: compact bf16 x + compact fp32 resid -----------
__global__ __launch_bounds__(256) void lft_gcast_kernel(
    const float* __restrict__ f0, const float* __restrict__ f1,
    const int* __restrict__ gl, const int* __restrict__ minfo,
    ushort* xc, float* rc)
{
    int blk = blockIdx.x;
    int side = blk >= 600 ? 1 : 0;
    int i0 = (blk - side * 600) * 4 + (threadIdx.x >> 6);
    int mv = minfo[2 + side];
    const int* glp = gl + side * CAP;
    const float* f = side ? f1 : f0;
    ushort* xcp = xc + side * CAP * 256;
    float* rcp = rc + side * CAP * 256;
    int lane = threadIdx.x & 63;
    for (int i = i0; i < mv; i += 2400) {
        long src = (long)glp[i] * 256 + lane * 4;
        float4 v = *(const float4*)&f[src];
        long dst = (long)i * 256 + lane * 4;
        *(float4*)&rcp[dst] = v;
        ushort4 u; u.x = f2b(v.x); u.y = f2b(v.y); u.z = f2b(v.z); u.w = f2b(v.w);
        *(ushort4*)&xcp[dst] = u;
    }
}

// ---------------- weight convert + transpose: Wt[n*K+k] = bf16(W[k*N+n]) ----
__global__ __launch_bounds__(256) void lft_wconv_kernel(
    const float* W0, const float* W1p, const float* W2p, const float* W3p,
    int K, int N, int nTypes, ushort* dst)
{
    int z = blockIdx.z;
    int li = z / nTypes, mi = z % nTypes;
    const float* srcs[4] = {W0, W1p, W2p, W3p};
    const float* src = srcs[mi] + (size_t)li * K * N;
    ushort* outp = dst + (size_t)z * K * N;
    __shared__ float tile[32][33];
    int k0 = blockIdx.x * 32, n0 = blockIdx.y * 32;
    int t = threadIdx.x;
    int r = t >> 3, c4 = (t & 7) << 2;
    float4 v = *(const float4*)&src[(size_t)(k0 + r) * N + n0 + c4];
    tile[r][c4] = v.x; tile[r][c4 + 1] = v.y; tile[r][c4 + 2] = v.z; tile[r][c4 + 3] = v.w;
    __syncthreads();
    ushort4 o;
    o.x = f2b(tile[c4 + 0][r]);
    o.y = f2b(tile[c4 + 1][r]);
    o.z = f2b(tile[c4 + 2][r]);
    o.w = f2b(tile[c4 + 3][r]);
    *(ushort4*)&outp[(size_t)(n0 + r) * K + k0 + c4] = o;
}

// ---------------- bf16 MFMA GEMM over COMPACT rows ---------------------------
// XCD-aware block swizzle (T1). 3-buffer counted-vmcnt pipeline. 128x128 tile.
// act: 0 none, 1 elu+1, 2 relu; act 3 qkv N=768 (q/k/v bf16);
// act 4 kv N=512 (k/v bf16). k,v buffers are ushort (passed via Cf/Cv).
__global__ __launch_bounds__(256) void lft_mfma_gemm(
    const ushort* __restrict__ A0b, const ushort* __restrict__ A1b, int kSplit,
    const ushort* __restrict__ Wt,
    float* Cf, ushort* Cb, float* Cv, int N, int K, int act,
    const int* __restrict__ minfo, int side0)
{
    __shared__ ushort As[3][128 * 32];
    __shared__ ushort Bs[3][128 * 32];
    int gx = gridDim.x, gy = gridDim.y;
    int G = gx * gy * gridDim.z;
    int orig = (blockIdx.z * gy + blockIdx.y) * gx + blockIdx.x;
    int wid = ((orig & 7) * (G >> 3)) + (orig >> 3);   // G % 8 == 0 (all grids)
    int bx = wid % gx; int rest = wid / gx;
    int by = rest % gy; int bz = rest / gy;
    int side = side0 + bz;
    int m0 = by << 7;
    if (m0 >= minfo[side]) return;
    int n0 = bx << 7;
    const ushort* A0 = A0b + (long)side * CAP * kSplit;
    const ushort* A1 = A1b + (long)side * CAP * (K - kSplit);
    long so256 = (long)side * CAP * 256;
    long soN = (long)side * CAP * N;
    int t = threadIdx.x;
    int wv = t >> 6, lane = t & 63;
    int wm = wv >> 1, wn = wv & 1;
    int l16 = lane & 15, quad = lane >> 4;
    floatx4 acc[4][4] = {};

    int lrow = lane >> 2;
    int lcg = lane & 3;

    auto stage = [&](int buf, int k0) {
        const ushort* Asrc; int kcol, ldA;
        if (k0 < kSplit) { Asrc = A0; kcol = k0;          ldA = kSplit; }
        else             { Asrc = A1; kcol = k0 - kSplit; ldA = K - kSplit; }
        ushort* Ab = &As[buf][0];
        ushort* Bb = &Bs[buf][0];
#pragma unroll
        for (int s = 0; s < 2; s++) {
            int r = s * 64 + wv * 16 + lrow;
            int cgA = (lcg ^ swz(r)) << 3;
            GLOAD16(&Asrc[(size_t)(m0 + r) * ldA + kcol + cgA], &Ab[(s * 64 + wv * 16) * 32]);
            GLOAD16(&Wt[(size_t)(n0 + r) * K + k0 + cgA], &Bb[(s * 64 + wv * 16) * 32]);
        }
    };

    auto compute = [&](int buf) {
        const ushort* Ab = &As[buf][0];
        const ushort* Bb = &Bs[buf][0];
        short8 af[4], bfr[4];
#pragma unroll
        for (int i = 0; i < 4; i++) {
            int rA = wm * 64 + i * 16 + l16;
            int rB = wn * 64 + i * 16 + l16;
            af[i]  = *(const short8*)&Ab[rA * 32 + ((quad ^ swz(rA)) << 3)];
            bfr[i] = *(const short8*)&Bb[rB * 32 + ((quad ^ swz(rB)) << 3)];
        }
        __builtin_amdgcn_s_setprio(1);
#pragma unroll
        for (int i = 0; i < 4; i++)
#pragma unroll
            for (int j = 0; j < 4; j++)
                acc[i][j] = __builtin_amdgcn_mfma_f32_16x16x32_bf16(af[i], bfr[j], acc[i][j], 0, 0, 0);
        __builtin_amdgcn_s_setprio(0);
    };

    int nt = K >> 5;               // 8 or 16
    stage(0, 0);
    stage(1, 32);
    int cur = 0;
    for (int tt = 0; tt < nt; ++tt) {
        if (tt + 2 < nt) {
            int nb = cur + 2; if (nb >= 3) nb -= 3;
            stage(nb, (tt + 2) << 5);
            VMWAIT(8);             // tile tt done; tt+1, tt+2 in flight
        } else if (tt + 2 == nt) {
            VMWAIT(4);
        } else {
            VMWAIT(0);
        }
        BAR();
        compute(cur);
        if (tt + 1 < nt) BAR();
        cur = cur + 1 == 3 ? 0 : cur + 1;
    }

#pragma unroll
    for (int i = 0; i < 4; i++) {
#pragma unroll
        for (int j = 0; j < 4; j++) {
#pragma unroll
            for (int r = 0; r < 4; r++) {
                float v = acc[i][j][r];
                long row = m0 + wm * 64 + i * 16 + quad * 4 + r;
                int col = n0 + wn * 64 + j * 16 + l16;
                if (act == 3) {
                    if (col < 256)      Cb[so256 + row * 256 + col] = f2b(elu1(v));
                    else if (col < 512) ((ushort*)Cf)[so256 + row * 256 + col - 256] = f2b(elu1(v));
                    else                ((ushort*)Cv)[so256 + row * 256 + col - 512] = f2b(v);
                } else if (act == 4) {
                    if (col < 256) ((ushort*)Cf)[so256 + row * 256 + col] = f2b(elu1(v));
                    else           ((ushort*)Cv)[so256 + row * 256 + col - 256] = f2b(v);
                } else {
                    if (act == 1)      v = elu1(v);
                    else if (act == 2) v = fmaxf(v, 0.f);
                    if (Cf) Cf[soN + row * N + col] = v;
                    if (Cb) Cb[soN + row * N + col] = f2b(v);
                }
            }
        }
    }
}

// ---------------- fused GEMM (N=256) + row-LN over COMPACT rows -------------
// 512 threads, M=64 tile (grid.x=384 per side, early-exit), 8 waves (2m x 4n):
// wave (wm,wn) owns rows [32wm,+32) x cols [64wn,+64). Staging per thread per
// K-step: waves 0-3 one A-load, all waves two B-loads (2.5 avg vs 5 at 256thr).
// Same proven 2-phase drain pipeline. LDS 42KB.
__global__ __launch_bounds__(512) void lft_gemm_ln(
    const ushort* __restrict__ A0b, const ushort* __restrict__ A1b, int kSplit,
    const ushort* __restrict__ Wt, int K,
    const float* __restrict__ g, const float* __restrict__ bb,
    const float* __restrict__ rcInB, float* rcOutB,
    const int* __restrict__ glB, const int* __restrict__ minfo,
    float* outScB, ushort* __restrict__ outBB, int side0)
{
    __shared__ ushort As[2][64 * 32];
    __shared__ ushort Bs[2][256 * 32];
    __shared__ float gs[256], bs[256];
    __shared__ float psum[4][64], psq[4][64];
    int side = side0 + blockIdx.z;
    long m0 = (long)blockIdx.x << 6;
    if (m0 >= minfo[side]) return;
    const ushort* A0 = A0b + (long)side * CAP * kSplit;
    const ushort* A1 = A1b + (long)side * CAP * (K - kSplit);
    long so = (long)side * CAP * 256;
    int t = threadIdx.x;
    int wv = t >> 6, lane = t & 63;
    int wm = wv >> 2, wn = wv & 3;
    int l16 = lane & 15, quad = lane >> 4;
    if (t < 256) { gs[t] = g[t]; bs[t] = bb[t]; }
    floatx4 acc[2][4] = {};

    int lrow = lane >> 2;
    int lcg = lane & 3;

    auto stage = [&](int buf, int k0) {
        const ushort* Asrc; int kcol, ldA;
        if (k0 < kSplit) { Asrc = A0; kcol = k0;          ldA = kSplit; }
        else             { Asrc = A1; kcol = k0 - kSplit; ldA = K - kSplit; }
        if (wv < 4) {                                      // A rows 0..63
            int r = wv * 16 + lrow;
            int cgA = (lcg ^ swz(r)) << 3;
            GLOAD16(&Asrc[(m0 + r) * ldA + kcol + cgA], &As[buf][(wv * 16) * 32]);
        }
#pragma unroll
        for (int s = 0; s < 2; s++) {                      // B rows 0..255
            int r = s * 128 + wv * 16 + lrow;
            int cgB = (lcg ^ swz(r)) << 3;
            GLOAD16(&Wt[(size_t)r * K + k0 + cgB], &Bs[buf][(s * 128 + wv * 16) * 32]);
        }
    };

    int nt = K >> 5;
    stage(0, 0);
    WAIT_BAR();
    int cur = 0;
    for (int tt = 0; tt < nt; ++tt) {
        if (tt + 1 < nt) stage(cur ^ 1, (tt + 1) << 5);
        const ushort* Ab = &As[cur][0];
        const ushort* Bb = &Bs[cur][0];
        short8 af[2], bfr[4];
#pragma unroll
        for (int i = 0; i < 2; i++) {
            int rA = wm * 32 + i * 16 + l16;
            af[i] = *(const short8*)&Ab[rA * 32 + ((quad ^ swz(rA)) << 3)];
        }
#pragma unroll
        for (int j = 0; j < 4; j++) {
            int rB = wn * 64 + j * 16 + l16;
            bfr[j] = *(const short8*)&Bb[rB * 32 + ((quad ^ swz(rB)) << 3)];
        }
#pragma unroll
        for (int i = 0; i < 2; i++)
#pragma unroll
            for (int j = 0; j < 4; j++)
                acc[i][j] = __builtin_amdgcn_mfma_f32_16x16x32_bf16(af[i], bfr[j], acc[i][j], 0, 0, 0);
        if (tt + 1 < nt) { WAIT_BAR(); cur ^= 1; }
    }
    // per-row partial sums (this wave's 64 cols) -> LDS
#pragma unroll
    for (int i = 0; i < 2; i++) {
#pragma unroll
        for (int r = 0; r < 4; r++) {
            float s = 0.f, q = 0.f;
#pragma unroll
            for (int j = 0; j < 4; j++) { float v = acc[i][j][r]; s += v; q += v * v; }
#pragma unroll
            for (int o = 8; o >= 1; o >>= 1) {
                s += __shfl_xor(s, o, 64);
                q += __shfl_xor(q, o, 64);
            }
            if (l16 == 0) {
                int row = wm * 32 + i * 16 + quad * 4 + r;
                psum[wn][row] = s; psq[wn][row] = q;
            }
        }
    }
    __syncthreads();
    if (t < 64) {
        float s = psum[0][t] + psum[1][t] + psum[2][t] + psum[3][t];
        float q = psq[0][t] + psq[1][t] + psq[2][t] + psq[3][t];
        float mean = s * (1.0f / 256.0f);
        float var = q * (1.0f / 256.0f) - mean * mean;
        psum[0][t] = mean;
        psq[0][t] = rsqrtf(var + 1e-5f);
    }
    __syncthreads();
    int mvE = minfo[2 + side];
    const float* rcIn = rcInB ? rcInB + so : nullptr;
    float* rcOut = rcOutB ? rcOutB + so : nullptr;
    const int* glp = glB + side * CAP;
    float* outSc = outScB ? outScB + (long)side * 9830400L : nullptr;
    ushort* outB = outBB ? outBB + so : nullptr;
#pragma unroll
    for (int i = 0; i < 2; i++) {
#pragma unroll
        for (int r = 0; r < 4; r++) {
            int rloc = wm * 32 + i * 16 + quad * 4 + r;
            long grow = m0 + rloc;
            float mean = psum[0][rloc], rstd = psq[0][rloc];
#pragma unroll
            for (int j = 0; j < 4; j++) {
                int col = wn * 64 + j * 16 + l16;
                float y = (acc[i][j][r] - mean) * rstd * gs[col] + bs[col];
                if (rcIn) y += rcIn[grow * 256 + col];
                if (rcOut) rcOut[grow * 256 + col] = y;
                if (outSc && grow < mvE) outSc[(long)glp[grow] * 256 + col] = y;
                if (outB) outB[grow * 256 + col] = f2b(y);
            }
        }
    }
}

// ---------------- per-class KV / Ksum reduction (compact, bf16 inputs) -------
// Per-chunk private slots (plain stores, no memset/atomics).
__global__ __launch_bounds__(256) void lft_kv_kernel(
    const ushort* __restrict__ kcB, const ushort* __restrict__ vcB,
    const int* __restrict__ cmetaB,
    float* kvbB, float* ksbB, int sideSrc0)
{
    int side = sideSrc0 + (blockIdx.z >> 6);
    int zz = blockIdx.z & 63;
    int chunk = blockIdx.x, c = blockIdx.y;
    int b = zz >> 3, h = zz & 7;
    const int* cmeta = cmetaB + side * 128;
    int cstart = cmeta[(b * 8 + c) * 2], n = cmeta[(b * 8 + c) * 2 + 1];
    int per = (n + KV_NCH - 1) / KV_NCH;
    int s0 = chunk * per;
    int s1 = min(s0 + per, n);
    const ushort* phik = kcB + (long)side * CAP * 256;
    const ushort* vmat = vcB + (long)side * CAP * 256;
    int slot = side * KV_NCH + chunk;
    float* kv = kvbB + (long)slot * 524288;
    float* ksum = ksbB + (long)slot * 16384;
    int t = threadIdx.x;
    __shared__ float kb[8][32];
    __shared__ float vb[8][32];
    int od = t >> 3, oe = (t & 7) << 2;
    int lt = t >> 5, ld = t & 31;
    float a0 = 0.f, a1 = 0.f, a2 = 0.f, a3 = 0.f, ak = 0.f;
    for (int s = s0; s < s1; s += 8) {
        float kval = 0.f, vval = 0.f;
        if (s + lt < s1) {
            long bse = (long)(cstart + s + lt) * 256 + h * 32 + ld;
            kval = b2f(phik[bse]);
            vval = b2f(vmat[bse]);
        }
        __syncthreads();
        kb[lt][ld] = kval;
        vb[lt][ld] = vval;
        __syncthreads();
#pragma unroll
        for (int j = 0; j < 8; j++) {
            float kd = kb[j][od];
            float4 vv = *(const float4*)&vb[j][oe];
            a0 += kd * vv.x; a1 += kd * vv.y; a2 += kd * vv.z; a3 += kd * vv.w;
            ak += kd;
        }
    }
    float* dst = kv + (((long)(b * NPROTO + c) * 8 + h) << 10) + od * 32 + oe;
    dst[0] = a0; dst[1] = a1; dst[2] = a2; dst[3] = a3;
    if ((t & 7) == 0)
        ksum[(((long)(b * NPROTO + c) * 8 + h) << 5) + od] = ak;
}

// ---------------- msg via MFMA; kv fragments = sum of KV_NCH chunk slots -----
__global__ __launch_bounds__(256) void lft_msg_kernel(
    const ushort* __restrict__ qcB, const float* __restrict__ kvbB,
    const float* __restrict__ ksbB, const int* __restrict__ cmetaB,
    ushort* __restrict__ msgcB, int sideX0, int sideKV0)
{
    int add = blockIdx.z >> 3, b = blockIdx.z & 7;
    int sideX = sideX0 + add, sideKV = sideKV0 + add;
    int chunk = blockIdx.x, c = blockIdx.y;
    const int* cmeta = cmetaB + sideX * 128;
    int cstart = cmeta[(b * 8 + c) * 2], n = cmeta[(b * 8 + c) * 2 + 1];
    int per = (n + MSG_NCH - 1) / MSG_NCH;
    int s0 = chunk * per, s1 = min(s0 + per, n);
    if (s0 >= s1) return;
    const ushort* pq = qcB + (long)sideX * CAP * 256;
    ushort* msg = msgcB + (long)sideX * CAP * 256;
    int t = threadIdx.x;
    int wave = t >> 6, lane = t & 63;
    int l16 = lane & 15, quad = lane >> 4;
    int bc = b * 8 + c;
    short8 bfr[2][3];
#pragma unroll
    for (int hh = 0; hh < 2; hh++) {
        int h = wave * 2 + hh;
        long kvoff = ((long)bc * 8 + h) * 1024;
        long ksoff = ((long)bc * 8 + h) * 32;
#pragma unroll
        for (int nt = 0; nt < 2; nt++)
#pragma unroll
            for (int j = 0; j < 8; j++) {
                float v = 0.f;
#pragma unroll
                for (int ch = 0; ch < KV_NCH; ch++)
                    v += kvbB[(long)(sideKV * KV_NCH + ch) * 524288 + kvoff
                              + (quad * 8 + j) * 32 + nt * 16 + l16];
                bfr[hh][nt][j] = (short)f2b(v);
            }
#pragma unroll
        for (int j = 0; j < 8; j++) {
            float v = 0.f;
#pragma unroll
            for (int ch = 0; ch < KV_NCH; ch++)
                v += ksbB[(long)(sideKV * KV_NCH + ch) * 16384 + ksoff + quad * 8 + j];
            bfr[hh][2][j] = (l16 == 0) ? (short)f2b(v) : (short)0;
        }
    }
    for (int s = s0; s < s1; s += 16) {
        long rowA = cstart + min(s + l16, s1 - 1);
#pragma unroll
        for (int hh = 0; hh < 2; hh++) {
            int h = wave * 2 + hh;
            short8 a = *(const short8*)&pq[rowA * 256 + h * 32 + quad * 8];
            floatx4 n0 = {}, n1 = {}, dd = {};
            n0 = __builtin_amdgcn_mfma_f32_16x16x32_bf16(a, bfr[hh][0], n0, 0, 0, 0);
            n1 = __builtin_amdgcn_mfma_f32_16x16x32_bf16(a, bfr[hh][1], n1, 0, 0, 0);
            dd = __builtin_amdgcn_mfma_f32_16x16x32_bf16(a, bfr[hh][2], dd, 0, 0, 0);
#pragma unroll
            for (int r = 0; r < 4; r++) {
                int rowi = s + quad * 4 + r;
                float den = __shfl(dd[r], lane & 48, 64);
                float inv = 1.f / (den + 1e-6f);
                if (rowi < s1) {
                    long base = (long)(cstart + rowi) * 256 + h * 32;
                    msg[base + l16]      = f2b(n0[r] * inv);
                    msg[base + 16 + l16] = f2b(n1[r] * inv);
                }
            }
        }
    }
}

extern "C" void kernel_launch(void* const* d_in, const int* in_sizes, int n_in,
                              void* d_out, int out_size, void* d_ws, size_t ws_size,
                              hipStream_t stream)
{
    (void)in_sizes; (void)n_in; (void)out_size; (void)ws_size;
    const float* feat0 = (const float*)d_in[0];
    const float* feat1 = (const float*)d_in[1];
    const int*   mask0 = (const int*)d_in[2];
    const int*   mask1 = (const int*)d_in[3];
    const float* f0wo  = (const float*)d_in[4];
    const float* f1wo  = (const float*)d_in[5];
    const float* proto = (const float*)d_in[6];
    const float* Wq = (const float*)d_in[7];
    const float* Wk = (const float*)d_in[8];
    const float* Wv = (const float*)d_in[9];
    const float* Wm = (const float*)d_in[10];
    const float* W1 = (const float*)d_in[11];
    const float* W2 = (const float*)d_in[12];
    const float* g1 = (const float*)d_in[13];
    const float* b1 = (const float*)d_in[14];
    const float* g2 = (const float*)d_in[15];
    const float* b2 = (const float*)d_in[16];
    float* out = (float*)d_out;
    float* ws = (float*)d_ws;

    // ---- workspace layout (side-strided compact buffers, CAP rows/side) ----
    const long FSZ = 9830400L;
    float* rc = ws;                               // 2*CAP*256 f
    ushort* kc = (ushort*)(rc + 2 * CAP * 256);   // 2*CAP*256 us  bf16
    ushort* vc = kc + 2 * CAP * 256;              // 2*CAP*256 us  bf16
    ushort* hid = vc + 2 * CAP * 256;             // 2*CAP*512 us
    ushort* xc   = hid + 2 * CAP * 512;
    ushort* msgc = xc + 2 * CAP * 256;
    ushort* qc   = msgc + 2 * CAP * 256;
    ushort* wb   = qc + 2 * CAP * 256;
    ushort* wb1  = wb + 16 * 65536;
    ushort* wb2  = wb1 + 4 * 262144;
    float* ksb = (float*)(wb2 + 4 * 131072);      // 2*KV_NCH*16384 f
    int* cls0 = (int*)(ksb + 2 * KV_NCH * 16384);
    int* cls1 = cls0 + 38400;
    int* gl   = cls1 + 38400;                     // 2*CAP ints
    int* meta = gl + 2 * CAP;
    int* minfo = meta + 256;
    int* cmeta = minfo + 20;
    // kvb aliases hid (dead between kv_kernel and w1-GEMM)
    float* kvb = (float*)hid;

    lft_wconv_kernel<<<dim3(8, 8, 16), 256, 0, stream>>>(Wq, Wk, Wv, Wm, 256, 256, 4, wb);
    lft_wconv_kernel<<<dim3(16, 16, 4), 256, 0, stream>>>(W1, W1, W1, W1, 512, 512, 1, wb1);
    lft_wconv_kernel<<<dim3(16, 8, 4), 256, 0, stream>>>(W2, W2, W2, W2, 512, 256, 1, wb2);
    hipMemcpyAsync(out + 20352000L, proto, 2048 * 4, hipMemcpyDeviceToDevice, stream);
    lft_class_kernel<<<600, 256, 0, stream>>>(f0wo, f1wo, mask0, mask1, proto,
                                              out, cls0, cls1);
    lft_invcopy_kernel<<<1200, 256, 0, stream>>>(feat0, feat1, cls0, cls1, out);
    lft_count_kernel<<<16, 256, 0, stream>>>(cls0, cls1, meta);
    lft_scan_kernel<<<1, 256, 0, stream>>>(meta, minfo, cmeta);
    lft_place_kernel<<<16, 256, 0, stream>>>(cls0, cls1, cmeta, gl);
    lft_gcast_kernel<<<1200, 256, 0, stream>>>(feat0, feat1, gl, minfo, xc, rc);

    dim3 blk(256);
    dim3 blkL(512);
    for (int li = 0; li < 4; li++) {
        const ushort* wq = wb + (size_t)(li * 4 + 0) * 65536;   // [wq|wk|wv|wm]
        const ushort* wk = wb + (size_t)(li * 4 + 1) * 65536;
        const ushort* wm = wb + (size_t)(li * 4 + 3) * 65536;
        const ushort* w1 = wb1 + (size_t)li * 262144;
        const ushort* w2 = wb2 + (size_t)li * 131072;
        const float* g1p = g1 + li * 256; const float* b1p = b1 + li * 256;
        const float* g2p = g2 + li * 256; const float* b2p = b2 + li * 256;
        bool last = (li == 3);

        if ((li & 1) == 0) {
            // ---- self-self, both sides combined (z=2) ----
            lft_mfma_gemm<<<dim3(6, 192, 2), blk, 0, stream>>>(
                xc, xc, 256, wq, (float*)kc, qc, (float*)vc, 768, 256, 3, minfo, 0);
            lft_kv_kernel<<<dim3(KV_NCH, 8, 128), blk, 0, stream>>>(kc, vc, cmeta, kvb, ksb, 0);
            lft_msg_kernel<<<dim3(MSG_NCH, 8, 16), blk, 0, stream>>>(qc, kvb, ksb, cmeta, msgc, 0, 0);
            lft_gemm_ln<<<dim3(384, 1, 2), blkL, 0, stream>>>(
                msgc, msgc, 256, wm, 256, g1p, b1p,
                nullptr, nullptr, gl, minfo, nullptr, msgc, 0);
            lft_mfma_gemm<<<dim3(4, 192, 2), blk, 0, stream>>>(
                xc, msgc, 256, w1, nullptr, hid, nullptr, 512, 512, 2, minfo, 0);
            lft_gemm_ln<<<dim3(384, 1, 2), blkL, 0, stream>>>(
                hid, hid, 512, w2, 512, g2p, b2p,
                rc, rc, gl, minfo, nullptr, xc, 0);
        } else {
            // ---- cross-self: q for both sides from OLD features ----
            lft_mfma_gemm<<<dim3(2, 192, 2), blk, 0, stream>>>(
                xc, xc, 256, wq, nullptr, qc, nullptr, 256, 256, 1, minfo, 0);
            // k|v from side1 (old) -> kc/vc side1
            lft_mfma_gemm<<<dim3(4, 192, 1), blk, 0, stream>>>(
                xc, xc, 256, wk, (float*)kc, nullptr, (float*)vc, 512, 256, 4, minfo, 1);
            lft_kv_kernel<<<dim3(KV_NCH, 8, 64), blk, 0, stream>>>(kc, vc, cmeta, kvb, ksb, 1);
            lft_msg_kernel<<<dim3(MSG_NCH, 8, 8), blk, 0, stream>>>(qc, kvb, ksb, cmeta, msgc, 0, 1);
            lft_gemm_ln<<<dim3(384, 1, 1), blkL, 0, stream>>>(
                msgc, msgc, 256, wm, 256, g1p, b1p,
                nullptr, nullptr, gl, minfo, nullptr, msgc, 0);
            lft_mfma_gemm<<<dim3(4, 192, 1), blk, 0, stream>>>(
                xc, msgc, 256, w1, nullptr, hid, nullptr, 512, 512, 2, minfo, 0);
            lft_gemm_ln<<<dim3(384, 1, 1), blkL, 0, stream>>>(
                hid, hid, 512, w2, 512, g2p, b2p,
                rc, last ? nullptr : rc, gl, minfo, last ? out : nullptr, xc, 0);
            // ---- side1 attends UPDATED side0 ----
            lft_mfma_gemm<<<dim3(4, 192, 1), blk, 0, stream>>>(
                xc, xc, 256, wk, (float*)kc, nullptr, (float*)vc, 512, 256, 4, minfo, 0);
            lft_kv_kernel<<<dim3(KV_NCH, 8, 64), blk, 0, stream>>>(kc, vc, cmeta, kvb, ksb, 0);
            lft_msg_kernel<<<dim3(MSG_NCH, 8, 8), blk, 0, stream>>>(qc, kvb, ksb, cmeta, msgc, 1, 0);
            lft_gemm_ln<<<dim3(384, 1, 1), blkL, 0, stream>>>(
                msgc, msgc, 256, wm, 256, g1p, b1p,
                nullptr, nullptr, gl, minfo, nullptr, msgc, 1);
            lft_mfma_gemm<<<dim3(4, 192, 1), blk, 0, stream>>>(
                xc, msgc, 256, w1, nullptr, hid, nullptr, 512, 512, 2, minfo, 1);
            lft_gemm_ln<<<dim3(384, 1, 1), blkL, 0, stream>>>(
                hid, hid, 512, w2, 512, g2p, b2p,
                rc, last ? nullptr : rc, gl, minfo, last ? out : nullptr,
                last ? nullptr : xc, 1);
        }
    }
}

// Round 18
// 1260.704 us; speedup vs baseline: 1.3078x; 1.0717x over previous
//
#include <hip/hip_runtime.h>
#include <math.h>

#define NPROTO 8
#define KV_NCH 4
#define MSG_NCH 8
#define CAP 24576L            // compact rows per side (Mv ~= 19200 +- ~200)

typedef __attribute__((ext_vector_type(8))) short short8;
typedef __attribute__((ext_vector_type(4))) float floatx4;

static __device__ __forceinline__ ushort f2b(float f) {
    unsigned u = __builtin_bit_cast(unsigned, f);
    unsigned r = (u + 0x7fffu + ((u >> 16) & 1u)) >> 16;
    return (ushort)r;
}

static __device__ __forceinline__ float b2f(ushort u) {
    return __builtin_bit_cast(float, (unsigned)u << 16);
}

static __device__ __forceinline__ float elu1(float v) {
    return v > 0.f ? v + 1.f : __expf(v);
}

// async 16B global -> LDS (linear dest: wave base + lane*16B)
#define GLOAD16(gp, lp) __builtin_amdgcn_global_load_lds( \
    (const __attribute__((address_space(1))) void*)(gp),  \
    (__attribute__((address_space(3))) void*)(lp), 16, 0, 0)

// full drain + barrier (gemm_ln's proven 2-phase structure)
#define WAIT_BAR() asm volatile("s_waitcnt vmcnt(0) lgkmcnt(0)\n\ts_barrier" ::: "memory")
// counted waits (mfma_gemm 3-buffer pipeline; 4 loads/thread/tile)
#define VMWAIT(N) asm volatile("s_waitcnt vmcnt(" #N ")" ::: "memory")
#define BAR() __builtin_amdgcn_s_barrier()

// swizzle of the 16B-group index within a 32-col bf16 row (4 groups/row)
static __device__ __forceinline__ int swz(int r) { return (r >> 1) & 3; }

// ---------------- prototype projection / argmax-class kernel ----------------
__global__ __launch_bounds__(256) void lft_class_kernel(
    const float* __restrict__ f0wo, const float* __restrict__ f1wo,
    const int* __restrict__ mask0, const int* __restrict__ mask1,
    const float* __restrict__ proto,
    float* out, int* cls0, int* cls1)
{
    __shared__ float pr[2048];          // proto [8][256]
    __shared__ float tile[128][68];     // [token][ch chunk], stride 68
    __shared__ float sm[128][8];
    int t = threadIdx.x;
    *(float4*)&pr[t * 4]        = *(const float4*)&proto[t * 4];
    *(float4*)&pr[1024 + t * 4] = *(const float4*)&proto[1024 + t * 4];
    long tok0 = (long)blockIdx.x * 128;
    const float* fsrc; const int* msrc; float* fpout; float* clsout; int* clsarr; long tbase;
    if (tok0 < 38400) {
        tbase = tok0; fsrc = f0wo; msrc = mask0;
        fpout = out + 19737600L; clsout = out + 19660800L; clsarr = cls0;
    } else {
        tbase = tok0 - 38400; fsrc = f1wo; msrc = mask1;
        fpout = out + 20044800L; clsout = out + 19699200L; clsarr = cls1;
    }
    int tok = t & 127, half = t >> 7;
    float s[4] = {};
    int r0 = t >> 4;            // 0..15
    int c4 = (t & 15) << 2;     // 0..60
    for (int ct = 0; ct < 4; ct++) {
        __syncthreads();
#pragma unroll
        for (int rr = 0; rr < 8; rr++) {
            int row = rr * 16 + r0;
            float4 v = *(const float4*)&fsrc[(tbase + row) * 256 + ct * 64 + c4];
            *(float4*)&tile[row][c4] = v;
        }
        __syncthreads();
#pragma unroll
        for (int cc = 0; cc < 16; cc++) {
            float4 f = *(const float4*)&tile[tok][cc << 2];
#pragma unroll
            for (int p = 0; p < 4; p++) {
                float4 pv = *(const float4*)&pr[(half * 4 + p) * 256 + ct * 64 + (cc << 2)];
                s[p] += f.x * pv.x + f.y * pv.y + f.z * pv.z + f.w * pv.w;
            }
        }
    }
#pragma unroll
    for (int p = 0; p < 4; p++) {
        fpout[(tbase + tok) * 8 + half * 4 + p] = s[p];
        sm[tok][half * 4 + p] = s[p];
    }
    __syncthreads();
    if (t < 128) {
        int best = 0; float bv = sm[t][0];
#pragma unroll
        for (int p = 1; p < 8; p++) { if (sm[t][p] > bv) { bv = sm[t][p]; best = p; } }
        clsout[tbase + t] = (float)best;
        clsarr[tbase + t] = msrc[tbase + t] ? best : -1;
    }
}

// ---------------- copy ONLY invalid-token rows of feat into out --------------
__global__ __launch_bounds__(256) void lft_invcopy_kernel(
    const float* __restrict__ f0, const float* __restrict__ f1,
    const int* __restrict__ cls0, const int* __restrict__ cls1,
    float* out)
{
    int w = blockIdx.x * 4 + (threadIdx.x >> 6);   // 0..4799
    int lane = threadIdx.x & 63;
    for (long row = w; row < 76800; row += 4800) {
        int side = row >= 38400;
        long r = row - (long)side * 38400;
        int c = side ? cls1[r] : cls0[r];
        if (c < 0) {
            const float* src = side ? f1 : f0;
            float4 v = *(const float4*)&src[r * 256 + lane * 4];
            *(float4*)&out[(long)side * 9830400L + r * 256 + lane * 4] = v;
        }
    }
}

// ---------------- per-(L,b) class counts -> meta {base,cnt} ------------------
__global__ __launch_bounds__(256) void lft_count_kernel(
    const int* __restrict__ cls0, const int* __restrict__ cls1, int* meta)
{
    int g = blockIdx.x; int L = g >> 3, b = g & 7;
    const int* cls = (L ? cls1 : cls0) + b * 4800;
    int* mt = meta + (L * 8 + b) * 16;
    __shared__ int cnt[8];
    int t = threadIdx.x;
    if (t < 8) cnt[t] = 0;
    __syncthreads();
    for (int tok = t; tok < 4800; tok += 256) {
        int c = cls[tok];
        if (c >= 0) atomicAdd(&cnt[c], 1);
    }
    __syncthreads();
    if (t == 0) {
        int s = 0;
        for (int c = 0; c < 8; c++) { mt[c * 2] = s; mt[c * 2 + 1] = cnt[c]; s += cnt[c]; }
    }
}

// ---------------- cross-batch scan: minfo (Mv, boff) + compact cmeta ---------
__global__ __launch_bounds__(256) void lft_scan_kernel(
    const int* __restrict__ meta, int* minfo, int* cmeta)
{
    int t = threadIdx.x;
    __shared__ int nb[16];
    if (t < 16) {
        int s = 0;
        for (int c = 0; c < 8; c++) s += meta[t * 16 + c * 2 + 1];
        nb[t] = s;
    }
    __syncthreads();
    if (t == 0) {
        int off = 0;
        for (int b = 0; b < 8; b++) { minfo[4 + b] = off; off += nb[b]; }
        minfo[2] = off; minfo[0] = (off + 127) & ~127;
        off = 0;
        for (int b = 0; b < 8; b++) { minfo[12 + b] = off; off += nb[8 + b]; }
        minfo[3] = off; minfo[1] = (off + 127) & ~127;
    }
    __syncthreads();
    if (t < 128) {
        int L = t >> 6, b = (t >> 3) & 7, c = t & 7;
        cmeta[t * 2]     = minfo[4 + L * 8 + b] + meta[(L * 8 + b) * 16 + c * 2];
        cmeta[t * 2 + 1] = meta[(L * 8 + b) * 16 + c * 2 + 1];
    }
}

// ---------------- place valid tokens into compact gather lists ---------------
__global__ __launch_bounds__(256) void lft_place_kernel(
    const int* __restrict__ cls0, const int* __restrict__ cls1,
    const int* __restrict__ cmeta, int* gl)
{
    int g = blockIdx.x; int L = g >> 3, b = g & 7;
    const int* cls = (L ? cls1 : cls0) + b * 4800;
    int* glp = gl + L * CAP;
    __shared__ int pos[8];
    int t = threadIdx.x;
    if (t < 8) pos[t] = cmeta[(L * 64 + b * 8 + t) * 2];
    __syncthreads();
    for (int tok = t; tok < 4800; tok += 256) {
        int c = cls[tok];
        if (c >= 0) { int p = atomicAdd(&pos[c], 1); glp[p] = b * 4800 + tok; }
    }
}

// ---------------- gather-cast: compact bf16 x + compact fp32 resid -----------
__global__ __launch_bounds__(256) void lft_gcast_kernel(
    const float* __restrict__ f0, const float* __restrict__ f1,
    const int* __restrict__ gl, const int* __restrict__ minfo,
    ushort* xc, float* rc)
{
    int blk = blockIdx.x;
    int side = blk >= 600 ? 1 : 0;
    int i0 = (blk - side * 600) * 4 + (threadIdx.x >> 6);
    int mv = minfo[2 + side];
    const int* glp = gl + side * CAP;
    const float* f = side ? f1 : f0;
    ushort* xcp = xc + side * CAP * 256;
    float* rcp = rc + side * CAP * 256;
    int lane = threadIdx.x & 63;
    for (int i = i0; i < mv; i += 2400) {
        long src = (long)glp[i] * 256 + lane * 4;
        float4 v = *(const float4*)&f[src];
        long dst = (long)i * 256 + lane * 4;
        *(float4*)&rcp[dst] = v;
        ushort4 u; u.x = f2b(v.x); u.y = f2b(v.y); u.z = f2b(v.z); u.w = f2b(v.w);
        *(ushort4*)&xcp[dst] = u;
    }
}

// ---------------- weight convert + transpose: Wt[n*K+k] = bf16(W[k*N+n]) ----
__global__ __launch_bounds__(256) void lft_wconv_kernel(
    const float* W0, const float* W1p, const float* W2p, const float* W3p,
    int K, int N, int nTypes, ushort* dst)
{
    int z = blockIdx.z;
    int li = z / nTypes, mi = z % nTypes;
    const float* srcs[4] = {W0, W1p, W2p, W3p};
    const float* src = srcs[mi] + (size_t)li * K * N;
    ushort* outp = dst + (size_t)z * K * N;
    __shared__ float tile[32][33];
    int k0 = blockIdx.x * 32, n0 = blockIdx.y * 32;
    int t = threadIdx.x;
    int r = t >> 3, c4 = (t & 7) << 2;
    float4 v = *(const float4*)&src[(size_t)(k0 + r) * N + n0 + c4];
    tile[r][c4] = v.x; tile[r][c4 + 1] = v.y; tile[r][c4 + 2] = v.z; tile[r][c4 + 3] = v.w;
    __syncthreads();
    ushort4 o;
    o.x = f2b(tile[c4 + 0][r]);
    o.y = f2b(tile[c4 + 1][r]);
    o.z = f2b(tile[c4 + 2][r]);
    o.w = f2b(tile[c4 + 3][r]);
    *(ushort4*)&outp[(size_t)(n0 + r) * K + k0 + c4] = o;
}

// ---------------- bf16 MFMA GEMM over COMPACT rows ---------------------------
// XCD-aware block swizzle (T1). 3-buffer counted-vmcnt pipeline. 128x128 tile.
// Epilogue: LDS-transposed coalesced bf16 stores. Each of 8 threads/row now
// stores its FULL 16-element (32B) span (two short8) - R16/R17 stored only 8
// of 16 elements, leaving half the columns uninitialized (the NaN).
// act: 1 elu+1 (q); 2 relu (hid, ldc=512); act 3 qkv N=768; act 4 kv N=512.
__global__ __launch_bounds__(256) void lft_mfma_gemm(
    const ushort* __restrict__ A0b, const ushort* __restrict__ A1b, int kSplit,
    const ushort* __restrict__ Wt,
    float* Cf, ushort* Cb, float* Cv, int N, int K, int act,
    const int* __restrict__ minfo, int side0)
{
    __shared__ ushort As[3][128 * 32];
    __shared__ ushort Bs[3][128 * 32];
    int gx = gridDim.x, gy = gridDim.y;
    int G = gx * gy * gridDim.z;
    int orig = (blockIdx.z * gy + blockIdx.y) * gx + blockIdx.x;
    int wid = ((orig & 7) * (G >> 3)) + (orig >> 3);   // G % 8 == 0 (all grids)
    int bx = wid % gx; int rest = wid / gx;
    int by = rest % gy; int bz = rest / gy;
    int side = side0 + bz;
    int m0 = by << 7;
    if (m0 >= minfo[side]) return;
    int n0 = bx << 7;
    const ushort* A0 = A0b + (long)side * CAP * kSplit;
    const ushort* A1 = A1b + (long)side * CAP * (K - kSplit);
    long so256 = (long)side * CAP * 256;
    long soN = (long)side * CAP * N;
    int t = threadIdx.x;
    int wv = t >> 6, lane = t & 63;
    int wm = wv >> 1, wn = wv & 1;
    int l16 = lane & 15, quad = lane >> 4;
    floatx4 acc[4][4] = {};

    int lrow = lane >> 2;
    int lcg = lane & 3;

    auto stage = [&](int buf, int k0) {
        const ushort* Asrc; int kcol, ldA;
        if (k0 < kSplit) { Asrc = A0; kcol = k0;          ldA = kSplit; }
        else             { Asrc = A1; kcol = k0 - kSplit; ldA = K - kSplit; }
        ushort* Ab = &As[buf][0];
        ushort* Bb = &Bs[buf][0];
#pragma unroll
        for (int s = 0; s < 2; s++) {
            int r = s * 64 + wv * 16 + lrow;
            int cgA = (lcg ^ swz(r)) << 3;
            GLOAD16(&Asrc[(size_t)(m0 + r) * ldA + kcol + cgA], &Ab[(s * 64 + wv * 16) * 32]);
            GLOAD16(&Wt[(size_t)(n0 + r) * K + k0 + cgA], &Bb[(s * 64 + wv * 16) * 32]);
        }
    };

    auto compute = [&](int buf) {
        const ushort* Ab = &As[buf][0];
        const ushort* Bb = &Bs[buf][0];
        short8 af[4], bfr[4];
#pragma unroll
        for (int i = 0; i < 4; i++) {
            int rA = wm * 64 + i * 16 + l16;
            int rB = wn * 64 + i * 16 + l16;
            af[i]  = *(const short8*)&Ab[rA * 32 + ((quad ^ swz(rA)) << 3)];
            bfr[i] = *(const short8*)&Bb[rB * 32 + ((quad ^ swz(rB)) << 3)];
        }
        __builtin_amdgcn_s_setprio(1);
#pragma unroll
        for (int i = 0; i < 4; i++)
#pragma unroll
            for (int j = 0; j < 4; j++)
                acc[i][j] = __builtin_amdgcn_mfma_f32_16x16x32_bf16(af[i], bfr[j], acc[i][j], 0, 0, 0);
        __builtin_amdgcn_s_setprio(0);
    };

    int nt = K >> 5;               // 8 or 16
    stage(0, 0);
    stage(1, 32);
    int cur = 0;
    for (int tt = 0; tt < nt; ++tt) {
        if (tt + 2 < nt) {
            int nb = cur + 2; if (nb >= 3) nb -= 3;
            stage(nb, (tt + 2) << 5);
            VMWAIT(8);             // tile tt done; tt+1, tt+2 in flight
        } else if (tt + 2 == nt) {
            VMWAIT(4);
        } else {
            VMWAIT(0);
        }
        BAR();
        compute(cur);
        if (tt + 1 < nt) BAR();
        cur = cur + 1 == 3 ? 0 : cur + 1;
    }

    // ---- LDS-transposed coalesced bf16 epilogue ----
    // block-uniform dst (n0 multiple of 128; matrix boundaries at 256/512)
    ushort* dst; int ncol0; int amode; long base; int ldc;
    if (act == 3) {
        base = so256; ldc = 256;
        if (n0 < 256)      { dst = Cb;          ncol0 = n0;       amode = 1; }
        else if (n0 < 512) { dst = (ushort*)Cf; ncol0 = n0 - 256; amode = 1; }
        else               { dst = (ushort*)Cv; ncol0 = n0 - 512; amode = 0; }
    } else if (act == 4) {
        base = so256; ldc = 256;
        if (n0 < 256) { dst = (ushort*)Cf; ncol0 = n0;       amode = 1; }
        else          { dst = (ushort*)Cv; ncol0 = n0 - 256; amode = 0; }
    } else {  // act 1 (q, elu) or act 2 (hid, relu)
        base = soN; ldc = N;
        dst = Cb; ncol0 = n0; amode = (act == 1) ? 1 : 2;
    }
    ushort* tb = &As[0][0];        // 32 x 144 transpose tile (aliases As)
    int lr = t >> 3;               // 0..31 (8 threads/row)
    int cs = (t & 7) << 4;         // element offset 0,16,..,112 (16 elems = 32B)
    int wmr = lr >> 4, rloc = lr & 15;
#pragma unroll
    for (int i = 0; i < 4; i++) {
        __syncthreads();           // prior LDS reads (compute / tb) complete
#pragma unroll
        for (int j = 0; j < 4; j++) {
#pragma unroll
            for (int r = 0; r < 4; r++) {
                float v = acc[i][j][r];
                if (amode == 1)      v = elu1(v);
                else if (amode == 2) v = fmaxf(v, 0.f);
                tb[(wm * 16 + quad * 4 + r) * 144 + wn * 64 + j * 16 + l16] = f2b(v);
            }
        }
        __syncthreads();
        long row = m0 + wmr * 64 + i * 16 + rloc;
        short8 v0 = *(const short8*)&tb[lr * 144 + cs];
        short8 v1 = *(const short8*)&tb[lr * 144 + cs + 8];
        *(short8*)&dst[base + row * ldc + ncol0 + cs] = v0;
        *(short8*)&dst[base + row * ldc + ncol0 + cs + 8] = v1;
    }
}

// ---------------- fused GEMM (N=256) + row-LN over COMPACT rows -------------
// 512 threads, M=64 tile (grid.x=384 per side, early-exit), 8 waves (2m x 4n).
__global__ __launch_bounds__(512) void lft_gemm_ln(
    const ushort* __restrict__ A0b, const ushort* __restrict__ A1b, int kSplit,
    const ushort* __restrict__ Wt, int K,
    const float* __restrict__ g, const float* __restrict__ bb,
    const float* __restrict__ rcInB, float* rcOutB,
    const int* __restrict__ glB, const int* __restrict__ minfo,
    float* outScB, ushort* __restrict__ outBB, int side0)
{
    __shared__ ushort As[2][64 * 32];
    __shared__ ushort Bs[2][256 * 32];
    __shared__ float gs[256], bs[256];
    __shared__ float psum[4][64], psq[4][64];
    int side = side0 + blockIdx.z;
    long m0 = (long)blockIdx.x << 6;
    if (m0 >= minfo[side]) return;
    const ushort* A0 = A0b + (long)side * CAP * kSplit;
    const ushort* A1 = A1b + (long)side * CAP * (K - kSplit);
    long so = (long)side * CAP * 256;
    int t = threadIdx.x;
    int wv = t >> 6, lane = t & 63;
    int wm = wv >> 2, wn = wv & 3;
    int l16 = lane & 15, quad = lane >> 4;
    if (t < 256) { gs[t] = g[t]; bs[t] = bb[t]; }
    floatx4 acc[2][4] = {};

    int lrow = lane >> 2;
    int lcg = lane & 3;

    auto stage = [&](int buf, int k0) {
        const ushort* Asrc; int kcol, ldA;
        if (k0 < kSplit) { Asrc = A0; kcol = k0;          ldA = kSplit; }
        else             { Asrc = A1; kcol = k0 - kSplit; ldA = K - kSplit; }
        if (wv < 4) {                                      // A rows 0..63
            int r = wv * 16 + lrow;
            int cgA = (lcg ^ swz(r)) << 3;
            GLOAD16(&Asrc[(m0 + r) * ldA + kcol + cgA], &As[buf][(wv * 16) * 32]);
        }
#pragma unroll
        for (int s = 0; s < 2; s++) {                      // B rows 0..255
            int r = s * 128 + wv * 16 + lrow;
            int cgB = (lcg ^ swz(r)) << 3;
            GLOAD16(&Wt[(size_t)r * K + k0 + cgB], &Bs[buf][(s * 128 + wv * 16) * 32]);
        }
    };

    int nt = K >> 5;
    stage(0, 0);
    WAIT_BAR();
    int cur = 0;
    for (int tt = 0; tt < nt; ++tt) {
        if (tt + 1 < nt) stage(cur ^ 1, (tt + 1) << 5);
        const ushort* Ab = &As[cur][0];
        const ushort* Bb = &Bs[cur][0];
        short8 af[2], bfr[4];
#pragma unroll
        for (int i = 0; i < 2; i++) {
            int rA = wm * 32 + i * 16 + l16;
            af[i] = *(const short8*)&Ab[rA * 32 + ((quad ^ swz(rA)) << 3)];
        }
#pragma unroll
        for (int j = 0; j < 4; j++) {
            int rB = wn * 64 + j * 16 + l16;
            bfr[j] = *(const short8*)&Bb[rB * 32 + ((quad ^ swz(rB)) << 3)];
        }
#pragma unroll
        for (int i = 0; i < 2; i++)
#pragma unroll
            for (int j = 0; j < 4; j++)
                acc[i][j] = __builtin_amdgcn_mfma_f32_16x16x32_bf16(af[i], bfr[j], acc[i][j], 0, 0, 0);
        if (tt + 1 < nt) { WAIT_BAR(); cur ^= 1; }
    }
    // per-row partial sums (this wave's 64 cols) -> LDS
#pragma unroll
    for (int i = 0; i < 2; i++) {
#pragma unroll
        for (int r = 0; r < 4; r++) {
            float s = 0.f, q = 0.f;
#pragma unroll
            for (int j = 0; j < 4; j++) { float v = acc[i][j][r]; s += v; q += v * v; }
#pragma unroll
            for (int o = 8; o >= 1; o >>= 1) {
                s += __shfl_xor(s, o, 64);
                q += __shfl_xor(q, o, 64);
            }
            if (l16 == 0) {
                int row = wm * 32 + i * 16 + quad * 4 + r;
                psum[wn][row] = s; psq[wn][row] = q;
            }
        }
    }
    __syncthreads();
    if (t < 64) {
        float s = psum[0][t] + psum[1][t] + psum[2][t] + psum[3][t];
        float q = psq[0][t] + psq[1][t] + psq[2][t] + psq[3][t];
        float mean = s * (1.0f / 256.0f);
        float var = q * (1.0f / 256.0f) - mean * mean;
        psum[0][t] = mean;
        psq[0][t] = rsqrtf(var + 1e-5f);
    }
    __syncthreads();
    int mvE = minfo[2 + side];
    const float* rcIn = rcInB ? rcInB + so : nullptr;
    float* rcOut = rcOutB ? rcOutB + so : nullptr;
    const int* glp = glB + side * CAP;
    float* outSc = outScB ? outScB + (long)side * 9830400L : nullptr;
    ushort* outB = outBB ? outBB + so : nullptr;
#pragma unroll
    for (int i = 0; i < 2; i++) {
#pragma unroll
        for (int r = 0; r < 4; r++) {
            int rloc = wm * 32 + i * 16 + quad * 4 + r;
            long grow = m0 + rloc;
            float mean = psum[0][rloc], rstd = psq[0][rloc];
#pragma unroll
            for (int j = 0; j < 4; j++) {
                int col = wn * 64 + j * 16 + l16;
                float y = (acc[i][j][r] - mean) * rstd * gs[col] + bs[col];
                if (rcIn) y += rcIn[grow * 256 + col];
                if (rcOut) rcOut[grow * 256 + col] = y;
                if (outSc && grow < mvE) outSc[(long)glp[grow] * 256 + col] = y;
                if (outB) outB[grow * 256 + col] = f2b(y);
            }
        }
    }
}

// ---------------- per-class KV / Ksum reduction (compact, bf16 inputs) -------
// Per-chunk private slots (plain stores, no memset/atomics).
__global__ __launch_bounds__(256) void lft_kv_kernel(
    const ushort* __restrict__ kcB, const ushort* __restrict__ vcB,
    const int* __restrict__ cmetaB,
    float* kvbB, float* ksbB, int sideSrc0)
{
    int side = sideSrc0 + (blockIdx.z >> 6);
    int zz = blockIdx.z & 63;
    int chunk = blockIdx.x, c = blockIdx.y;
    int b = zz >> 3, h = zz & 7;
    const int* cmeta = cmetaB + side * 128;
    int cstart = cmeta[(b * 8 + c) * 2], n = cmeta[(b * 8 + c) * 2 + 1];
    int per = (n + KV_NCH - 1) / KV_NCH;
    int s0 = chunk * per;
    int s1 = min(s0 + per, n);
    const ushort* phik = kcB + (long)side * CAP * 256;
    const ushort* vmat = vcB + (long)side * CAP * 256;
    int slot = side * KV_NCH + chunk;
    float* kv = kvbB + (long)slot * 524288;
    float* ksum = ksbB + (long)slot * 16384;
    int t = threadIdx.x;
    __shared__ float kb[8][32];
    __shared__ float vb[8][32];
    int od = t >> 3, oe = (t & 7) << 2;
    int lt = t >> 5, ld = t & 31;
    float a0 = 0.f, a1 = 0.f, a2 = 0.f, a3 = 0.f, ak = 0.f;
    for (int s = s0; s < s1; s += 8) {
        float kval = 0.f, vval = 0.f;
        if (s + lt < s1) {
            long bse = (long)(cstart + s + lt) * 256 + h * 32 + ld;
            kval = b2f(phik[bse]);
            vval = b2f(vmat[bse]);
        }
        __syncthreads();
        kb[lt][ld] = kval;
        vb[lt][ld] = vval;
        __syncthreads();
#pragma unroll
        for (int j = 0; j < 8; j++) {
            float kd = kb[j][od];
            float4 vv = *(const float4*)&vb[j][oe];
            a0 += kd * vv.x; a1 += kd * vv.y; a2 += kd * vv.z; a3 += kd * vv.w;
            ak += kd;
        }
    }
    float* dst = kv + (((long)(b * NPROTO + c) * 8 + h) << 10) + od * 32 + oe;
    dst[0] = a0; dst[1] = a1; dst[2] = a2; dst[3] = a3;
    if ((t & 7) == 0)
        ksum[(((long)(b * NPROTO + c) * 8 + h) << 5) + od] = ak;
}

// ---------------- msg via MFMA; kv fragments = sum of KV_NCH chunk slots -----
__global__ __launch_bounds__(256) void lft_msg_kernel(
    const ushort* __restrict__ qcB, const float* __restrict__ kvbB,
    const float* __restrict__ ksbB, const int* __restrict__ cmetaB,
    ushort* __restrict__ msgcB, int sideX0, int sideKV0)
{
    int add = blockIdx.z >> 3, b = blockIdx.z & 7;
    int sideX = sideX0 + add, sideKV = sideKV0 + add;
    int chunk = blockIdx.x, c = blockIdx.y;
    const int* cmeta = cmetaB + sideX * 128;
    int cstart = cmeta[(b * 8 + c) * 2], n = cmeta[(b * 8 + c) * 2 + 1];
    int per = (n + MSG_NCH - 1) / MSG_NCH;
    int s0 = chunk * per, s1 = min(s0 + per, n);
    if (s0 >= s1) return;
    const ushort* pq = qcB + (long)sideX * CAP * 256;
    ushort* msg = msgcB + (long)sideX * CAP * 256;
    int t = threadIdx.x;
    int wave = t >> 6, lane = t & 63;
    int l16 = lane & 15, quad = lane >> 4;
    int bc = b * 8 + c;
    short8 bfr[2][3];
#pragma unroll
    for (int hh = 0; hh < 2; hh++) {
        int h = wave * 2 + hh;
        long kvoff = ((long)bc * 8 + h) * 1024;
        long ksoff = ((long)bc * 8 + h) * 32;
#pragma unroll
        for (int nt = 0; nt < 2; nt++)
#pragma unroll
            for (int j = 0; j < 8; j++) {
                float v = 0.f;
#pragma unroll
                for (int ch = 0; ch < KV_NCH; ch++)
                    v += kvbB[(long)(sideKV * KV_NCH + ch) * 524288 + kvoff
                              + (quad * 8 + j) * 32 + nt * 16 + l16];
                bfr[hh][nt][j] = (short)f2b(v);
            }
#pragma unroll
        for (int j = 0; j < 8; j++) {
            float v = 0.f;
#pragma unroll
            for (int ch = 0; ch < KV_NCH; ch++)
                v += ksbB[(long)(sideKV * KV_NCH + ch) * 16384 + ksoff + quad * 8 + j];
            bfr[hh][2][j] = (l16 == 0) ? (short)f2b(v) : (short)0;
        }
    }
    for (int s = s0; s < s1; s += 16) {
        long rowA = cstart + min(s + l16, s1 - 1);
#pragma unroll
        for (int hh = 0; hh < 2; hh++) {
            int h = wave * 2 + hh;
            short8 a = *(const short8*)&pq[rowA * 256 + h * 32 + quad * 8];
            floatx4 n0 = {}, n1 = {}, dd = {};
            n0 = __builtin_amdgcn_mfma_f32_16x16x32_bf16(a, bfr[hh][0], n0, 0, 0, 0);
            n1 = __builtin_amdgcn_mfma_f32_16x16x32_bf16(a, bfr[hh][1], n1, 0, 0, 0);
            dd = __builtin_amdgcn_mfma_f32_16x16x32_bf16(a, bfr[hh][2], dd, 0, 0, 0);
#pragma unroll
            for (int r = 0; r < 4; r++) {
                int rowi = s + quad * 4 + r;
                float den = __shfl(dd[r], lane & 48, 64);
                float inv = 1.f / (den + 1e-6f);
                if (rowi < s1) {
                    long base = (long)(cstart + rowi) * 256 + h * 32;
                    msg[base + l16]      = f2b(n0[r] * inv);
                    msg[base + 16 + l16] = f2b(n1[r] * inv);
                }
            }
        }
    }
}

extern "C" void kernel_launch(void* const* d_in, const int* in_sizes, int n_in,
                              void* d_out, int out_size, void* d_ws, size_t ws_size,
                              hipStream_t stream)
{
    (void)in_sizes; (void)n_in; (void)out_size; (void)ws_size;
    const float* feat0 = (const float*)d_in[0];
    const float* feat1 = (const float*)d_in[1];
    const int*   mask0 = (const int*)d_in[2];
    const int*   mask1 = (const int*)d_in[3];
    const float* f0wo  = (const float*)d_in[4];
    const float* f1wo  = (const float*)d_in[5];
    const float* proto = (const float*)d_in[6];
    const float* Wq = (const float*)d_in[7];
    const float* Wk = (const float*)d_in[8];
    const float* Wv = (const float*)d_in[9];
    const float* Wm = (const float*)d_in[10];
    const float* W1 = (const float*)d_in[11];
    const float* W2 = (const float*)d_in[12];
    const float* g1 = (const float*)d_in[13];
    const float* b1 = (const float*)d_in[14];
    const float* g2 = (const float*)d_in[15];
    const float* b2 = (const float*)d_in[16];
    float* out = (float*)d_out;
    float* ws = (float*)d_ws;

    // ---- workspace layout (side-strided compact buffers, CAP rows/side) ----
    const long FSZ = 9830400L;
    float* rc = ws;                               // 2*CAP*256 f
    ushort* kc = (ushort*)(rc + 2 * CAP * 256);   // 2*CAP*256 us  bf16
    ushort* vc = kc + 2 * CAP * 256;              // 2*CAP*256 us  bf16
    ushort* hid = vc + 2 * CAP * 256;             // 2*CAP*512 us
    ushort* xc   = hid + 2 * CAP * 512;
    ushort* msgc = xc + 2 * CAP * 256;
    ushort* qc   = msgc + 2 * CAP * 256;
    ushort* wb   = qc + 2 * CAP * 256;
    ushort* wb1  = wb + 16 * 65536;
    ushort* wb2  = wb1 + 4 * 262144;
    float* ksb = (float*)(wb2 + 4 * 131072);      // 2*KV_NCH*16384 f
    int* cls0 = (int*)(ksb + 2 * KV_NCH * 16384);
    int* cls1 = cls0 + 38400;
    int* gl   = cls1 + 38400;                     // 2*CAP ints
    int* meta = gl + 2 * CAP;
    int* minfo = meta + 256;
    int* cmeta = minfo + 20;
    // kvb aliases hid (dead between kv_kernel and w1-GEMM)
    float* kvb = (float*)hid;

    lft_wconv_kernel<<<dim3(8, 8, 16), 256, 0, stream>>>(Wq, Wk, Wv, Wm, 256, 256, 4, wb);
    lft_wconv_kernel<<<dim3(16, 16, 4), 256, 0, stream>>>(W1, W1, W1, W1, 512, 512, 1, wb1);
    lft_wconv_kernel<<<dim3(16, 8, 4), 256, 0, stream>>>(W2, W2, W2, W2, 512, 256, 1, wb2);
    hipMemcpyAsync(out + 20352000L, proto, 2048 * 4, hipMemcpyDeviceToDevice, stream);
    lft_class_kernel<<<600, 256, 0, stream>>>(f0wo, f1wo, mask0, mask1, proto,
                                              out, cls0, cls1);
    lft_invcopy_kernel<<<1200, 256, 0, stream>>>(feat0, feat1, cls0, cls1, out);
    lft_count_kernel<<<16, 256, 0, stream>>>(cls0, cls1, meta);
    lft_scan_kernel<<<1, 256, 0, stream>>>(meta, minfo, cmeta);
    lft_place_kernel<<<16, 256, 0, stream>>>(cls0, cls1, cmeta, gl);
    lft_gcast_kernel<<<1200, 256, 0, stream>>>(feat0, feat1, gl, minfo, xc, rc);

    dim3 blk(256);
    dim3 blkL(512);
    for (int li = 0; li < 4; li++) {
        const ushort* wq = wb + (size_t)(li * 4 + 0) * 65536;   // [wq|wk|wv|wm]
        const ushort* wk = wb + (size_t)(li * 4 + 1) * 65536;
        const ushort* wm = wb + (size_t)(li * 4 + 3) * 65536;
        const ushort* w1 = wb1 + (size_t)li * 262144;
        const ushort* w2 = wb2 + (size_t)li * 131072;
        const float* g1p = g1 + li * 256; const float* b1p = b1 + li * 256;
        const float* g2p = g2 + li * 256; const float* b2p = b2 + li * 256;
        bool last = (li == 3);

        if ((li & 1) == 0) {
            // ---- self-self, both sides combined (z=2) ----
            lft_mfma_gemm<<<dim3(6, 192, 2), blk, 0, stream>>>(
                xc, xc, 256, wq, (float*)kc, qc, (float*)vc, 768, 256, 3, minfo, 0);
            lft_kv_kernel<<<dim3(KV_NCH, 8, 128), blk, 0, stream>>>(kc, vc, cmeta, kvb, ksb, 0);
            lft_msg_kernel<<<dim3(MSG_NCH, 8, 16), blk, 0, stream>>>(qc, kvb, ksb, cmeta, msgc, 0, 0);
            lft_gemm_ln<<<dim3(384, 1, 2), blkL, 0, stream>>>(
                msgc, msgc, 256, wm, 256, g1p, b1p,
                nullptr, nullptr, gl, minfo, nullptr, msgc, 0);
            lft_mfma_gemm<<<dim3(4, 192, 2), blk, 0, stream>>>(
                xc, msgc, 256, w1, nullptr, hid, nullptr, 512, 512, 2, minfo, 0);
            lft_gemm_ln<<<dim3(384, 1, 2), blkL, 0, stream>>>(
                hid, hid, 512, w2, 512, g2p, b2p,
                rc, rc, gl, minfo, nullptr, xc, 0);
        } else {
            // ---- cross-self: q for both sides from OLD features ----
            lft_mfma_gemm<<<dim3(2, 192, 2), blk, 0, stream>>>(
                xc, xc, 256, wq, nullptr, qc, nullptr, 256, 256, 1, minfo, 0);
            // k|v from side1 (old) -> kc/vc side1
            lft_mfma_gemm<<<dim3(4, 192, 1), blk, 0, stream>>>(
                xc, xc, 256, wk, (float*)kc, nullptr, (float*)vc, 512, 256, 4, minfo, 1);
            lft_kv_kernel<<<dim3(KV_NCH, 8, 64), blk, 0, stream>>>(kc, vc, cmeta, kvb, ksb, 1);
            lft_msg_kernel<<<dim3(MSG_NCH, 8, 8), blk, 0, stream>>>(qc, kvb, ksb, cmeta, msgc, 0, 1);
            lft_gemm_ln<<<dim3(384, 1, 1), blkL, 0, stream>>>(
                msgc, msgc, 256, wm, 256, g1p, b1p,
                nullptr, nullptr, gl, minfo, nullptr, msgc, 0);
            lft_mfma_gemm<<<dim3(4, 192, 1), blk, 0, stream>>>(
                xc, msgc, 256, w1, nullptr, hid, nullptr, 512, 512, 2, minfo, 0);
            lft_gemm_ln<<<dim3(384, 1, 1), blkL, 0, stream>>>(
                hid, hid, 512, w2, 512, g2p, b2p,
                rc, last ? nullptr : rc, gl, minfo, last ? out : nullptr, xc, 0);
            // ---- side1 attends UPDATED side0 ----
            lft_mfma_gemm<<<dim3(4, 192, 1), blk, 0, stream>>>(
                xc, xc, 256, wk, (float*)kc, nullptr, (float*)vc, 512, 256, 4, minfo, 0);
            lft_kv_kernel<<<dim3(KV_NCH, 8, 64), blk, 0, stream>>>(kc, vc, cmeta, kvb, ksb, 0);
            lft_msg_kernel<<<dim3(MSG_NCH, 8, 8), blk, 0, stream>>>(qc, kvb, ksb, cmeta, msgc, 1, 0);
            lft_gemm_ln<<<dim3(384, 1, 1), blkL, 0, stream>>>(
                msgc, msgc, 256, wm, 256, g1p, b1p,
                nullptr, nullptr, gl, minfo, nullptr, msgc, 1);
            lft_mfma_gemm<<<dim3(4, 192, 1), blk, 0, stream>>>(
                xc, msgc, 256, w1, nullptr, hid, nullptr, 512, 512, 2, minfo, 1);
            lft_gemm_ln<<<dim3(384, 1, 1), blkL, 0, stream>>>(
                hid, hid, 512, w2, 512, g2p, b2p,
                rc, last ? nullptr : rc, gl, minfo, last ? out : nullptr,
                last ? nullptr : xc, 1);
        }
    }
}

// Round 19
// 1211.550 us; speedup vs baseline: 1.3609x; 1.0406x over previous
//
#include <hip/hip_runtime.h>
#include <math.h>

#define NPROTO 8
#define KV_NCH 4
#define MSG_NCH 8
#define CAP 24576L            // compact rows per side (Mv ~= 19200 +- ~200)

typedef __attribute__((ext_vector_type(8))) short short8;
typedef __attribute__((ext_vector_type(4))) float floatx4;

static __device__ __forceinline__ ushort f2b(float f) {
    unsigned u = __builtin_bit_cast(unsigned, f);
    unsigned r = (u + 0x7fffu + ((u >> 16) & 1u)) >> 16;
    return (ushort)r;
}

static __device__ __forceinline__ float b2f(ushort u) {
    return __builtin_bit_cast(float, (unsigned)u << 16);
}

static __device__ __forceinline__ float elu1(float v) {
    return v > 0.f ? v + 1.f : __expf(v);
}

// async 16B global -> LDS (linear dest: wave base + lane*16B)
#define GLOAD16(gp, lp) __builtin_amdgcn_global_load_lds( \
    (const __attribute__((address_space(1))) void*)(gp),  \
    (__attribute__((address_space(3))) void*)(lp), 16, 0, 0)

// full drain + barrier (gemm_ln's proven 2-phase structure)
#define WAIT_BAR() asm volatile("s_waitcnt vmcnt(0) lgkmcnt(0)\n\ts_barrier" ::: "memory")
// counted waits (mfma_gemm 3-buffer pipeline; 4 loads/thread/tile)
#define VMWAIT(N) asm volatile("s_waitcnt vmcnt(" #N ")" ::: "memory")
#define BAR() __builtin_amdgcn_s_barrier()

// swizzle of the 16B-group index within a 32-col bf16 row (4 groups/row)
static __device__ __forceinline__ int swz(int r) { return (r >> 1) & 3; }

// ---------------- prototype projection / argmax-class kernel ----------------
__global__ __launch_bounds__(256) void lft_class_kernel(
    const float* __restrict__ f0wo, const float* __restrict__ f1wo,
    const int* __restrict__ mask0, const int* __restrict__ mask1,
    const float* __restrict__ proto,
    float* out, int* cls0, int* cls1)
{
    __shared__ float pr[2048];          // proto [8][256]
    __shared__ float tile[128][68];     // [token][ch chunk], stride 68
    __shared__ float sm[128][8];
    int t = threadIdx.x;
    *(float4*)&pr[t * 4]        = *(const float4*)&proto[t * 4];
    *(float4*)&pr[1024 + t * 4] = *(const float4*)&proto[1024 + t * 4];
    long tok0 = (long)blockIdx.x * 128;
    const float* fsrc; const int* msrc; float* fpout; float* clsout; int* clsarr; long tbase;
    if (tok0 < 38400) {
        tbase = tok0; fsrc = f0wo; msrc = mask0;
        fpout = out + 19737600L; clsout = out + 19660800L; clsarr = cls0;
    } else {
        tbase = tok0 - 38400; fsrc = f1wo; msrc = mask1;
        fpout = out + 20044800L; clsout = out + 19699200L; clsarr = cls1;
    }
    int tok = t & 127, half = t >> 7;
    float s[4] = {};
    int r0 = t >> 4;            // 0..15
    int c4 = (t & 15) << 2;     // 0..60
    for (int ct = 0; ct < 4; ct++) {
        __syncthreads();
#pragma unroll
        for (int rr = 0; rr < 8; rr++) {
            int row = rr * 16 + r0;
            float4 v = *(const float4*)&fsrc[(tbase + row) * 256 + ct * 64 + c4];
            *(float4*)&tile[row][c4] = v;
        }
        __syncthreads();
#pragma unroll
        for (int cc = 0; cc < 16; cc++) {
            float4 f = *(const float4*)&tile[tok][cc << 2];
#pragma unroll
            for (int p = 0; p < 4; p++) {
                float4 pv = *(const float4*)&pr[(half * 4 + p) * 256 + ct * 64 + (cc << 2)];
                s[p] += f.x * pv.x + f.y * pv.y + f.z * pv.z + f.w * pv.w;
            }
        }
    }
#pragma unroll
    for (int p = 0; p < 4; p++) {
        fpout[(tbase + tok) * 8 + half * 4 + p] = s[p];
        sm[tok][half * 4 + p] = s[p];
    }
    __syncthreads();
    if (t < 128) {
        int best = 0; float bv = sm[t][0];
#pragma unroll
        for (int p = 1; p < 8; p++) { if (sm[t][p] > bv) { bv = sm[t][p]; best = p; } }
        clsout[tbase + t] = (float)best;
        clsarr[tbase + t] = msrc[tbase + t] ? best : -1;
    }
}

// ---------------- copy ONLY invalid-token rows of feat into out --------------
__global__ __launch_bounds__(256) void lft_invcopy_kernel(
    const float* __restrict__ f0, const float* __restrict__ f1,
    const int* __restrict__ cls0, const int* __restrict__ cls1,
    float* out)
{
    int w = blockIdx.x * 4 + (threadIdx.x >> 6);   // 0..4799
    int lane = threadIdx.x & 63;
    for (long row = w; row < 76800; row += 4800) {
        int side = row >= 38400;
        long r = row - (long)side * 38400;
        int c = side ? cls1[r] : cls0[r];
        if (c < 0) {
            const float* src = side ? f1 : f0;
            float4 v = *(const float4*)&src[r * 256 + lane * 4];
            *(float4*)&out[(long)side * 9830400L + r * 256 + lane * 4] = v;
        }
    }
}

// ---------------- per-(L,b) class counts -> meta {base,cnt} ------------------
__global__ __launch_bounds__(256) void lft_count_kernel(
    const int* __restrict__ cls0, const int* __restrict__ cls1, int* meta)
{
    int g = blockIdx.x; int L = g >> 3, b = g & 7;
    const int* cls = (L ? cls1 : cls0) + b * 4800;
    int* mt = meta + (L * 8 + b) * 16;
    __shared__ int cnt[8];
    int t = threadIdx.x;
    if (t < 8) cnt[t] = 0;
    __syncthreads();
    for (int tok = t; tok < 4800; tok += 256) {
        int c = cls[tok];
        if (c >= 0) atomicAdd(&cnt[c], 1);
    }
    __syncthreads();
    if (t == 0) {
        int s = 0;
        for (int c = 0; c < 8; c++) { mt[c * 2] = s; mt[c * 2 + 1] = cnt[c]; s += cnt[c]; }
    }
}

// ---------------- cross-batch scan: minfo (Mv, boff) + compact cmeta ---------
__global__ __launch_bounds__(256) void lft_scan_kernel(
    const int* __restrict__ meta, int* minfo, int* cmeta)
{
    int t = threadIdx.x;
    __shared__ int nb[16];
    if (t < 16) {
        int s = 0;
        for (int c = 0; c < 8; c++) s += meta[t * 16 + c * 2 + 1];
        nb[t] = s;
    }
    __syncthreads();
    if (t == 0) {
        int off = 0;
        for (int b = 0; b < 8; b++) { minfo[4 + b] = off; off += nb[b]; }
        minfo[2] = off; minfo[0] = (off + 127) & ~127;
        off = 0;
        for (int b = 0; b < 8; b++) { minfo[12 + b] = off; off += nb[8 + b]; }
        minfo[3] = off; minfo[1] = (off + 127) & ~127;
    }
    __syncthreads();
    if (t < 128) {
        int L = t >> 6, b = (t >> 3) & 7, c = t & 7;
        cmeta[t * 2]     = minfo[4 + L * 8 + b] + meta[(L * 8 + b) * 16 + c * 2];
        cmeta[t * 2 + 1] = meta[(L * 8 + b) * 16 + c * 2 + 1];
    }
}

// ---------------- place valid tokens into compact gather lists ---------------
__global__ __launch_bounds__(256) void lft_place_kernel(
    const int* __restrict__ cls0, const int* __restrict__ cls1,
    const int* __restrict__ cmeta, int* gl)
{
    int g = blockIdx.x; int L = g >> 3, b = g & 7;
    const int* cls = (L ? cls1 : cls0) + b * 4800;
    int* glp = gl + L * CAP;
    __shared__ int pos[8];
    int t = threadIdx.x;
    if (t < 8) pos[t] = cmeta[(L * 64 + b * 8 + t) * 2];
    __syncthreads();
    for (int tok = t; tok < 4800; tok += 256) {
        int c = cls[tok];
        if (c >= 0) { int p = atomicAdd(&pos[c], 1); glp[p] = b * 4800 + tok; }
    }
}

// ---------------- gather-cast: compact bf16 x + compact fp32 resid -----------
__global__ __launch_bounds__(256) void lft_gcast_kernel(
    const float* __restrict__ f0, const float* __restrict__ f1,
    const int* __restrict__ gl, const int* __restrict__ minfo,
    ushort* xc, float* rc)
{
    int blk = blockIdx.x;
    int side = blk >= 600 ? 1 : 0;
    int i0 = (blk - side * 600) * 4 + (threadIdx.x >> 6);
    int mv = minfo[2 + side];
    const int* glp = gl + side * CAP;
    const float* f = side ? f1 : f0;
    ushort* xcp = xc + side * CAP * 256;
    float* rcp = rc + side * CAP * 256;
    int lane = threadIdx.x & 63;
    for (int i = i0; i < mv; i += 2400) {
        long src = (long)glp[i] * 256 + lane * 4;
        float4 v = *(const float4*)&f[src];
        long dst = (long)i * 256 + lane * 4;
        *(float4*)&rcp[dst] = v;
        ushort4 u; u.x = f2b(v.x); u.y = f2b(v.y); u.z = f2b(v.z); u.w = f2b(v.w);
        *(ushort4*)&xcp[dst] = u;
    }
}

// ---------------- weight convert + transpose: Wt[n*K+k] = bf16(W[k*N+n]) ----
__global__ __launch_bounds__(256) void lft_wconv_kernel(
    const float* W0, const float* W1p, const float* W2p, const float* W3p,
    int K, int N, int nTypes, ushort* dst)
{
    int z = blockIdx.z;
    int li = z / nTypes, mi = z % nTypes;
    const float* srcs[4] = {W0, W1p, W2p, W3p};
    const float* src = srcs[mi] + (size_t)li * K * N;
    ushort* outp = dst + (size_t)z * K * N;
    __shared__ float tile[32][33];
    int k0 = blockIdx.x * 32, n0 = blockIdx.y * 32;
    int t = threadIdx.x;
    int r = t >> 3, c4 = (t & 7) << 2;
    float4 v = *(const float4*)&src[(size_t)(k0 + r) * N + n0 + c4];
    tile[r][c4] = v.x; tile[r][c4 + 1] = v.y; tile[r][c4 + 2] = v.z; tile[r][c4 + 3] = v.w;
    __syncthreads();
    ushort4 o;
    o.x = f2b(tile[c4 + 0][r]);
    o.y = f2b(tile[c4 + 1][r]);
    o.z = f2b(tile[c4 + 2][r]);
    o.w = f2b(tile[c4 + 3][r]);
    *(ushort4*)&outp[(size_t)(n0 + r) * K + k0 + c4] = o;
}

// ---------------- bf16 MFMA GEMM over COMPACT rows ---------------------------
// XCD-aware block swizzle (T1). 3-buffer counted-vmcnt pipeline. 128x128 tile.
// Epilogue: LDS-transposed coalesced bf16 stores (full 16-elem spans).
// act: 1 elu+1 (q); 2 relu (hid, ldc=512); act 3 qkv N=768; act 4 kv N=512.
__global__ __launch_bounds__(256) void lft_mfma_gemm(
    const ushort* __restrict__ A0b, const ushort* __restrict__ A1b, int kSplit,
    const ushort* __restrict__ Wt,
    float* Cf, ushort* Cb, float* Cv, int N, int K, int act,
    const int* __restrict__ minfo, int side0)
{
    __shared__ ushort As[3][128 * 32];
    __shared__ ushort Bs[3][128 * 32];
    int gx = gridDim.x, gy = gridDim.y;
    int G = gx * gy * gridDim.z;
    int orig = (blockIdx.z * gy + blockIdx.y) * gx + blockIdx.x;
    int wid = ((orig & 7) * (G >> 3)) + (orig >> 3);   // G % 8 == 0 (all grids)
    int bx = wid % gx; int rest = wid / gx;
    int by = rest % gy; int bz = rest / gy;
    int side = side0 + bz;
    int m0 = by << 7;
    if (m0 >= minfo[side]) return;
    int n0 = bx << 7;
    const ushort* A0 = A0b + (long)side * CAP * kSplit;
    const ushort* A1 = A1b + (long)side * CAP * (K - kSplit);
    long so256 = (long)side * CAP * 256;
    long soN = (long)side * CAP * N;
    int t = threadIdx.x;
    int wv = t >> 6, lane = t & 63;
    int wm = wv >> 1, wn = wv & 1;
    int l16 = lane & 15, quad = lane >> 4;
    floatx4 acc[4][4] = {};

    int lrow = lane >> 2;
    int lcg = lane & 3;

    auto stage = [&](int buf, int k0) {
        const ushort* Asrc; int kcol, ldA;
        if (k0 < kSplit) { Asrc = A0; kcol = k0;          ldA = kSplit; }
        else             { Asrc = A1; kcol = k0 - kSplit; ldA = K - kSplit; }
        ushort* Ab = &As[buf][0];
        ushort* Bb = &Bs[buf][0];
#pragma unroll
        for (int s = 0; s < 2; s++) {
            int r = s * 64 + wv * 16 + lrow;
            int cgA = (lcg ^ swz(r)) << 3;
            GLOAD16(&Asrc[(size_t)(m0 + r) * ldA + kcol + cgA], &Ab[(s * 64 + wv * 16) * 32]);
            GLOAD16(&Wt[(size_t)(n0 + r) * K + k0 + cgA], &Bb[(s * 64 + wv * 16) * 32]);
        }
    };

    auto compute = [&](int buf) {
        const ushort* Ab = &As[buf][0];
        const ushort* Bb = &Bs[buf][0];
        short8 af[4], bfr[4];
#pragma unroll
        for (int i = 0; i < 4; i++) {
            int rA = wm * 64 + i * 16 + l16;
            int rB = wn * 64 + i * 16 + l16;
            af[i]  = *(const short8*)&Ab[rA * 32 + ((quad ^ swz(rA)) << 3)];
            bfr[i] = *(const short8*)&Bb[rB * 32 + ((quad ^ swz(rB)) << 3)];
        }
        __builtin_amdgcn_s_setprio(1);
#pragma unroll
        for (int i = 0; i < 4; i++)
#pragma unroll
            for (int j = 0; j < 4; j++)
                acc[i][j] = __builtin_amdgcn_mfma_f32_16x16x32_bf16(af[i], bfr[j], acc[i][j], 0, 0, 0);
        __builtin_amdgcn_s_setprio(0);
    };

    int nt = K >> 5;               // 8 or 16
    stage(0, 0);
    stage(1, 32);
    int cur = 0;
    for (int tt = 0; tt < nt; ++tt) {
        if (tt + 2 < nt) {
            int nb = cur + 2; if (nb >= 3) nb -= 3;
            stage(nb, (tt + 2) << 5);
            VMWAIT(8);             // tile tt done; tt+1, tt+2 in flight
        } else if (tt + 2 == nt) {
            VMWAIT(4);
        } else {
            VMWAIT(0);
        }
        BAR();
        compute(cur);
        if (tt + 1 < nt) BAR();
        cur = cur + 1 == 3 ? 0 : cur + 1;
    }

    // ---- LDS-transposed coalesced bf16 epilogue ----
    ushort* dst; int ncol0; int amode; long base; int ldc;
    if (act == 3) {
        base = so256; ldc = 256;
        if (n0 < 256)      { dst = Cb;          ncol0 = n0;       amode = 1; }
        else if (n0 < 512) { dst = (ushort*)Cf; ncol0 = n0 - 256; amode = 1; }
        else               { dst = (ushort*)Cv; ncol0 = n0 - 512; amode = 0; }
    } else if (act == 4) {
        base = so256; ldc = 256;
        if (n0 < 256) { dst = (ushort*)Cf; ncol0 = n0;       amode = 1; }
        else          { dst = (ushort*)Cv; ncol0 = n0 - 256; amode = 0; }
    } else {  // act 1 (q, elu) or act 2 (hid, relu)
        base = soN; ldc = N;
        dst = Cb; ncol0 = n0; amode = (act == 1) ? 1 : 2;
    }
    ushort* tb = &As[0][0];        // 32 x 144 transpose tile (aliases As)
    int lr = t >> 3;               // 0..31 (8 threads/row)
    int cs = (t & 7) << 4;         // element offset 0,16,..,112 (16 elems = 32B)
    int wmr = lr >> 4, rloc = lr & 15;
#pragma unroll
    for (int i = 0; i < 4; i++) {
        __syncthreads();           // prior LDS reads (compute / tb) complete
#pragma unroll
        for (int j = 0; j < 4; j++) {
#pragma unroll
            for (int r = 0; r < 4; r++) {
                float v = acc[i][j][r];
                if (amode == 1)      v = elu1(v);
                else if (amode == 2) v = fmaxf(v, 0.f);
                tb[(wm * 16 + quad * 4 + r) * 144 + wn * 64 + j * 16 + l16] = f2b(v);
            }
        }
        __syncthreads();
        long row = m0 + wmr * 64 + i * 16 + rloc;
        short8 v0 = *(const short8*)&tb[lr * 144 + cs];
        short8 v1 = *(const short8*)&tb[lr * 144 + cs + 8];
        *(short8*)&dst[base + row * ldc + ncol0 + cs] = v0;
        *(short8*)&dst[base + row * ldc + ncol0 + cs + 8] = v1;
    }
}

// ---------------- fused GEMM (N=256) + row-LN over COMPACT rows -------------
// 512 threads, M=64 tile (grid.x=384 per side, early-exit), 8 waves (2m x 4n).
// Epilogue: per i-stripe LDS fp32 transpose (unioned over As/Bs) -> linear
// phase with float4 rcIn read + float4 rcOut / ushort4 outB stores (coalesced).
__global__ __launch_bounds__(512) void lft_gemm_ln(
    const ushort* __restrict__ A0b, const ushort* __restrict__ A1b, int kSplit,
    const ushort* __restrict__ Wt, int K,
    const float* __restrict__ g, const float* __restrict__ bb,
    const float* __restrict__ rcInB, float* rcOutB,
    const int* __restrict__ glB, const int* __restrict__ minfo,
    float* outScB, ushort* __restrict__ outBB, int side0)
{
    __shared__ union {
        struct { ushort As[2][64 * 32]; ushort Bs[2][256 * 32]; } s;  // 40KB
        float tile[32][260];                                          // 33.3KB
    } u;
    __shared__ float gs[256], bs[256];
    __shared__ float psum[4][64], psq[4][64];
    int side = side0 + blockIdx.z;
    long m0 = (long)blockIdx.x << 6;
    if (m0 >= minfo[side]) return;
    const ushort* A0 = A0b + (long)side * CAP * kSplit;
    const ushort* A1 = A1b + (long)side * CAP * (K - kSplit);
    long so = (long)side * CAP * 256;
    int t = threadIdx.x;
    int wv = t >> 6, lane = t & 63;
    int wm = wv >> 2, wn = wv & 3;
    int l16 = lane & 15, quad = lane >> 4;
    if (t < 256) { gs[t] = g[t]; bs[t] = bb[t]; }
    floatx4 acc[2][4] = {};

    int lrow = lane >> 2;
    int lcg = lane & 3;

    auto stage = [&](int buf, int k0) {
        const ushort* Asrc; int kcol, ldA;
        if (k0 < kSplit) { Asrc = A0; kcol = k0;          ldA = kSplit; }
        else             { Asrc = A1; kcol = k0 - kSplit; ldA = K - kSplit; }
        if (wv < 4) {                                      // A rows 0..63
            int r = wv * 16 + lrow;
            int cgA = (lcg ^ swz(r)) << 3;
            GLOAD16(&Asrc[(m0 + r) * ldA + kcol + cgA], &u.s.As[buf][(wv * 16) * 32]);
        }
#pragma unroll
        for (int s = 0; s < 2; s++) {                      // B rows 0..255
            int r = s * 128 + wv * 16 + lrow;
            int cgB = (lcg ^ swz(r)) << 3;
            GLOAD16(&Wt[(size_t)r * K + k0 + cgB], &u.s.Bs[buf][(s * 128 + wv * 16) * 32]);
        }
    };

    int nt = K >> 5;
    stage(0, 0);
    WAIT_BAR();
    int cur = 0;
    for (int tt = 0; tt < nt; ++tt) {
        if (tt + 1 < nt) stage(cur ^ 1, (tt + 1) << 5);
        const ushort* Ab = &u.s.As[cur][0];
        const ushort* Bb = &u.s.Bs[cur][0];
        short8 af[2], bfr[4];
#pragma unroll
        for (int i = 0; i < 2; i++) {
            int rA = wm * 32 + i * 16 + l16;
            af[i] = *(const short8*)&Ab[rA * 32 + ((quad ^ swz(rA)) << 3)];
        }
#pragma unroll
        for (int j = 0; j < 4; j++) {
            int rB = wn * 64 + j * 16 + l16;
            bfr[j] = *(const short8*)&Bb[rB * 32 + ((quad ^ swz(rB)) << 3)];
        }
#pragma unroll
        for (int i = 0; i < 2; i++)
#pragma unroll
            for (int j = 0; j < 4; j++)
                acc[i][j] = __builtin_amdgcn_mfma_f32_16x16x32_bf16(af[i], bfr[j], acc[i][j], 0, 0, 0);
        if (tt + 1 < nt) { WAIT_BAR(); cur ^= 1; }
    }
    // per-row partial sums (this wave's 64 cols) -> LDS
#pragma unroll
    for (int i = 0; i < 2; i++) {
#pragma unroll
        for (int r = 0; r < 4; r++) {
            float s = 0.f, q = 0.f;
#pragma unroll
            for (int j = 0; j < 4; j++) { float v = acc[i][j][r]; s += v; q += v * v; }
#pragma unroll
            for (int o = 8; o >= 1; o >>= 1) {
                s += __shfl_xor(s, o, 64);
                q += __shfl_xor(q, o, 64);
            }
            if (l16 == 0) {
                int row = wm * 32 + i * 16 + quad * 4 + r;
                psum[wn][row] = s; psq[wn][row] = q;
            }
        }
    }
    __syncthreads();
    if (t < 64) {
        float s = psum[0][t] + psum[1][t] + psum[2][t] + psum[3][t];
        float q = psq[0][t] + psq[1][t] + psq[2][t] + psq[3][t];
        float mean = s * (1.0f / 256.0f);
        float var = q * (1.0f / 256.0f) - mean * mean;
        psum[0][t] = mean;
        psq[0][t] = rsqrtf(var + 1e-5f);
    }
    __syncthreads();
    int mvE = minfo[2 + side];
    const float* rcIn = rcInB ? rcInB + so : nullptr;
    float* rcOut = rcOutB ? rcOutB + so : nullptr;
    const int* glp = glB + side * CAP;
    float* outSc = outScB ? outScB + (long)side * 9830400L : nullptr;
    ushort* outB = outBB ? outBB + so : nullptr;
    // ---- coalesced epilogue: 2 stripes of 32 tile-rows ----
#pragma unroll
    for (int i = 0; i < 2; i++) {
        // phase A: LN (no resid) into fp32 tile
#pragma unroll
        for (int r = 0; r < 4; r++) {
            int rloc = wm * 32 + i * 16 + quad * 4 + r;
            int tr = wm * 16 + quad * 4 + r;
            float mean = psum[0][rloc], rstd = psq[0][rloc];
#pragma unroll
            for (int j = 0; j < 4; j++) {
                int col = wn * 64 + j * 16 + l16;
                u.tile[tr][col] = (acc[i][j][r] - mean) * rstd * gs[col] + bs[col];
            }
        }
        __syncthreads();
        // phase B: linear coalesced residual-add + stores
#pragma unroll
        for (int e = 0; e < 4; e++) {
            int idx = e * 512 + t;          // 0..2047
            int tr = idx >> 6;              // tile row 0..31
            int c4 = (idx & 63) << 2;       // col 0..252 step 4
            long arow = m0 + (long)((tr >> 4) * 32 + i * 16 + (tr & 15));
            float4 v = *(float4*)&u.tile[tr][c4];
            if (rcIn) {
                float4 rv = *(const float4*)&rcIn[arow * 256 + c4];
                v.x += rv.x; v.y += rv.y; v.z += rv.z; v.w += rv.w;
            }
            if (rcOut) *(float4*)&rcOut[arow * 256 + c4] = v;
            if (outSc && arow < mvE)
                *(float4*)&outSc[(long)glp[arow] * 256 + c4] = v;
            if (outB) {
                ushort4 uo; uo.x = f2b(v.x); uo.y = f2b(v.y);
                uo.z = f2b(v.z); uo.w = f2b(v.w);
                *(ushort4*)&outB[arow * 256 + c4] = uo;
            }
        }
        if (i == 0) __syncthreads();
    }
}

// ---------------- per-class KV / Ksum reduction (compact, bf16 inputs) -------
// Per-chunk private slots (plain stores, no memset/atomics).
__global__ __launch_bounds__(256) void lft_kv_kernel(
    const ushort* __restrict__ kcB, const ushort* __restrict__ vcB,
    const int* __restrict__ cmetaB,
    float* kvbB, float* ksbB, int sideSrc0)
{
    int side = sideSrc0 + (blockIdx.z >> 6);
    int zz = blockIdx.z & 63;
    int chunk = blockIdx.x, c = blockIdx.y;
    int b = zz >> 3, h = zz & 7;
    const int* cmeta = cmetaB + side * 128;
    int cstart = cmeta[(b * 8 + c) * 2], n = cmeta[(b * 8 + c) * 2 + 1];
    int per = (n + KV_NCH - 1) / KV_NCH;
    int s0 = chunk * per;
    int s1 = min(s0 + per, n);
    const ushort* phik = kcB + (long)side * CAP * 256;
    const ushort* vmat = vcB + (long)side * CAP * 256;
    int slot = side * KV_NCH + chunk;
    float* kv = kvbB + (long)slot * 524288;
    float* ksum = ksbB + (long)slot * 16384;
    int t = threadIdx.x;
    __shared__ float kb[8][32];
    __shared__ float vb[8][32];
    int od = t >> 3, oe = (t & 7) << 2;
    int lt = t >> 5, ld = t & 31;
    float a0 = 0.f, a1 = 0.f, a2 = 0.f, a3 = 0.f, ak = 0.f;
    for (int s = s0; s < s1; s += 8) {
        float kval = 0.f, vval = 0.f;
        if (s + lt < s1) {
            long bse = (long)(cstart + s + lt) * 256 + h * 32 + ld;
            kval = b2f(phik[bse]);
            vval = b2f(vmat[bse]);
        }
        __syncthreads();
        kb[lt][ld] = kval;
        vb[lt][ld] = vval;
        __syncthreads();
#pragma unroll
        for (int j = 0; j < 8; j++) {
            float kd = kb[j][od];
            float4 vv = *(const float4*)&vb[j][oe];
            a0 += kd * vv.x; a1 += kd * vv.y; a2 += kd * vv.z; a3 += kd * vv.w;
            ak += kd;
        }
    }
    float* dst = kv + (((long)(b * NPROTO + c) * 8 + h) << 10) + od * 32 + oe;
    dst[0] = a0; dst[1] = a1; dst[2] = a2; dst[3] = a3;
    if ((t & 7) == 0)
        ksum[(((long)(b * NPROTO + c) * 8 + h) << 5) + od] = ak;
}

// ---------------- msg via MFMA; kv fragments = sum of KV_NCH chunk slots -----
__global__ __launch_bounds__(256) void lft_msg_kernel(
    const ushort* __restrict__ qcB, const float* __restrict__ kvbB,
    const float* __restrict__ ksbB, const int* __restrict__ cmetaB,
    ushort* __restrict__ msgcB, int sideX0, int sideKV0)
{
    int add = blockIdx.z >> 3, b = blockIdx.z & 7;
    int sideX = sideX0 + add, sideKV = sideKV0 + add;
    int chunk = blockIdx.x, c = blockIdx.y;
    const int* cmeta = cmetaB + sideX * 128;
    int cstart = cmeta[(b * 8 + c) * 2], n = cmeta[(b * 8 + c) * 2 + 1];
    int per = (n + MSG_NCH - 1) / MSG_NCH;
    int s0 = chunk * per, s1 = min(s0 + per, n);
    if (s0 >= s1) return;
    const ushort* pq = qcB + (long)sideX * CAP * 256;
    ushort* msg = msgcB + (long)sideX * CAP * 256;
    int t = threadIdx.x;
    int wave = t >> 6, lane = t & 63;
    int l16 = lane & 15, quad = lane >> 4;
    int bc = b * 8 + c;
    short8 bfr[2][3];
#pragma unroll
    for (int hh = 0; hh < 2; hh++) {
        int h = wave * 2 + hh;
        long kvoff = ((long)bc * 8 + h) * 1024;
        long ksoff = ((long)bc * 8 + h) * 32;
#pragma unroll
        for (int nt = 0; nt < 2; nt++)
#pragma unroll
            for (int j = 0; j < 8; j++) {
                float v = 0.f;
#pragma unroll
                for (int ch = 0; ch < KV_NCH; ch++)
                    v += kvbB[(long)(sideKV * KV_NCH + ch) * 524288 + kvoff
                              + (quad * 8 + j) * 32 + nt * 16 + l16];
                bfr[hh][nt][j] = (short)f2b(v);
            }
#pragma unroll
        for (int j = 0; j < 8; j++) {
            float v = 0.f;
#pragma unroll
            for (int ch = 0; ch < KV_NCH; ch++)
                v += ksbB[(long)(sideKV * KV_NCH + ch) * 16384 + ksoff + quad * 8 + j];
            bfr[hh][2][j] = (l16 == 0) ? (short)f2b(v) : (short)0;
        }
    }
    for (int s = s0; s < s1; s += 16) {
        long rowA = cstart + min(s + l16, s1 - 1);
#pragma unroll
        for (int hh = 0; hh < 2; hh++) {
            int h = wave * 2 + hh;
            short8 a = *(const short8*)&pq[rowA * 256 + h * 32 + quad * 8];
            floatx4 n0 = {}, n1 = {}, dd = {};
            n0 = __builtin_amdgcn_mfma_f32_16x16x32_bf16(a, bfr[hh][0], n0, 0, 0, 0);
            n1 = __builtin_amdgcn_mfma_f32_16x16x32_bf16(a, bfr[hh][1], n1, 0, 0, 0);
            dd = __builtin_amdgcn_mfma_f32_16x16x32_bf16(a, bfr[hh][2], dd, 0, 0, 0);
#pragma unroll
            for (int r = 0; r < 4; r++) {
                int rowi = s + quad * 4 + r;
                float den = __shfl(dd[r], lane & 48, 64);
                float inv = 1.f / (den + 1e-6f);
                if (rowi < s1) {
                    long base = (long)(cstart + rowi) * 256 + h * 32;
                    msg[base + l16]      = f2b(n0[r] * inv);
                    msg[base + 16 + l16] = f2b(n1[r] * inv);
                }
            }
        }
    }
}

extern "C" void kernel_launch(void* const* d_in, const int* in_sizes, int n_in,
                              void* d_out, int out_size, void* d_ws, size_t ws_size,
                              hipStream_t stream)
{
    (void)in_sizes; (void)n_in; (void)out_size; (void)ws_size;
    const float* feat0 = (const float*)d_in[0];
    const float* feat1 = (const float*)d_in[1];
    const int*   mask0 = (const int*)d_in[2];
    const int*   mask1 = (const int*)d_in[3];
    const float* f0wo  = (const float*)d_in[4];
    const float* f1wo  = (const float*)d_in[5];
    const float* proto = (const float*)d_in[6];
    const float* Wq = (const float*)d_in[7];
    const float* Wk = (const float*)d_in[8];
    const float* Wv = (const float*)d_in[9];
    const float* Wm = (const float*)d_in[10];
    const float* W1 = (const float*)d_in[11];
    const float* W2 = (const float*)d_in[12];
    const float* g1 = (const float*)d_in[13];
    const float* b1 = (const float*)d_in[14];
    const float* g2 = (const float*)d_in[15];
    const float* b2 = (const float*)d_in[16];
    float* out = (float*)d_out;
    float* ws = (float*)d_ws;

    // ---- workspace layout (side-strided compact buffers, CAP rows/side) ----
    const long FSZ = 9830400L;
    float* rc = ws;                               // 2*CAP*256 f
    ushort* kc = (ushort*)(rc + 2 * CAP * 256);   // 2*CAP*256 us  bf16
    ushort* vc = kc + 2 * CAP * 256;              // 2*CAP*256 us  bf16
    ushort* hid = vc + 2 * CAP * 256;             // 2*CAP*512 us
    ushort* xc   = hid + 2 * CAP * 512;
    ushort* msgc = xc + 2 * CAP * 256;
    ushort* qc   = msgc + 2 * CAP * 256;
    ushort* wb   = qc + 2 * CAP * 256;
    ushort* wb1  = wb + 16 * 65536;
    ushort* wb2  = wb1 + 4 * 262144;
    float* ksb = (float*)(wb2 + 4 * 131072);      // 2*KV_NCH*16384 f
    int* cls0 = (int*)(ksb + 2 * KV_NCH * 16384);
    int* cls1 = cls0 + 38400;
    int* gl   = cls1 + 38400;                     // 2*CAP ints
    int* meta = gl + 2 * CAP;
    int* minfo = meta + 256;
    int* cmeta = minfo + 20;
    // kvb aliases hid (dead between kv_kernel and w1-GEMM)
    float* kvb = (float*)hid;

    lft_wconv_kernel<<<dim3(8, 8, 16), 256, 0, stream>>>(Wq, Wk, Wv, Wm, 256, 256, 4, wb);
    lft_wconv_kernel<<<dim3(16, 16, 4), 256, 0, stream>>>(W1, W1, W1, W1, 512, 512, 1, wb1);
    lft_wconv_kernel<<<dim3(16, 8, 4), 256, 0, stream>>>(W2, W2, W2, W2, 512, 256, 1, wb2);
    hipMemcpyAsync(out + 20352000L, proto, 2048 * 4, hipMemcpyDeviceToDevice, stream);
    lft_class_kernel<<<600, 256, 0, stream>>>(f0wo, f1wo, mask0, mask1, proto,
                                              out, cls0, cls1);
    lft_invcopy_kernel<<<1200, 256, 0, stream>>>(feat0, feat1, cls0, cls1, out);
    lft_count_kernel<<<16, 256, 0, stream>>>(cls0, cls1, meta);
    lft_scan_kernel<<<1, 256, 0, stream>>>(meta, minfo, cmeta);
    lft_place_kernel<<<16, 256, 0, stream>>>(cls0, cls1, cmeta, gl);
    lft_gcast_kernel<<<1200, 256, 0, stream>>>(feat0, feat1, gl, minfo, xc, rc);

    dim3 blk(256);
    dim3 blkL(512);
    for (int li = 0; li < 4; li++) {
        const ushort* wq = wb + (size_t)(li * 4 + 0) * 65536;   // [wq|wk|wv|wm]
        const ushort* wk = wb + (size_t)(li * 4 + 1) * 65536;
        const ushort* wm = wb + (size_t)(li * 4 + 3) * 65536;
        const ushort* w1 = wb1 + (size_t)li * 262144;
        const ushort* w2 = wb2 + (size_t)li * 131072;
        const float* g1p = g1 + li * 256; const float* b1p = b1 + li * 256;
        const float* g2p = g2 + li * 256; const float* b2p = b2 + li * 256;
        bool last = (li == 3);

        if ((li & 1) == 0) {
            // ---- self-self, both sides combined (z=2) ----
            lft_mfma_gemm<<<dim3(6, 192, 2), blk, 0, stream>>>(
                xc, xc, 256, wq, (float*)kc, qc, (float*)vc, 768, 256, 3, minfo, 0);
            lft_kv_kernel<<<dim3(KV_NCH, 8, 128), blk, 0, stream>>>(kc, vc, cmeta, kvb, ksb, 0);
            lft_msg_kernel<<<dim3(MSG_NCH, 8, 16), blk, 0, stream>>>(qc, kvb, ksb, cmeta, msgc, 0, 0);
            lft_gemm_ln<<<dim3(384, 1, 2), blkL, 0, stream>>>(
                msgc, msgc, 256, wm, 256, g1p, b1p,
                nullptr, nullptr, gl, minfo, nullptr, msgc, 0);
            lft_mfma_gemm<<<dim3(4, 192, 2), blk, 0, stream>>>(
                xc, msgc, 256, w1, nullptr, hid, nullptr, 512, 512, 2, minfo, 0);
            lft_gemm_ln<<<dim3(384, 1, 2), blkL, 0, stream>>>(
                hid, hid, 512, w2, 512, g2p, b2p,
                rc, rc, gl, minfo, nullptr, xc, 0);
        } else {
            // ---- cross-self: q for both sides from OLD features ----
            lft_mfma_gemm<<<dim3(2, 192, 2), blk, 0, stream>>>(
                xc, xc, 256, wq, nullptr, qc, nullptr, 256, 256, 1, minfo, 0);
            // k|v from side1 (old) -> kc/vc side1
            lft_mfma_gemm<<<dim3(4, 192, 1), blk, 0, stream>>>(
                xc, xc, 256, wk, (float*)kc, nullptr, (float*)vc, 512, 256, 4, minfo, 1);
            lft_kv_kernel<<<dim3(KV_NCH, 8, 64), blk, 0, stream>>>(kc, vc, cmeta, kvb, ksb, 1);
            lft_msg_kernel<<<dim3(MSG_NCH, 8, 8), blk, 0, stream>>>(qc, kvb, ksb, cmeta, msgc, 0, 1);
            lft_gemm_ln<<<dim3(384, 1, 1), blkL, 0, stream>>>(
                msgc, msgc, 256, wm, 256, g1p, b1p,
                nullptr, nullptr, gl, minfo, nullptr, msgc, 0);
            lft_mfma_gemm<<<dim3(4, 192, 1), blk, 0, stream>>>(
                xc, msgc, 256, w1, nullptr, hid, nullptr, 512, 512, 2, minfo, 0);
            lft_gemm_ln<<<dim3(384, 1, 1), blkL, 0, stream>>>(
                hid, hid, 512, w2, 512, g2p, b2p,
                rc, last ? nullptr : rc, gl, minfo, last ? out : nullptr, xc, 0);
            // ---- side1 attends UPDATED side0 ----
            lft_mfma_gemm<<<dim3(4, 192, 1), blk, 0, stream>>>(
                xc, xc, 256, wk, (float*)kc, nullptr, (float*)vc, 512, 256, 4, minfo, 0);
            lft_kv_kernel<<<dim3(KV_NCH, 8, 64), blk, 0, stream>>>(kc, vc, cmeta, kvb, ksb, 0);
            lft_msg_kernel<<<dim3(MSG_NCH, 8, 8), blk, 0, stream>>>(qc, kvb, ksb, cmeta, msgc, 1, 0);
            lft_gemm_ln<<<dim3(384, 1, 1), blkL, 0, stream>>>(
                msgc, msgc, 256, wm, 256, g1p, b1p,
                nullptr, nullptr, gl, minfo, nullptr, msgc, 1);
            lft_mfma_gemm<<<dim3(4, 192, 1), blk, 0, stream>>>(
                xc, msgc, 256, w1, nullptr, hid, nullptr, 512, 512, 2, minfo, 1);
            lft_gemm_ln<<<dim3(384, 1, 1), blkL, 0, stream>>>(
                hid, hid, 512, w2, 512, g2p, b2p,
                rc, last ? nullptr : rc, gl, minfo, last ? out : nullptr,
                last ? nullptr : xc, 1);
        }
    }
}

// Round 20
// 1209.763 us; speedup vs baseline: 1.3629x; 1.0015x over previous
//
#include <hip/hip_runtime.h>
#include <math.h>

#define NPROTO 8
#define KV_NCH 4
#define MSG_NCH 8
#define CAP 24576L            // compact rows per side (Mv ~= 19200 +- ~200)

typedef __attribute__((ext_vector_type(8))) short short8;
typedef __attribute__((ext_vector_type(4))) float floatx4;

static __device__ __forceinline__ ushort f2b(float f) {
    unsigned u = __builtin_bit_cast(unsigned, f);
    unsigned r = (u + 0x7fffu + ((u >> 16) & 1u)) >> 16;
    return (ushort)r;
}

static __device__ __forceinline__ float b2f(ushort u) {
    return __builtin_bit_cast(float, (unsigned)u << 16);
}

static __device__ __forceinline__ float elu1(float v) {
    return v > 0.f ? v + 1.f : __expf(v);
}

// async 16B global -> LDS (linear dest: wave base + lane*16B)
#define GLOAD16(gp, lp) __builtin_amdgcn_global_load_lds( \
    (const __attribute__((address_space(1))) void*)(gp),  \
    (__attribute__((address_space(3))) void*)(lp), 16, 0, 0)

// full drain + barrier (gemm_ln's proven 2-phase structure)
#define WAIT_BAR() asm volatile("s_waitcnt vmcnt(0) lgkmcnt(0)\n\ts_barrier" ::: "memory")
// counted waits (mfma_gemm 3-buffer pipeline; 4 loads/thread/tile)
#define VMWAIT(N) asm volatile("s_waitcnt vmcnt(" #N ")" ::: "memory")
#define BAR() __builtin_amdgcn_s_barrier()

// swizzle of the 16B-group index within a 32-col bf16 row (4 groups/row)
static __device__ __forceinline__ int swz(int r) { return (r >> 1) & 3; }

// ---------------- prototype projection / argmax-class kernel ----------------
__global__ __launch_bounds__(256) void lft_class_kernel(
    const float* __restrict__ f0wo, const float* __restrict__ f1wo,
    const int* __restrict__ mask0, const int* __restrict__ mask1,
    const float* __restrict__ proto,
    float* out, int* cls0, int* cls1)
{
    __shared__ float pr[2048];          // proto [8][256]
    __shared__ float tile[128][68];     // [token][ch chunk], stride 68
    __shared__ float sm[128][8];
    int t = threadIdx.x;
    *(float4*)&pr[t * 4]        = *(const float4*)&proto[t * 4];
    *(float4*)&pr[1024 + t * 4] = *(const float4*)&proto[1024 + t * 4];
    long tok0 = (long)blockIdx.x * 128;
    const float* fsrc; const int* msrc; float* fpout; float* clsout; int* clsarr; long tbase;
    if (tok0 < 38400) {
        tbase = tok0; fsrc = f0wo; msrc = mask0;
        fpout = out + 19737600L; clsout = out + 19660800L; clsarr = cls0;
    } else {
        tbase = tok0 - 38400; fsrc = f1wo; msrc = mask1;
        fpout = out + 20044800L; clsout = out + 19699200L; clsarr = cls1;
    }
    int tok = t & 127, half = t >> 7;
    float s[4] = {};
    int r0 = t >> 4;            // 0..15
    int c4 = (t & 15) << 2;     // 0..60
    for (int ct = 0; ct < 4; ct++) {
        __syncthreads();
#pragma unroll
        for (int rr = 0; rr < 8; rr++) {
            int row = rr * 16 + r0;
            float4 v = *(const float4*)&fsrc[(tbase + row) * 256 + ct * 64 + c4];
            *(float4*)&tile[row][c4] = v;
        }
        __syncthreads();
#pragma unroll
        for (int cc = 0; cc < 16; cc++) {
            float4 f = *(const float4*)&tile[tok][cc << 2];
#pragma unroll
            for (int p = 0; p < 4; p++) {
                float4 pv = *(const float4*)&pr[(half * 4 + p) * 256 + ct * 64 + (cc << 2)];
                s[p] += f.x * pv.x + f.y * pv.y + f.z * pv.z + f.w * pv.w;
            }
        }
    }
#pragma unroll
    for (int p = 0; p < 4; p++) {
        fpout[(tbase + tok) * 8 + half * 4 + p] = s[p];
        sm[tok][half * 4 + p] = s[p];
    }
    __syncthreads();
    if (t < 128) {
        int best = 0; float bv = sm[t][0];
#pragma unroll
        for (int p = 1; p < 8; p++) { if (sm[t][p] > bv) { bv = sm[t][p]; best = p; } }
        clsout[tbase + t] = (float)best;
        clsarr[tbase + t] = msrc[tbase + t] ? best : -1;
    }
}

// ---------------- copy ONLY invalid-token rows of feat into out --------------
__global__ __launch_bounds__(256) void lft_invcopy_kernel(
    const float* __restrict__ f0, const float* __restrict__ f1,
    const int* __restrict__ cls0, const int* __restrict__ cls1,
    float* out)
{
    int w = blockIdx.x * 4 + (threadIdx.x >> 6);   // 0..4799
    int lane = threadIdx.x & 63;
    for (long row = w; row < 76800; row += 4800) {
        int side = row >= 38400;
        long r = row - (long)side * 38400;
        int c = side ? cls1[r] : cls0[r];
        if (c < 0) {
            const float* src = side ? f1 : f0;
            float4 v = *(const float4*)&src[r * 256 + lane * 4];
            *(float4*)&out[(long)side * 9830400L + r * 256 + lane * 4] = v;
        }
    }
}

// ---------------- per-(L,b) class counts -> meta {base,cnt} ------------------
__global__ __launch_bounds__(256) void lft_count_kernel(
    const int* __restrict__ cls0, const int* __restrict__ cls1, int* meta)
{
    int g = blockIdx.x; int L = g >> 3, b = g & 7;
    const int* cls = (L ? cls1 : cls0) + b * 4800;
    int* mt = meta + (L * 8 + b) * 16;
    __shared__ int cnt[8];
    int t = threadIdx.x;
    if (t < 8) cnt[t] = 0;
    __syncthreads();
    for (int tok = t; tok < 4800; tok += 256) {
        int c = cls[tok];
        if (c >= 0) atomicAdd(&cnt[c], 1);
    }
    __syncthreads();
    if (t == 0) {
        int s = 0;
        for (int c = 0; c < 8; c++) { mt[c * 2] = s; mt[c * 2 + 1] = cnt[c]; s += cnt[c]; }
    }
}

// ---------------- cross-batch scan: minfo (Mv, boff) + compact cmeta ---------
__global__ __launch_bounds__(256) void lft_scan_kernel(
    const int* __restrict__ meta, int* minfo, int* cmeta)
{
    int t = threadIdx.x;
    __shared__ int nb[16];
    if (t < 16) {
        int s = 0;
        for (int c = 0; c < 8; c++) s += meta[t * 16 + c * 2 + 1];
        nb[t] = s;
    }
    __syncthreads();
    if (t == 0) {
        int off = 0;
        for (int b = 0; b < 8; b++) { minfo[4 + b] = off; off += nb[b]; }
        minfo[2] = off; minfo[0] = (off + 127) & ~127;
        off = 0;
        for (int b = 0; b < 8; b++) { minfo[12 + b] = off; off += nb[8 + b]; }
        minfo[3] = off; minfo[1] = (off + 127) & ~127;
    }
    __syncthreads();
    if (t < 128) {
        int L = t >> 6, b = (t >> 3) & 7, c = t & 7;
        cmeta[t * 2]     = minfo[4 + L * 8 + b] + meta[(L * 8 + b) * 16 + c * 2];
        cmeta[t * 2 + 1] = meta[(L * 8 + b) * 16 + c * 2 + 1];
    }
}

// ---------------- place valid tokens into compact gather lists ---------------
__global__ __launch_bounds__(256) void lft_place_kernel(
    const int* __restrict__ cls0, const int* __restrict__ cls1,
    const int* __restrict__ cmeta, int* gl)
{
    int g = blockIdx.x; int L = g >> 3, b = g & 7;
    const int* cls = (L ? cls1 : cls0) + b * 4800;
    int* glp = gl + L * CAP;
    __shared__ int pos[8];
    int t = threadIdx.x;
    if (t < 8) pos[t] = cmeta[(L * 64 + b * 8 + t) * 2];
    __syncthreads();
    for (int tok = t; tok < 4800; tok += 256) {
        int c = cls[tok];
        if (c >= 0) { int p = atomicAdd(&pos[c], 1); glp[p] = b * 4800 + tok; }
    }
}

// ---------------- gather-cast: compact bf16 x + compact fp32 resid -----------
__global__ __launch_bounds__(256) void lft_gcast_kernel(
    const float* __restrict__ f0, const float* __restrict__ f1,
    const int* __restrict__ gl, const int* __restrict__ minfo,
    ushort* xc, float* rc)
{
    int blk = blockIdx.x;
    int side = blk >= 600 ? 1 : 0;
    int i0 = (blk - side * 600) * 4 + (threadIdx.x >> 6);
    int mv = minfo[2 + side];
    const int* glp = gl + side * CAP;
    const float* f = side ? f1 : f0;
    ushort* xcp = xc + side * CAP * 256;
    float* rcp = rc + side * CAP * 256;
    int lane = threadIdx.x & 63;
    for (int i = i0; i < mv; i += 2400) {
        long src = (long)glp[i] * 256 + lane * 4;
        float4 v = *(const float4*)&f[src];
        long dst = (long)i * 256 + lane * 4;
        *(float4*)&rcp[dst] = v;
        ushort4 u; u.x = f2b(v.x); u.y = f2b(v.y); u.z = f2b(v.z); u.w = f2b(v.w);
        *(ushort4*)&xcp[dst] = u;
    }
}

// ---------------- weight convert + transpose: Wt[n*K+k] = bf16(W[k*N+n]) ----
__global__ __launch_bounds__(256) void lft_wconv_kernel(
    const float* W0, const float* W1p, const float* W2p, const float* W3p,
    int K, int N, int nTypes, ushort* dst)
{
    int z = blockIdx.z;
    int li = z / nTypes, mi = z % nTypes;
    const float* srcs[4] = {W0, W1p, W2p, W3p};
    const float* src = srcs[mi] + (size_t)li * K * N;
    ushort* outp = dst + (size_t)z * K * N;
    __shared__ float tile[32][33];
    int k0 = blockIdx.x * 32, n0 = blockIdx.y * 32;
    int t = threadIdx.x;
    int r = t >> 3, c4 = (t & 7) << 2;
    float4 v = *(const float4*)&src[(size_t)(k0 + r) * N + n0 + c4];
    tile[r][c4] = v.x; tile[r][c4 + 1] = v.y; tile[r][c4 + 2] = v.z; tile[r][c4 + 3] = v.w;
    __syncthreads();
    ushort4 o;
    o.x = f2b(tile[c4 + 0][r]);
    o.y = f2b(tile[c4 + 1][r]);
    o.z = f2b(tile[c4 + 2][r]);
    o.w = f2b(tile[c4 + 3][r]);
    *(ushort4*)&outp[(size_t)(n0 + r) * K + k0 + c4] = o;
}

// ---------------- bf16 MFMA GEMM over COMPACT rows ---------------------------
// XCD-aware block swizzle (T1). 3-buffer counted-vmcnt pipeline. 128x128 tile.
// Epilogue: LDS-transposed coalesced bf16 stores (full 16-elem spans).
// act: 1 elu+1 (q); 2 relu (hid, ldc=512); act 3 qkv N=768; act 4 kv N=512.
__global__ __launch_bounds__(256) void lft_mfma_gemm(
    const ushort* __restrict__ A0b, const ushort* __restrict__ A1b, int kSplit,
    const ushort* __restrict__ Wt,
    float* Cf, ushort* Cb, float* Cv, int N, int K, int act,
    const int* __restrict__ minfo, int side0)
{
    __shared__ ushort As[3][128 * 32];
    __shared__ ushort Bs[3][128 * 32];
    int gx = gridDim.x, gy = gridDim.y;
    int G = gx * gy * gridDim.z;
    int orig = (blockIdx.z * gy + blockIdx.y) * gx + blockIdx.x;
    int wid = ((orig & 7) * (G >> 3)) + (orig >> 3);   // G % 8 == 0 (all grids)
    int bx = wid % gx; int rest = wid / gx;
    int by = rest % gy; int bz = rest / gy;
    int side = side0 + bz;
    int m0 = by << 7;
    if (m0 >= minfo[side]) return;
    int n0 = bx << 7;
    const ushort* A0 = A0b + (long)side * CAP * kSplit;
    const ushort* A1 = A1b + (long)side * CAP * (K - kSplit);
    long so256 = (long)side * CAP * 256;
    long soN = (long)side * CAP * N;
    int t = threadIdx.x;
    int wv = t >> 6, lane = t & 63;
    int wm = wv >> 1, wn = wv & 1;
    int l16 = lane & 15, quad = lane >> 4;
    floatx4 acc[4][4] = {};

    int lrow = lane >> 2;
    int lcg = lane & 3;

    auto stage = [&](int buf, int k0) {
        const ushort* Asrc; int kcol, ldA;
        if (k0 < kSplit) { Asrc = A0; kcol = k0;          ldA = kSplit; }
        else             { Asrc = A1; kcol = k0 - kSplit; ldA = K - kSplit; }
        ushort* Ab = &As[buf][0];
        ushort* Bb = &Bs[buf][0];
#pragma unroll
        for (int s = 0; s < 2; s++) {
            int r = s * 64 + wv * 16 + lrow;
            int cgA = (lcg ^ swz(r)) << 3;
            GLOAD16(&Asrc[(size_t)(m0 + r) * ldA + kcol + cgA], &Ab[(s * 64 + wv * 16) * 32]);
            GLOAD16(&Wt[(size_t)(n0 + r) * K + k0 + cgA], &Bb[(s * 64 + wv * 16) * 32]);
        }
    };

    auto compute = [&](int buf) {
        const ushort* Ab = &As[buf][0];
        const ushort* Bb = &Bs[buf][0];
        short8 af[4], bfr[4];
#pragma unroll
        for (int i = 0; i < 4; i++) {
            int rA = wm * 64 + i * 16 + l16;
            int rB = wn * 64 + i * 16 + l16;
            af[i]  = *(const short8*)&Ab[rA * 32 + ((quad ^ swz(rA)) << 3)];
            bfr[i] = *(const short8*)&Bb[rB * 32 + ((quad ^ swz(rB)) << 3)];
        }
        __builtin_amdgcn_s_setprio(1);
#pragma unroll
        for (int i = 0; i < 4; i++)
#pragma unroll
            for (int j = 0; j < 4; j++)
                acc[i][j] = __builtin_amdgcn_mfma_f32_16x16x32_bf16(af[i], bfr[j], acc[i][j], 0, 0, 0);
        __builtin_amdgcn_s_setprio(0);
    };

    int nt = K >> 5;               // 8 or 16
    stage(0, 0);
    stage(1, 32);
    int cur = 0;
    for (int tt = 0; tt < nt; ++tt) {
        if (tt + 2 < nt) {
            int nb = cur + 2; if (nb >= 3) nb -= 3;
            stage(nb, (tt + 2) << 5);
            VMWAIT(8);             // tile tt done; tt+1, tt+2 in flight
        } else if (tt + 2 == nt) {
            VMWAIT(4);
        } else {
            VMWAIT(0);
        }
        BAR();
        compute(cur);
        if (tt + 1 < nt) BAR();
        cur = cur + 1 == 3 ? 0 : cur + 1;
    }

    // ---- LDS-transposed coalesced bf16 epilogue ----
    ushort* dst; int ncol0; int amode; long base; int ldc;
    if (act == 3) {
        base = so256; ldc = 256;
        if (n0 < 256)      { dst = Cb;          ncol0 = n0;       amode = 1; }
        else if (n0 < 512) { dst = (ushort*)Cf; ncol0 = n0 - 256; amode = 1; }
        else               { dst = (ushort*)Cv; ncol0 = n0 - 512; amode = 0; }
    } else if (act == 4) {
        base = so256; ldc = 256;
        if (n0 < 256) { dst = (ushort*)Cf; ncol0 = n0;       amode = 1; }
        else          { dst = (ushort*)Cv; ncol0 = n0 - 256; amode = 0; }
    } else {  // act 1 (q, elu) or act 2 (hid, relu)
        base = soN; ldc = N;
        dst = Cb; ncol0 = n0; amode = (act == 1) ? 1 : 2;
    }
    ushort* tb = &As[0][0];        // 32 x 144 transpose tile (aliases As)
    int lr = t >> 3;               // 0..31 (8 threads/row)
    int cs = (t & 7) << 4;         // element offset 0,16,..,112 (16 elems = 32B)
    int wmr = lr >> 4, rloc = lr & 15;
#pragma unroll
    for (int i = 0; i < 4; i++) {
        __syncthreads();           // prior LDS reads (compute / tb) complete
#pragma unroll
        for (int j = 0; j < 4; j++) {
#pragma unroll
            for (int r = 0; r < 4; r++) {
                float v = acc[i][j][r];
                if (amode == 1)      v = elu1(v);
                else if (amode == 2) v = fmaxf(v, 0.f);
                tb[(wm * 16 + quad * 4 + r) * 144 + wn * 64 + j * 16 + l16] = f2b(v);
            }
        }
        __syncthreads();
        long row = m0 + wmr * 64 + i * 16 + rloc;
        short8 v0 = *(const short8*)&tb[lr * 144 + cs];
        short8 v1 = *(const short8*)&tb[lr * 144 + cs + 8];
        *(short8*)&dst[base + row * ldc + ncol0 + cs] = v0;
        *(short8*)&dst[base + row * ldc + ncol0 + cs + 8] = v1;
    }
}

// ---------------- fused GEMM (N=256) + row-LN over COMPACT rows -------------
// 512 threads, M=64 tile (grid.x=384 per side, early-exit), 8 waves (2m x 4n).
// Epilogue: per i-stripe LDS fp32 transpose -> linear coalesced phase.
__global__ __launch_bounds__(512) void lft_gemm_ln(
    const ushort* __restrict__ A0b, const ushort* __restrict__ A1b, int kSplit,
    const ushort* __restrict__ Wt, int K,
    const float* __restrict__ g, const float* __restrict__ bb,
    const float* __restrict__ rcInB, float* rcOutB,
    const int* __restrict__ glB, const int* __restrict__ minfo,
    float* outScB, ushort* __restrict__ outBB, int side0)
{
    __shared__ union {
        struct { ushort As[2][64 * 32]; ushort Bs[2][256 * 32]; } s;  // 40KB
        float tile[32][260];                                          // 33.3KB
    } u;
    __shared__ float gs[256], bs[256];
    __shared__ float psum[4][64], psq[4][64];
    int side = side0 + blockIdx.z;
    long m0 = (long)blockIdx.x << 6;
    if (m0 >= minfo[side]) return;
    const ushort* A0 = A0b + (long)side * CAP * kSplit;
    const ushort* A1 = A1b + (long)side * CAP * (K - kSplit);
    long so = (long)side * CAP * 256;
    int t = threadIdx.x;
    int wv = t >> 6, lane = t & 63;
    int wm = wv >> 2, wn = wv & 3;
    int l16 = lane & 15, quad = lane >> 4;
    if (t < 256) { gs[t] = g[t]; bs[t] = bb[t]; }
    floatx4 acc[2][4] = {};

    int lrow = lane >> 2;
    int lcg = lane & 3;

    auto stage = [&](int buf, int k0) {
        const ushort* Asrc; int kcol, ldA;
        if (k0 < kSplit) { Asrc = A0; kcol = k0;          ldA = kSplit; }
        else             { Asrc = A1; kcol = k0 - kSplit; ldA = K - kSplit; }
        if (wv < 4) {                                      // A rows 0..63
            int r = wv * 16 + lrow;
            int cgA = (lcg ^ swz(r)) << 3;
            GLOAD16(&Asrc[(m0 + r) * ldA + kcol + cgA], &u.s.As[buf][(wv * 16) * 32]);
        }
#pragma unroll
        for (int s = 0; s < 2; s++) {                      // B rows 0..255
            int r = s * 128 + wv * 16 + lrow;
            int cgB = (lcg ^ swz(r)) << 3;
            GLOAD16(&Wt[(size_t)r * K + k0 + cgB], &u.s.Bs[buf][(s * 128 + wv * 16) * 32]);
        }
    };

    int nt = K >> 5;
    stage(0, 0);
    WAIT_BAR();
    int cur = 0;
    for (int tt = 0; tt < nt; ++tt) {
        if (tt + 1 < nt) stage(cur ^ 1, (tt + 1) << 5);
        const ushort* Ab = &u.s.As[cur][0];
        const ushort* Bb = &u.s.Bs[cur][0];
        short8 af[2], bfr[4];
#pragma unroll
        for (int i = 0; i < 2; i++) {
            int rA = wm * 32 + i * 16 + l16;
            af[i] = *(const short8*)&Ab[rA * 32 + ((quad ^ swz(rA)) << 3)];
        }
#pragma unroll
        for (int j = 0; j < 4; j++) {
            int rB = wn * 64 + j * 16 + l16;
            bfr[j] = *(const short8*)&Bb[rB * 32 + ((quad ^ swz(rB)) << 3)];
        }
#pragma unroll
        for (int i = 0; i < 2; i++)
#pragma unroll
            for (int j = 0; j < 4; j++)
                acc[i][j] = __builtin_amdgcn_mfma_f32_16x16x32_bf16(af[i], bfr[j], acc[i][j], 0, 0, 0);
        if (tt + 1 < nt) { WAIT_BAR(); cur ^= 1; }
    }
    // per-row partial sums (this wave's 64 cols) -> LDS
#pragma unroll
    for (int i = 0; i < 2; i++) {
#pragma unroll
        for (int r = 0; r < 4; r++) {
            float s = 0.f, q = 0.f;
#pragma unroll
            for (int j = 0; j < 4; j++) { float v = acc[i][j][r]; s += v; q += v * v; }
#pragma unroll
            for (int o = 8; o >= 1; o >>= 1) {
                s += __shfl_xor(s, o, 64);
                q += __shfl_xor(q, o, 64);
            }
            if (l16 == 0) {
                int row = wm * 32 + i * 16 + quad * 4 + r;
                psum[wn][row] = s; psq[wn][row] = q;
            }
        }
    }
    __syncthreads();
    if (t < 64) {
        float s = psum[0][t] + psum[1][t] + psum[2][t] + psum[3][t];
        float q = psq[0][t] + psq[1][t] + psq[2][t] + psq[3][t];
        float mean = s * (1.0f / 256.0f);
        float var = q * (1.0f / 256.0f) - mean * mean;
        psum[0][t] = mean;
        psq[0][t] = rsqrtf(var + 1e-5f);
    }
    __syncthreads();
    int mvE = minfo[2 + side];
    const float* rcIn = rcInB ? rcInB + so : nullptr;
    float* rcOut = rcOutB ? rcOutB + so : nullptr;
    const int* glp = glB + side * CAP;
    float* outSc = outScB ? outScB + (long)side * 9830400L : nullptr;
    ushort* outB = outBB ? outBB + so : nullptr;
    // ---- coalesced epilogue: 2 stripes of 32 tile-rows ----
#pragma unroll
    for (int i = 0; i < 2; i++) {
        // phase A: LN (no resid) into fp32 tile
#pragma unroll
        for (int r = 0; r < 4; r++) {
            int rloc = wm * 32 + i * 16 + quad * 4 + r;
            int tr = wm * 16 + quad * 4 + r;
            float mean = psum[0][rloc], rstd = psq[0][rloc];
#pragma unroll
            for (int j = 0; j < 4; j++) {
                int col = wn * 64 + j * 16 + l16;
                u.tile[tr][col] = (acc[i][j][r] - mean) * rstd * gs[col] + bs[col];
            }
        }
        __syncthreads();
        // phase B: linear coalesced residual-add + stores
#pragma unroll
        for (int e = 0; e < 4; e++) {
            int idx = e * 512 + t;          // 0..2047
            int tr = idx >> 6;              // tile row 0..31
            int c4 = (idx & 63) << 2;       // col 0..252 step 4
            long arow = m0 + (long)((tr >> 4) * 32 + i * 16 + (tr & 15));
            float4 v = *(float4*)&u.tile[tr][c4];
            if (rcIn) {
                float4 rv = *(const float4*)&rcIn[arow * 256 + c4];
                v.x += rv.x; v.y += rv.y; v.z += rv.z; v.w += rv.w;
            }
            if (rcOut) *(float4*)&rcOut[arow * 256 + c4] = v;
            if (outSc && arow < mvE)
                *(float4*)&outSc[(long)glp[arow] * 256 + c4] = v;
            if (outB) {
                ushort4 uo; uo.x = f2b(v.x); uo.y = f2b(v.y);
                uo.z = f2b(v.z); uo.w = f2b(v.w);
                *(ushort4*)&outB[arow * 256 + c4] = uo;
            }
        }
        if (i == 0) __syncthreads();
    }
}

// ---------------- per-class KV / Ksum reduction (compact, bf16 inputs) -------
// Per-chunk private slots (plain stores, no memset/atomics).
__global__ __launch_bounds__(256) void lft_kv_kernel(
    const ushort* __restrict__ kcB, const ushort* __restrict__ vcB,
    const int* __restrict__ cmetaB,
    float* kvbB, float* ksbB, int sideSrc0)
{
    int side = sideSrc0 + (blockIdx.z >> 6);
    int zz = blockIdx.z & 63;
    int chunk = blockIdx.x, c = blockIdx.y;
    int b = zz >> 3, h = zz & 7;
    const int* cmeta = cmetaB + side * 128;
    int cstart = cmeta[(b * 8 + c) * 2], n = cmeta[(b * 8 + c) * 2 + 1];
    int per = (n + KV_NCH - 1) / KV_NCH;
    int s0 = chunk * per;
    int s1 = min(s0 + per, n);
    const ushort* phik = kcB + (long)side * CAP * 256;
    const ushort* vmat = vcB + (long)side * CAP * 256;
    int slot = side * KV_NCH + chunk;
    float* kv = kvbB + (long)slot * 524288;
    float* ksum = ksbB + (long)slot * 16384;
    int t = threadIdx.x;
    __shared__ float kb[8][32];
    __shared__ float vb[8][32];
    int od = t >> 3, oe = (t & 7) << 2;
    int lt = t >> 5, ld = t & 31;
    float a0 = 0.f, a1 = 0.f, a2 = 0.f, a3 = 0.f, ak = 0.f;
    for (int s = s0; s < s1; s += 8) {
        float kval = 0.f, vval = 0.f;
        if (s + lt < s1) {
            long bse = (long)(cstart + s + lt) * 256 + h * 32 + ld;
            kval = b2f(phik[bse]);
            vval = b2f(vmat[bse]);
        }
        __syncthreads();
        kb[lt][ld] = kval;
        vb[lt][ld] = vval;
        __syncthreads();
#pragma unroll
        for (int j = 0; j < 8; j++) {
            float kd = kb[j][od];
            float4 vv = *(const float4*)&vb[j][oe];
            a0 += kd * vv.x; a1 += kd * vv.y; a2 += kd * vv.z; a3 += kd * vv.w;
            ak += kd;
        }
    }
    float* dst = kv + (((long)(b * NPROTO + c) * 8 + h) << 10) + od * 32 + oe;
    dst[0] = a0; dst[1] = a1; dst[2] = a2; dst[3] = a3;
    if ((t & 7) == 0)
        ksum[(((long)(b * NPROTO + c) * 8 + h) << 5) + od] = ak;
}

// ---------------- msg via MFMA; LDS row-tiled q reads + coalesced writes -----
// Per 16-row step: stage 16 full q rows coalesced (32x16B per row), MFMA from
// LDS (stride 264 -> 2-way bank alias, free), results to LDS out-tile, then
// 16B coalesced row writes with tail guard.
__global__ __launch_bounds__(256) void lft_msg_kernel(
    const ushort* __restrict__ qcB, const float* __restrict__ kvbB,
    const float* __restrict__ ksbB, const int* __restrict__ cmetaB,
    ushort* __restrict__ msgcB, int sideX0, int sideKV0)
{
    int add = blockIdx.z >> 3, b = blockIdx.z & 7;
    int sideX = sideX0 + add, sideKV = sideKV0 + add;
    int chunk = blockIdx.x, c = blockIdx.y;
    const int* cmeta = cmetaB + sideX * 128;
    int cstart = cmeta[(b * 8 + c) * 2], n = cmeta[(b * 8 + c) * 2 + 1];
    int per = (n + MSG_NCH - 1) / MSG_NCH;
    int s0 = chunk * per, s1 = min(s0 + per, n);
    if (s0 >= s1) return;
    const ushort* pq = qcB + (long)sideX * CAP * 256;
    ushort* msg = msgcB + (long)sideX * CAP * 256;
    __shared__ ushort qt[16][264];
    __shared__ ushort ot[16][264];
    int t = threadIdx.x;
    int wave = t >> 6, lane = t & 63;
    int l16 = lane & 15, quad = lane >> 4;
    int bc = b * 8 + c;
    short8 bfr[2][3];
#pragma unroll
    for (int hh = 0; hh < 2; hh++) {
        int h = wave * 2 + hh;
        long kvoff = ((long)bc * 8 + h) * 1024;
        long ksoff = ((long)bc * 8 + h) * 32;
#pragma unroll
        for (int nt = 0; nt < 2; nt++)
#pragma unroll
            for (int j = 0; j < 8; j++) {
                float v = 0.f;
#pragma unroll
                for (int ch = 0; ch < KV_NCH; ch++)
                    v += kvbB[(long)(sideKV * KV_NCH + ch) * 524288 + kvoff
                              + (quad * 8 + j) * 32 + nt * 16 + l16];
                bfr[hh][nt][j] = (short)f2b(v);
            }
#pragma unroll
        for (int j = 0; j < 8; j++) {
            float v = 0.f;
#pragma unroll
            for (int ch = 0; ch < KV_NCH; ch++)
                v += ksbB[(long)(sideKV * KV_NCH + ch) * 16384 + ksoff + quad * 8 + j];
            bfr[hh][2][j] = (l16 == 0) ? (short)f2b(v) : (short)0;
        }
    }
    int srow = t >> 5;              // staging row 0..7 (x2 iters -> 0..15)
    int scol = (t & 31) << 3;       // 8-elem group 0..248
    for (int s = s0; s < s1; s += 16) {
        // stage 16 q rows (clamped) coalesced
#pragma unroll
        for (int it = 0; it < 2; it++) {
            int sr = it * 8 + srow;
            int rr = min(s + sr, s1 - 1);
            *(short8*)&qt[sr][scol] = *(const short8*)&pq[(long)(cstart + rr) * 256 + scol];
        }
        __syncthreads();
#pragma unroll
        for (int hh = 0; hh < 2; hh++) {
            int h = wave * 2 + hh;
            short8 a = *(const short8*)&qt[l16][h * 32 + quad * 8];
            floatx4 n0 = {}, n1 = {}, dd = {};
            n0 = __builtin_amdgcn_mfma_f32_16x16x32_bf16(a, bfr[hh][0], n0, 0, 0, 0);
            n1 = __builtin_amdgcn_mfma_f32_16x16x32_bf16(a, bfr[hh][1], n1, 0, 0, 0);
            dd = __builtin_amdgcn_mfma_f32_16x16x32_bf16(a, bfr[hh][2], dd, 0, 0, 0);
#pragma unroll
            for (int r = 0; r < 4; r++) {
                float den = __shfl(dd[r], lane & 48, 64);
                float inv = 1.f / (den + 1e-6f);
                ot[quad * 4 + r][h * 32 + l16]      = f2b(n0[r] * inv);
                ot[quad * 4 + r][h * 32 + 16 + l16] = f2b(n1[r] * inv);
            }
        }
        __syncthreads();
        // coalesced write-out with tail guard
#pragma unroll
        for (int it = 0; it < 2; it++) {
            int sr = it * 8 + srow;
            if (s + sr < s1)
                *(short8*)&msg[(long)(cstart + s + sr) * 256 + scol] =
                    *(const short8*)&ot[sr][scol];
        }
        __syncthreads();
    }
}

extern "C" void kernel_launch(void* const* d_in, const int* in_sizes, int n_in,
                              void* d_out, int out_size, void* d_ws, size_t ws_size,
                              hipStream_t stream)
{
    (void)in_sizes; (void)n_in; (void)out_size; (void)ws_size;
    const float* feat0 = (const float*)d_in[0];
    const float* feat1 = (const float*)d_in[1];
    const int*   mask0 = (const int*)d_in[2];
    const int*   mask1 = (const int*)d_in[3];
    const float* f0wo  = (const float*)d_in[4];
    const float* f1wo  = (const float*)d_in[5];
    const float* proto = (const float*)d_in[6];
    const float* Wq = (const float*)d_in[7];
    const float* Wk = (const float*)d_in[8];
    const float* Wv = (const float*)d_in[9];
    const float* Wm = (const float*)d_in[10];
    const float* W1 = (const float*)d_in[11];
    const float* W2 = (const float*)d_in[12];
    const float* g1 = (const float*)d_in[13];
    const float* b1 = (const float*)d_in[14];
    const float* g2 = (const float*)d_in[15];
    const float* b2 = (const float*)d_in[16];
    float* out = (float*)d_out;
    float* ws = (float*)d_ws;

    // ---- workspace layout (side-strided compact buffers, CAP rows/side) ----
    const long FSZ = 9830400L;
    float* rc = ws;                               // 2*CAP*256 f
    ushort* kc = (ushort*)(rc + 2 * CAP * 256);   // 2*CAP*256 us  bf16
    ushort* vc = kc + 2 * CAP * 256;              // 2*CAP*256 us  bf16
    ushort* hid = vc + 2 * CAP * 256;             // 2*CAP*512 us
    ushort* xc   = hid + 2 * CAP * 512;
    ushort* msgc = xc + 2 * CAP * 256;
    ushort* qc   = msgc + 2 * CAP * 256;
    ushort* wb   = qc + 2 * CAP * 256;
    ushort* wb1  = wb + 16 * 65536;
    ushort* wb2  = wb1 + 4 * 262144;
    float* ksb = (float*)(wb2 + 4 * 131072);      // 2*KV_NCH*16384 f
    int* cls0 = (int*)(ksb + 2 * KV_NCH * 16384);
    int* cls1 = cls0 + 38400;
    int* gl   = cls1 + 38400;                     // 2*CAP ints
    int* meta = gl + 2 * CAP;
    int* minfo = meta + 256;
    int* cmeta = minfo + 20;
    // kvb aliases hid (dead between kv_kernel and w1-GEMM)
    float* kvb = (float*)hid;

    lft_wconv_kernel<<<dim3(8, 8, 16), 256, 0, stream>>>(Wq, Wk, Wv, Wm, 256, 256, 4, wb);
    lft_wconv_kernel<<<dim3(16, 16, 4), 256, 0, stream>>>(W1, W1, W1, W1, 512, 512, 1, wb1);
    lft_wconv_kernel<<<dim3(16, 8, 4), 256, 0, stream>>>(W2, W2, W2, W2, 512, 256, 1, wb2);
    hipMemcpyAsync(out + 20352000L, proto, 2048 * 4, hipMemcpyDeviceToDevice, stream);
    lft_class_kernel<<<600, 256, 0, stream>>>(f0wo, f1wo, mask0, mask1, proto,
                                              out, cls0, cls1);
    lft_invcopy_kernel<<<1200, 256, 0, stream>>>(feat0, feat1, cls0, cls1, out);
    lft_count_kernel<<<16, 256, 0, stream>>>(cls0, cls1, meta);
    lft_scan_kernel<<<1, 256, 0, stream>>>(meta, minfo, cmeta);
    lft_place_kernel<<<16, 256, 0, stream>>>(cls0, cls1, cmeta, gl);
    lft_gcast_kernel<<<1200, 256, 0, stream>>>(feat0, feat1, gl, minfo, xc, rc);

    dim3 blk(256);
    dim3 blkL(512);
    for (int li = 0; li < 4; li++) {
        const ushort* wq = wb + (size_t)(li * 4 + 0) * 65536;   // [wq|wk|wv|wm]
        const ushort* wk = wb + (size_t)(li * 4 + 1) * 65536;
        const ushort* wm = wb + (size_t)(li * 4 + 3) * 65536;
        const ushort* w1 = wb1 + (size_t)li * 262144;
        const ushort* w2 = wb2 + (size_t)li * 131072;
        const float* g1p = g1 + li * 256; const float* b1p = b1 + li * 256;
        const float* g2p = g2 + li * 256; const float* b2p = b2 + li * 256;
        bool last = (li == 3);

        if ((li & 1) == 0) {
            // ---- self-self, both sides combined (z=2) ----
            lft_mfma_gemm<<<dim3(6, 192, 2), blk, 0, stream>>>(
                xc, xc, 256, wq, (float*)kc, qc, (float*)vc, 768, 256, 3, minfo, 0);
            lft_kv_kernel<<<dim3(KV_NCH, 8, 128), blk, 0, stream>>>(kc, vc, cmeta, kvb, ksb, 0);
            lft_msg_kernel<<<dim3(MSG_NCH, 8, 16), blk, 0, stream>>>(qc, kvb, ksb, cmeta, msgc, 0, 0);
            lft_gemm_ln<<<dim3(384, 1, 2), blkL, 0, stream>>>(
                msgc, msgc, 256, wm, 256, g1p, b1p,
                nullptr, nullptr, gl, minfo, nullptr, msgc, 0);
            lft_mfma_gemm<<<dim3(4, 192, 2), blk, 0, stream>>>(
                xc, msgc, 256, w1, nullptr, hid, nullptr, 512, 512, 2, minfo, 0);
            lft_gemm_ln<<<dim3(384, 1, 2), blkL, 0, stream>>>(
                hid, hid, 512, w2, 512, g2p, b2p,
                rc, rc, gl, minfo, nullptr, xc, 0);
        } else {
            // ---- cross-self: q for both sides from OLD features ----
            lft_mfma_gemm<<<dim3(2, 192, 2), blk, 0, stream>>>(
                xc, xc, 256, wq, nullptr, qc, nullptr, 256, 256, 1, minfo, 0);
            // k|v from side1 (old) -> kc/vc side1
            lft_mfma_gemm<<<dim3(4, 192, 1), blk, 0, stream>>>(
                xc, xc, 256, wk, (float*)kc, nullptr, (float*)vc, 512, 256, 4, minfo, 1);
            lft_kv_kernel<<<dim3(KV_NCH, 8, 64), blk, 0, stream>>>(kc, vc, cmeta, kvb, ksb, 1);
            lft_msg_kernel<<<dim3(MSG_NCH, 8, 8), blk, 0, stream>>>(qc, kvb, ksb, cmeta, msgc, 0, 1);
            lft_gemm_ln<<<dim3(384, 1, 1), blkL, 0, stream>>>(
                msgc, msgc, 256, wm, 256, g1p, b1p,
                nullptr, nullptr, gl, minfo, nullptr, msgc, 0);
            lft_mfma_gemm<<<dim3(4, 192, 1), blk, 0, stream>>>(
                xc, msgc, 256, w1, nullptr, hid, nullptr, 512, 512, 2, minfo, 0);
            lft_gemm_ln<<<dim3(384, 1, 1), blkL, 0, stream>>>(
                hid, hid, 512, w2, 512, g2p, b2p,
                rc, last ? nullptr : rc, gl, minfo, last ? out : nullptr, xc, 0);
            // ---- side1 attends UPDATED side0 ----
            lft_mfma_gemm<<<dim3(4, 192, 1), blk, 0, stream>>>(
                xc, xc, 256, wk, (float*)kc, nullptr, (float*)vc, 512, 256, 4, minfo, 0);
            lft_kv_kernel<<<dim3(KV_NCH, 8, 64), blk, 0, stream>>>(kc, vc, cmeta, kvb, ksb, 0);
            lft_msg_kernel<<<dim3(MSG_NCH, 8, 8), blk, 0, stream>>>(qc, kvb, ksb, cmeta, msgc, 1, 0);
            lft_gemm_ln<<<dim3(384, 1, 1), blkL, 0, stream>>>(
                msgc, msgc, 256, wm, 256, g1p, b1p,
                nullptr, nullptr, gl, minfo, nullptr, msgc, 1);
            lft_mfma_gemm<<<dim3(4, 192, 1), blk, 0, stream>>>(
                xc, msgc, 256, w1, nullptr, hid, nullptr, 512, 512, 2, minfo, 1);
            lft_gemm_ln<<<dim3(384, 1, 1), blkL, 0, stream>>>(
                hid, hid, 512, w2, 512, g2p, b2p,
                rc, last ? nullptr : rc, gl, minfo, last ? out : nullptr,
                last ? nullptr : xc, 1);
        }
    }
}

// Round 21
// 1208.490 us; speedup vs baseline: 1.3643x; 1.0011x over previous
//
#include <hip/hip_runtime.h>
#include <math.h>

#define NPROTO 8
#define KV_NCH 4
#define MSG_NCH 8
#define CAP 24576L            // compact rows per side (Mv ~= 19200 +- ~200)

typedef __attribute__((ext_vector_type(8))) short short8;
typedef __attribute__((ext_vector_type(4))) float floatx4;

static __device__ __forceinline__ ushort f2b(float f) {
    unsigned u = __builtin_bit_cast(unsigned, f);
    unsigned r = (u + 0x7fffu + ((u >> 16) & 1u)) >> 16;
    return (ushort)r;
}

static __device__ __forceinline__ float b2f(ushort u) {
    return __builtin_bit_cast(float, (unsigned)u << 16);
}

static __device__ __forceinline__ float elu1(float v) {
    return v > 0.f ? v + 1.f : __expf(v);
}

// async 16B global -> LDS (linear dest: wave base + lane*16B)
#define GLOAD16(gp, lp) __builtin_amdgcn_global_load_lds( \
    (const __attribute__((address_space(1))) void*)(gp),  \
    (__attribute__((address_space(3))) void*)(lp), 16, 0, 0)

// full drain + barrier (gemm_ln's proven 2-phase structure)
#define WAIT_BAR() asm volatile("s_waitcnt vmcnt(0) lgkmcnt(0)\n\ts_barrier" ::: "memory")
// counted waits (mfma_gemm 3-buffer pipeline; 4 loads/thread/tile)
#define VMWAIT(N) asm volatile("s_waitcnt vmcnt(" #N ")" ::: "memory")
#define BAR() __builtin_amdgcn_s_barrier()

// swizzle of the 16B-group index within a 32-col bf16 row (4 groups/row)
static __device__ __forceinline__ int swz(int r) { return (r >> 1) & 3; }

// ---------------- prototype projection / argmax-class kernel ----------------
__global__ __launch_bounds__(256) void lft_class_kernel(
    const float* __restrict__ f0wo, const float* __restrict__ f1wo,
    const int* __restrict__ mask0, const int* __restrict__ mask1,
    const float* __restrict__ proto,
    float* out, int* cls0, int* cls1)
{
    __shared__ float pr[2048];          // proto [8][256]
    __shared__ float tile[128][68];     // [token][ch chunk], stride 68
    __shared__ float sm[128][8];
    int t = threadIdx.x;
    *(float4*)&pr[t * 4]        = *(const float4*)&proto[t * 4];
    *(float4*)&pr[1024 + t * 4] = *(const float4*)&proto[1024 + t * 4];
    long tok0 = (long)blockIdx.x * 128;
    const float* fsrc; const int* msrc; float* fpout; float* clsout; int* clsarr; long tbase;
    if (tok0 < 38400) {
        tbase = tok0; fsrc = f0wo; msrc = mask0;
        fpout = out + 19737600L; clsout = out + 19660800L; clsarr = cls0;
    } else {
        tbase = tok0 - 38400; fsrc = f1wo; msrc = mask1;
        fpout = out + 20044800L; clsout = out + 19699200L; clsarr = cls1;
    }
    int tok = t & 127, half = t >> 7;
    float s[4] = {};
    int r0 = t >> 4;            // 0..15
    int c4 = (t & 15) << 2;     // 0..60
    for (int ct = 0; ct < 4; ct++) {
        __syncthreads();
#pragma unroll
        for (int rr = 0; rr < 8; rr++) {
            int row = rr * 16 + r0;
            float4 v = *(const float4*)&fsrc[(tbase + row) * 256 + ct * 64 + c4];
            *(float4*)&tile[row][c4] = v;
        }
        __syncthreads();
#pragma unroll
        for (int cc = 0; cc < 16; cc++) {
            float4 f = *(const float4*)&tile[tok][cc << 2];
#pragma unroll
            for (int p = 0; p < 4; p++) {
                float4 pv = *(const float4*)&pr[(half * 4 + p) * 256 + ct * 64 + (cc << 2)];
                s[p] += f.x * pv.x + f.y * pv.y + f.z * pv.z + f.w * pv.w;
            }
        }
    }
#pragma unroll
    for (int p = 0; p < 4; p++) {
        fpout[(tbase + tok) * 8 + half * 4 + p] = s[p];
        sm[tok][half * 4 + p] = s[p];
    }
    __syncthreads();
    if (t < 128) {
        int best = 0; float bv = sm[t][0];
#pragma unroll
        for (int p = 1; p < 8; p++) { if (sm[t][p] > bv) { bv = sm[t][p]; best = p; } }
        clsout[tbase + t] = (float)best;
        clsarr[tbase + t] = msrc[tbase + t] ? best : -1;
    }
}

// ---------------- copy ONLY invalid-token rows of feat into out --------------
__global__ __launch_bounds__(256) void lft_invcopy_kernel(
    const float* __restrict__ f0, const float* __restrict__ f1,
    const int* __restrict__ cls0, const int* __restrict__ cls1,
    float* out)
{
    int w = blockIdx.x * 4 + (threadIdx.x >> 6);   // 0..4799
    int lane = threadIdx.x & 63;
    for (long row = w; row < 76800; row += 4800) {
        int side = row >= 38400;
        long r = row - (long)side * 38400;
        int c = side ? cls1[r] : cls0[r];
        if (c < 0) {
            const float* src = side ? f1 : f0;
            float4 v = *(const float4*)&src[r * 256 + lane * 4];
            *(float4*)&out[(long)side * 9830400L + r * 256 + lane * 4] = v;
        }
    }
}

// ---------------- per-(L,b) class counts -> meta {base,cnt} ------------------
__global__ __launch_bounds__(256) void lft_count_kernel(
    const int* __restrict__ cls0, const int* __restrict__ cls1, int* meta)
{
    int g = blockIdx.x; int L = g >> 3, b = g & 7;
    const int* cls = (L ? cls1 : cls0) + b * 4800;
    int* mt = meta + (L * 8 + b) * 16;
    __shared__ int cnt[8];
    int t = threadIdx.x;
    if (t < 8) cnt[t] = 0;
    __syncthreads();
    for (int tok = t; tok < 4800; tok += 256) {
        int c = cls[tok];
        if (c >= 0) atomicAdd(&cnt[c], 1);
    }
    __syncthreads();
    if (t == 0) {
        int s = 0;
        for (int c = 0; c < 8; c++) { mt[c * 2] = s; mt[c * 2 + 1] = cnt[c]; s += cnt[c]; }
    }
}

// ---------------- cross-batch scan: minfo (Mv, boff) + compact cmeta ---------
__global__ __launch_bounds__(256) void lft_scan_kernel(
    const int* __restrict__ meta, int* minfo, int* cmeta)
{
    int t = threadIdx.x;
    __shared__ int nb[16];
    if (t < 16) {
        int s = 0;
        for (int c = 0; c < 8; c++) s += meta[t * 16 + c * 2 + 1];
        nb[t] = s;
    }
    __syncthreads();
    if (t == 0) {
        int off = 0;
        for (int b = 0; b < 8; b++) { minfo[4 + b] = off; off += nb[b]; }
        minfo[2] = off; minfo[0] = (off + 127) & ~127;
        off = 0;
        for (int b = 0; b < 8; b++) { minfo[12 + b] = off; off += nb[8 + b]; }
        minfo[3] = off; minfo[1] = (off + 127) & ~127;
    }
    __syncthreads();
    if (t < 128) {
        int L = t >> 6, b = (t >> 3) & 7, c = t & 7;
        cmeta[t * 2]     = minfo[4 + L * 8 + b] + meta[(L * 8 + b) * 16 + c * 2];
        cmeta[t * 2 + 1] = meta[(L * 8 + b) * 16 + c * 2 + 1];
    }
}

// ---------------- place valid tokens into compact gather lists ---------------
__global__ __launch_bounds__(256) void lft_place_kernel(
    const int* __restrict__ cls0, const int* __restrict__ cls1,
    const int* __restrict__ cmeta, int* gl)
{
    int g = blockIdx.x; int L = g >> 3, b = g & 7;
    const int* cls = (L ? cls1 : cls0) + b * 4800;
    int* glp = gl + L * CAP;
    __shared__ int pos[8];
    int t = threadIdx.x;
    if (t < 8) pos[t] = cmeta[(L * 64 + b * 8 + t) * 2];
    __syncthreads();
    for (int tok = t; tok < 4800; tok += 256) {
        int c = cls[tok];
        if (c >= 0) { int p = atomicAdd(&pos[c], 1); glp[p] = b * 4800 + tok; }
    }
}

// ---------------- gather-cast: compact bf16 x + compact fp32 resid -----------
__global__ __launch_bounds__(256) void lft_gcast_kernel(
    const float* __restrict__ f0, const float* __restrict__ f1,
    const int* __restrict__ gl, const int* __restrict__ minfo,
    ushort* xc, float* rc)
{
    int blk = blockIdx.x;
    int side = blk >= 600 ? 1 : 0;
    int i0 = (blk - side * 600) * 4 + (threadIdx.x >> 6);
    int mv = minfo[2 + side];
    const int* glp = gl + side * CAP;
    const float* f = side ? f1 : f0;
    ushort* xcp = xc + side * CAP * 256;
    float* rcp = rc + side * CAP * 256;
    int lane = threadIdx.x & 63;
    for (int i = i0; i < mv; i += 2400) {
        long src = (long)glp[i] * 256 + lane * 4;
        float4 v = *(const float4*)&f[src];
        long dst = (long)i * 256 + lane * 4;
        *(float4*)&rcp[dst] = v;
        ushort4 u; u.x = f2b(v.x); u.y = f2b(v.y); u.z = f2b(v.z); u.w = f2b(v.w);
        *(ushort4*)&xcp[dst] = u;
    }
}

// ---------------- weight convert + transpose: Wt[n*K+k] = bf16(W[k*N+n]) ----
__global__ __launch_bounds__(256) void lft_wconv_kernel(
    const float* W0, const float* W1p, const float* W2p, const float* W3p,
    int K, int N, int nTypes, ushort* dst)
{
    int z = blockIdx.z;
    int li = z / nTypes, mi = z % nTypes;
    const float* srcs[4] = {W0, W1p, W2p, W3p};
    const float* src = srcs[mi] + (size_t)li * K * N;
    ushort* outp = dst + (size_t)z * K * N;
    __shared__ float tile[32][33];
    int k0 = blockIdx.x * 32, n0 = blockIdx.y * 32;
    int t = threadIdx.x;
    int r = t >> 3, c4 = (t & 7) << 2;
    float4 v = *(const float4*)&src[(size_t)(k0 + r) * N + n0 + c4];
    tile[r][c4] = v.x; tile[r][c4 + 1] = v.y; tile[r][c4 + 2] = v.z; tile[r][c4 + 3] = v.w;
    __syncthreads();
    ushort4 o;
    o.x = f2b(tile[c4 + 0][r]);
    o.y = f2b(tile[c4 + 1][r]);
    o.z = f2b(tile[c4 + 2][r]);
    o.w = f2b(tile[c4 + 3][r]);
    *(ushort4*)&outp[(size_t)(n0 + r) * K + k0 + c4] = o;
}

// ---------------- bf16 MFMA GEMM over COMPACT rows ---------------------------
// XCD-aware block swizzle (T1). 3-buffer counted-vmcnt pipeline. 128x128 tile.
// Epilogue: LDS-transposed coalesced bf16 stores; tile stride 136 (row shift
// 16 banks -> quads 2-way = free; 144 gave 4-way = 1.39M conflicts/dispatch).
// act: 1 elu+1 (q); 2 relu (hid, ldc=512); act 3 qkv N=768; act 4 kv N=512.
__global__ __launch_bounds__(256) void lft_mfma_gemm(
    const ushort* __restrict__ A0b, const ushort* __restrict__ A1b, int kSplit,
    const ushort* __restrict__ Wt,
    float* Cf, ushort* Cb, float* Cv, int N, int K, int act,
    const int* __restrict__ minfo, int side0)
{
    __shared__ ushort As[3][128 * 32];
    __shared__ ushort Bs[3][128 * 32];
    int gx = gridDim.x, gy = gridDim.y;
    int G = gx * gy * gridDim.z;
    int orig = (blockIdx.z * gy + blockIdx.y) * gx + blockIdx.x;
    int wid = ((orig & 7) * (G >> 3)) + (orig >> 3);   // G % 8 == 0 (all grids)
    int bx = wid % gx; int rest = wid / gx;
    int by = rest % gy; int bz = rest / gy;
    int side = side0 + bz;
    int m0 = by << 7;
    if (m0 >= minfo[side]) return;
    int n0 = bx << 7;
    const ushort* A0 = A0b + (long)side * CAP * kSplit;
    const ushort* A1 = A1b + (long)side * CAP * (K - kSplit);
    long so256 = (long)side * CAP * 256;
    long soN = (long)side * CAP * N;
    int t = threadIdx.x;
    int wv = t >> 6, lane = t & 63;
    int wm = wv >> 1, wn = wv & 1;
    int l16 = lane & 15, quad = lane >> 4;
    floatx4 acc[4][4] = {};

    int lrow = lane >> 2;
    int lcg = lane & 3;

    auto stage = [&](int buf, int k0) {
        const ushort* Asrc; int kcol, ldA;
        if (k0 < kSplit) { Asrc = A0; kcol = k0;          ldA = kSplit; }
        else             { Asrc = A1; kcol = k0 - kSplit; ldA = K - kSplit; }
        ushort* Ab = &As[buf][0];
        ushort* Bb = &Bs[buf][0];
#pragma unroll
        for (int s = 0; s < 2; s++) {
            int r = s * 64 + wv * 16 + lrow;
            int cgA = (lcg ^ swz(r)) << 3;
            GLOAD16(&Asrc[(size_t)(m0 + r) * ldA + kcol + cgA], &Ab[(s * 64 + wv * 16) * 32]);
            GLOAD16(&Wt[(size_t)(n0 + r) * K + k0 + cgA], &Bb[(s * 64 + wv * 16) * 32]);
        }
    };

    auto compute = [&](int buf) {
        const ushort* Ab = &As[buf][0];
        const ushort* Bb = &Bs[buf][0];
        short8 af[4], bfr[4];
#pragma unroll
        for (int i = 0; i < 4; i++) {
            int rA = wm * 64 + i * 16 + l16;
            int rB = wn * 64 + i * 16 + l16;
            af[i]  = *(const short8*)&Ab[rA * 32 + ((quad ^ swz(rA)) << 3)];
            bfr[i] = *(const short8*)&Bb[rB * 32 + ((quad ^ swz(rB)) << 3)];
        }
        __builtin_amdgcn_s_setprio(1);
#pragma unroll
        for (int i = 0; i < 4; i++)
#pragma unroll
            for (int j = 0; j < 4; j++)
                acc[i][j] = __builtin_amdgcn_mfma_f32_16x16x32_bf16(af[i], bfr[j], acc[i][j], 0, 0, 0);
        __builtin_amdgcn_s_setprio(0);
    };

    int nt = K >> 5;               // 8 or 16
    stage(0, 0);
    stage(1, 32);
    int cur = 0;
    for (int tt = 0; tt < nt; ++tt) {
        if (tt + 2 < nt) {
            int nb = cur + 2; if (nb >= 3) nb -= 3;
            stage(nb, (tt + 2) << 5);
            VMWAIT(8);             // tile tt done; tt+1, tt+2 in flight
        } else if (tt + 2 == nt) {
            VMWAIT(4);
        } else {
            VMWAIT(0);
        }
        BAR();
        compute(cur);
        if (tt + 1 < nt) BAR();
        cur = cur + 1 == 3 ? 0 : cur + 1;
    }

    // ---- LDS-transposed coalesced bf16 epilogue (stride 136) ----
    ushort* dst; int ncol0; int amode; long base; int ldc;
    if (act == 3) {
        base = so256; ldc = 256;
        if (n0 < 256)      { dst = Cb;          ncol0 = n0;       amode = 1; }
        else if (n0 < 512) { dst = (ushort*)Cf; ncol0 = n0 - 256; amode = 1; }
        else               { dst = (ushort*)Cv; ncol0 = n0 - 512; amode = 0; }
    } else if (act == 4) {
        base = so256; ldc = 256;
        if (n0 < 256) { dst = (ushort*)Cf; ncol0 = n0;       amode = 1; }
        else          { dst = (ushort*)Cv; ncol0 = n0 - 256; amode = 0; }
    } else {  // act 1 (q, elu) or act 2 (hid, relu)
        base = soN; ldc = N;
        dst = Cb; ncol0 = n0; amode = (act == 1) ? 1 : 2;
    }
    ushort* tb = &As[0][0];        // 32 x 136 transpose tile (8.7KB, in As[0..1])
    int lr = t >> 3;               // 0..31 (8 threads/row)
    int cs = (t & 7) << 4;         // element offset 0,16,..,112 (16 elems = 32B)
    int wmr = lr >> 4, rloc = lr & 15;
#pragma unroll
    for (int i = 0; i < 4; i++) {
        __syncthreads();           // prior LDS reads (compute / tb) complete
#pragma unroll
        for (int j = 0; j < 4; j++) {
#pragma unroll
            for (int r = 0; r < 4; r++) {
                float v = acc[i][j][r];
                if (amode == 1)      v = elu1(v);
                else if (amode == 2) v = fmaxf(v, 0.f);
                tb[(wm * 16 + quad * 4 + r) * 136 + wn * 64 + j * 16 + l16] = f2b(v);
            }
        }
        __syncthreads();
        long row = m0 + wmr * 64 + i * 16 + rloc;
        short8 v0 = *(const short8*)&tb[lr * 136 + cs];
        short8 v1 = *(const short8*)&tb[lr * 136 + cs + 8];
        *(short8*)&dst[base + row * ldc + ncol0 + cs] = v0;
        *(short8*)&dst[base + row * ldc + ncol0 + cs + 8] = v1;
    }
}

// ---------------- fused GEMM (N=256) + row-LN over COMPACT rows -------------
// 512 threads, M=64 tile (grid.x=384 per side, early-exit), 8 waves (2m x 4n).
// Epilogue: per i-stripe LDS fp32 transpose -> linear coalesced phase.
__global__ __launch_bounds__(512) void lft_gemm_ln(
    const ushort* __restrict__ A0b, const ushort* __restrict__ A1b, int kSplit,
    const ushort* __restrict__ Wt, int K,
    const float* __restrict__ g, const float* __restrict__ bb,
    const float* __restrict__ rcInB, float* rcOutB,
    const int* __restrict__ glB, const int* __restrict__ minfo,
    float* outScB, ushort* __restrict__ outBB, int side0)
{
    __shared__ union {
        struct { ushort As[2][64 * 32]; ushort Bs[2][256 * 32]; } s;  // 40KB
        float tile[32][260];                                          // 33.3KB
    } u;
    __shared__ float gs[256], bs[256];
    __shared__ float psum[4][64], psq[4][64];
    int side = side0 + blockIdx.z;
    long m0 = (long)blockIdx.x << 6;
    if (m0 >= minfo[side]) return;
    const ushort* A0 = A0b + (long)side * CAP * kSplit;
    const ushort* A1 = A1b + (long)side * CAP * (K - kSplit);
    long so = (long)side * CAP * 256;
    int t = threadIdx.x;
    int wv = t >> 6, lane = t & 63;
    int wm = wv >> 2, wn = wv & 3;
    int l16 = lane & 15, quad = lane >> 4;
    if (t < 256) { gs[t] = g[t]; bs[t] = bb[t]; }
    floatx4 acc[2][4] = {};

    int lrow = lane >> 2;
    int lcg = lane & 3;

    auto stage = [&](int buf, int k0) {
        const ushort* Asrc; int kcol, ldA;
        if (k0 < kSplit) { Asrc = A0; kcol = k0;          ldA = kSplit; }
        else             { Asrc = A1; kcol = k0 - kSplit; ldA = K - kSplit; }
        if (wv < 4) {                                      // A rows 0..63
            int r = wv * 16 + lrow;
            int cgA = (lcg ^ swz(r)) << 3;
            GLOAD16(&Asrc[(m0 + r) * ldA + kcol + cgA], &u.s.As[buf][(wv * 16) * 32]);
        }
#pragma unroll
        for (int s = 0; s < 2; s++) {                      // B rows 0..255
            int r = s * 128 + wv * 16 + lrow;
            int cgB = (lcg ^ swz(r)) << 3;
            GLOAD16(&Wt[(size_t)r * K + k0 + cgB], &u.s.Bs[buf][(s * 128 + wv * 16) * 32]);
        }
    };

    int nt = K >> 5;
    stage(0, 0);
    WAIT_BAR();
    int cur = 0;
    for (int tt = 0; tt < nt; ++tt) {
        if (tt + 1 < nt) stage(cur ^ 1, (tt + 1) << 5);
        const ushort* Ab = &u.s.As[cur][0];
        const ushort* Bb = &u.s.Bs[cur][0];
        short8 af[2], bfr[4];
#pragma unroll
        for (int i = 0; i < 2; i++) {
            int rA = wm * 32 + i * 16 + l16;
            af[i] = *(const short8*)&Ab[rA * 32 + ((quad ^ swz(rA)) << 3)];
        }
#pragma unroll
        for (int j = 0; j < 4; j++) {
            int rB = wn * 64 + j * 16 + l16;
            bfr[j] = *(const short8*)&Bb[rB * 32 + ((quad ^ swz(rB)) << 3)];
        }
#pragma unroll
        for (int i = 0; i < 2; i++)
#pragma unroll
            for (int j = 0; j < 4; j++)
                acc[i][j] = __builtin_amdgcn_mfma_f32_16x16x32_bf16(af[i], bfr[j], acc[i][j], 0, 0, 0);
        if (tt + 1 < nt) { WAIT_BAR(); cur ^= 1; }
    }
    // per-row partial sums (this wave's 64 cols) -> LDS
#pragma unroll
    for (int i = 0; i < 2; i++) {
#pragma unroll
        for (int r = 0; r < 4; r++) {
            float s = 0.f, q = 0.f;
#pragma unroll
            for (int j = 0; j < 4; j++) { float v = acc[i][j][r]; s += v; q += v * v; }
#pragma unroll
            for (int o = 8; o >= 1; o >>= 1) {
                s += __shfl_xor(s, o, 64);
                q += __shfl_xor(q, o, 64);
            }
            if (l16 == 0) {
                int row = wm * 32 + i * 16 + quad * 4 + r;
                psum[wn][row] = s; psq[wn][row] = q;
            }
        }
    }
    __syncthreads();
    if (t < 64) {
        float s = psum[0][t] + psum[1][t] + psum[2][t] + psum[3][t];
        float q = psq[0][t] + psq[1][t] + psq[2][t] + psq[3][t];
        float mean = s * (1.0f / 256.0f);
        float var = q * (1.0f / 256.0f) - mean * mean;
        psum[0][t] = mean;
        psq[0][t] = rsqrtf(var + 1e-5f);
    }
    __syncthreads();
    int mvE = minfo[2 + side];
    const float* rcIn = rcInB ? rcInB + so : nullptr;
    float* rcOut = rcOutB ? rcOutB + so : nullptr;
    const int* glp = glB + side * CAP;
    float* outSc = outScB ? outScB + (long)side * 9830400L : nullptr;
    ushort* outB = outBB ? outBB + so : nullptr;
    // ---- coalesced epilogue: 2 stripes of 32 tile-rows ----
#pragma unroll
    for (int i = 0; i < 2; i++) {
        // phase A: LN (no resid) into fp32 tile
#pragma unroll
        for (int r = 0; r < 4; r++) {
            int rloc = wm * 32 + i * 16 + quad * 4 + r;
            int tr = wm * 16 + quad * 4 + r;
            float mean = psum[0][rloc], rstd = psq[0][rloc];
#pragma unroll
            for (int j = 0; j < 4; j++) {
                int col = wn * 64 + j * 16 + l16;
                u.tile[tr][col] = (acc[i][j][r] - mean) * rstd * gs[col] + bs[col];
            }
        }
        __syncthreads();
        // phase B: linear coalesced residual-add + stores
#pragma unroll
        for (int e = 0; e < 4; e++) {
            int idx = e * 512 + t;          // 0..2047
            int tr = idx >> 6;              // tile row 0..31
            int c4 = (idx & 63) << 2;       // col 0..252 step 4
            long arow = m0 + (long)((tr >> 4) * 32 + i * 16 + (tr & 15));
            float4 v = *(float4*)&u.tile[tr][c4];
            if (rcIn) {
                float4 rv = *(const float4*)&rcIn[arow * 256 + c4];
                v.x += rv.x; v.y += rv.y; v.z += rv.z; v.w += rv.w;
            }
            if (rcOut) *(float4*)&rcOut[arow * 256 + c4] = v;
            if (outSc && arow < mvE)
                *(float4*)&outSc[(long)glp[arow] * 256 + c4] = v;
            if (outB) {
                ushort4 uo; uo.x = f2b(v.x); uo.y = f2b(v.y);
                uo.z = f2b(v.z); uo.w = f2b(v.w);
                *(ushort4*)&outB[arow * 256 + c4] = uo;
            }
        }
        if (i == 0) __syncthreads();
    }
}

// ---------------- per-class KV / Ksum reduction (compact, bf16 inputs) -------
// Per-chunk private slots (plain stores, no memset/atomics).
__global__ __launch_bounds__(256) void lft_kv_kernel(
    const ushort* __restrict__ kcB, const ushort* __restrict__ vcB,
    const int* __restrict__ cmetaB,
    float* kvbB, float* ksbB, int sideSrc0)
{
    int side = sideSrc0 + (blockIdx.z >> 6);
    int zz = blockIdx.z & 63;
    int chunk = blockIdx.x, c = blockIdx.y;
    int b = zz >> 3, h = zz & 7;
    const int* cmeta = cmetaB + side * 128;
    int cstart = cmeta[(b * 8 + c) * 2], n = cmeta[(b * 8 + c) * 2 + 1];
    int per = (n + KV_NCH - 1) / KV_NCH;
    int s0 = chunk * per;
    int s1 = min(s0 + per, n);
    const ushort* phik = kcB + (long)side * CAP * 256;
    const ushort* vmat = vcB + (long)side * CAP * 256;
    int slot = side * KV_NCH + chunk;
    float* kv = kvbB + (long)slot * 524288;
    float* ksum = ksbB + (long)slot * 16384;
    int t = threadIdx.x;
    __shared__ float kb[8][32];
    __shared__ float vb[8][32];
    int od = t >> 3, oe = (t & 7) << 2;
    int lt = t >> 5, ld = t & 31;
    float a0 = 0.f, a1 = 0.f, a2 = 0.f, a3 = 0.f, ak = 0.f;
    for (int s = s0; s < s1; s += 8) {
        float kval = 0.f, vval = 0.f;
        if (s + lt < s1) {
            long bse = (long)(cstart + s + lt) * 256 + h * 32 + ld;
            kval = b2f(phik[bse]);
            vval = b2f(vmat[bse]);
        }
        __syncthreads();
        kb[lt][ld] = kval;
        vb[lt][ld] = vval;
        __syncthreads();
#pragma unroll
        for (int j = 0; j < 8; j++) {
            float kd = kb[j][od];
            float4 vv = *(const float4*)&vb[j][oe];
            a0 += kd * vv.x; a1 += kd * vv.y; a2 += kd * vv.z; a3 += kd * vv.w;
            ak += kd;
        }
    }
    float* dst = kv + (((long)(b * NPROTO + c) * 8 + h) << 10) + od * 32 + oe;
    dst[0] = a0; dst[1] = a1; dst[2] = a2; dst[3] = a3;
    if ((t & 7) == 0)
        ksum[(((long)(b * NPROTO + c) * 8 + h) << 5) + od] = ak;
}

// ---------------- msg via MFMA; LDS row-tiled q reads + coalesced writes -----
// qt/ot stride 272 (row shift 8 banks): MFMA reads <=2-way (264 gave 8-way).
__global__ __launch_bounds__(256) void lft_msg_kernel(
    const ushort* __restrict__ qcB, const float* __restrict__ kvbB,
    const float* __restrict__ ksbB, const int* __restrict__ cmetaB,
    ushort* __restrict__ msgcB, int sideX0, int sideKV0)
{
    int add = blockIdx.z >> 3, b = blockIdx.z & 7;
    int sideX = sideX0 + add, sideKV = sideKV0 + add;
    int chunk = blockIdx.x, c = blockIdx.y;
    const int* cmeta = cmetaB + sideX * 128;
    int cstart = cmeta[(b * 8 + c) * 2], n = cmeta[(b * 8 + c) * 2 + 1];
    int per = (n + MSG_NCH - 1) / MSG_NCH;
    int s0 = chunk * per, s1 = min(s0 + per, n);
    if (s0 >= s1) return;
    const ushort* pq = qcB + (long)sideX * CAP * 256;
    ushort* msg = msgcB + (long)sideX * CAP * 256;
    __shared__ ushort qt[16][272];
    __shared__ ushort ot[16][272];
    int t = threadIdx.x;
    int wave = t >> 6, lane = t & 63;
    int l16 = lane & 15, quad = lane >> 4;
    int bc = b * 8 + c;
    short8 bfr[2][3];
#pragma unroll
    for (int hh = 0; hh < 2; hh++) {
        int h = wave * 2 + hh;
        long kvoff = ((long)bc * 8 + h) * 1024;
        long ksoff = ((long)bc * 8 + h) * 32;
#pragma unroll
        for (int nt = 0; nt < 2; nt++)
#pragma unroll
            for (int j = 0; j < 8; j++) {
                float v = 0.f;
#pragma unroll
                for (int ch = 0; ch < KV_NCH; ch++)
                    v += kvbB[(long)(sideKV * KV_NCH + ch) * 524288 + kvoff
                              + (quad * 8 + j) * 32 + nt * 16 + l16];
                bfr[hh][nt][j] = (short)f2b(v);
            }
#pragma unroll
        for (int j = 0; j < 8; j++) {
            float v = 0.f;
#pragma unroll
            for (int ch = 0; ch < KV_NCH; ch++)
                v += ksbB[(long)(sideKV * KV_NCH + ch) * 16384 + ksoff + quad * 8 + j];
            bfr[hh][2][j] = (l16 == 0) ? (short)f2b(v) : (short)0;
        }
    }
    int srow = t >> 5;              // staging row 0..7 (x2 iters -> 0..15)
    int scol = (t & 31) << 3;       // 8-elem group 0..248
    for (int s = s0; s < s1; s += 16) {
        // stage 16 q rows (clamped) coalesced
#pragma unroll
        for (int it = 0; it < 2; it++) {
            int sr = it * 8 + srow;
            int rr = min(s + sr, s1 - 1);
            *(short8*)&qt[sr][scol] = *(const short8*)&pq[(long)(cstart + rr) * 256 + scol];
        }
        __syncthreads();
#pragma unroll
        for (int hh = 0; hh < 2; hh++) {
            int h = wave * 2 + hh;
            short8 a = *(const short8*)&qt[l16][h * 32 + quad * 8];
            floatx4 n0 = {}, n1 = {}, dd = {};
            n0 = __builtin_amdgcn_mfma_f32_16x16x32_bf16(a, bfr[hh][0], n0, 0, 0, 0);
            n1 = __builtin_amdgcn_mfma_f32_16x16x32_bf16(a, bfr[hh][1], n1, 0, 0, 0);
            dd = __builtin_amdgcn_mfma_f32_16x16x32_bf16(a, bfr[hh][2], dd, 0, 0, 0);
#pragma unroll
            for (int r = 0; r < 4; r++) {
                float den = __shfl(dd[r], lane & 48, 64);
                float inv = 1.f / (den + 1e-6f);
                ot[quad * 4 + r][h * 32 + l16]      = f2b(n0[r] * inv);
                ot[quad * 4 + r][h * 32 + 16 + l16] = f2b(n1[r] * inv);
            }
        }
        __syncthreads();
        // coalesced write-out with tail guard
#pragma unroll
        for (int it = 0; it < 2; it++) {
            int sr = it * 8 + srow;
            if (s + sr < s1)
                *(short8*)&msg[(long)(cstart + s + sr) * 256 + scol] =
                    *(const short8*)&ot[sr][scol];
        }
        __syncthreads();
    }
}

extern "C" void kernel_launch(void* const* d_in, const int* in_sizes, int n_in,
                              void* d_out, int out_size, void* d_ws, size_t ws_size,
                              hipStream_t stream)
{
    (void)in_sizes; (void)n_in; (void)out_size; (void)ws_size;
    const float* feat0 = (const float*)d_in[0];
    const float* feat1 = (const float*)d_in[1];
    const int*   mask0 = (const int*)d_in[2];
    const int*   mask1 = (const int*)d_in[3];
    const float* f0wo  = (const float*)d_in[4];
    const float* f1wo  = (const float*)d_in[5];
    const float* proto = (const float*)d_in[6];
    const float* Wq = (const float*)d_in[7];
    const float* Wk = (const float*)d_in[8];
    const float* Wv = (const float*)d_in[9];
    const float* Wm = (const float*)d_in[10];
    const float* W1 = (const float*)d_in[11];
    const float* W2 = (const float*)d_in[12];
    const float* g1 = (const float*)d_in[13];
    const float* b1 = (const float*)d_in[14];
    const float* g2 = (const float*)d_in[15];
    const float* b2 = (const float*)d_in[16];
    float* out = (float*)d_out;
    float* ws = (float*)d_ws;

    // ---- workspace layout (side-strided compact buffers, CAP rows/side) ----
    const long FSZ = 9830400L;
    float* rc = ws;                               // 2*CAP*256 f
    ushort* kc = (ushort*)(rc + 2 * CAP * 256);   // 2*CAP*256 us  bf16
    ushort* vc = kc + 2 * CAP * 256;              // 2*CAP*256 us  bf16
    ushort* hid = vc + 2 * CAP * 256;             // 2*CAP*512 us
    ushort* xc   = hid + 2 * CAP * 512;
    ushort* msgc = xc + 2 * CAP * 256;
    ushort* qc   = msgc + 2 * CAP * 256;
    ushort* wb   = qc + 2 * CAP * 256;
    ushort* wb1  = wb + 16 * 65536;
    ushort* wb2  = wb1 + 4 * 262144;
    float* ksb = (float*)(wb2 + 4 * 131072);      // 2*KV_NCH*16384 f
    int* cls0 = (int*)(ksb + 2 * KV_NCH * 16384);
    int* cls1 = cls0 + 38400;
    int* gl   = cls1 + 38400;                     // 2*CAP ints
    int* meta = gl + 2 * CAP;
    int* minfo = meta + 256;
    int* cmeta = minfo + 20;
    // kvb aliases hid (dead between kv_kernel and w1-GEMM)
    float* kvb = (float*)hid;

    lft_wconv_kernel<<<dim3(8, 8, 16), 256, 0, stream>>>(Wq, Wk, Wv, Wm, 256, 256, 4, wb);
    lft_wconv_kernel<<<dim3(16, 16, 4), 256, 0, stream>>>(W1, W1, W1, W1, 512, 512, 1, wb1);
    lft_wconv_kernel<<<dim3(16, 8, 4), 256, 0, stream>>>(W2, W2, W2, W2, 512, 256, 1, wb2);
    hipMemcpyAsync(out + 20352000L, proto, 2048 * 4, hipMemcpyDeviceToDevice, stream);
    lft_class_kernel<<<600, 256, 0, stream>>>(f0wo, f1wo, mask0, mask1, proto,
                                              out, cls0, cls1);
    lft_invcopy_kernel<<<1200, 256, 0, stream>>>(feat0, feat1, cls0, cls1, out);
    lft_count_kernel<<<16, 256, 0, stream>>>(cls0, cls1, meta);
    lft_scan_kernel<<<1, 256, 0, stream>>>(meta, minfo, cmeta);
    lft_place_kernel<<<16, 256, 0, stream>>>(cls0, cls1, cmeta, gl);
    lft_gcast_kernel<<<1200, 256, 0, stream>>>(feat0, feat1, gl, minfo, xc, rc);

    dim3 blk(256);
    dim3 blkL(512);
    for (int li = 0; li < 4; li++) {
        const ushort* wq = wb + (size_t)(li * 4 + 0) * 65536;   // [wq|wk|wv|wm]
        const ushort* wk = wb + (size_t)(li * 4 + 1) * 65536;
        const ushort* wm = wb + (size_t)(li * 4 + 3) * 65536;
        const ushort* w1 = wb1 + (size_t)li * 262144;
        const ushort* w2 = wb2 + (size_t)li * 131072;
        const float* g1p = g1 + li * 256; const float* b1p = b1 + li * 256;
        const float* g2p = g2 + li * 256; const float* b2p = b2 + li * 256;
        bool last = (li == 3);

        if ((li & 1) == 0) {
            // ---- self-self, both sides combined (z=2) ----
            lft_mfma_gemm<<<dim3(6, 192, 2), blk, 0, stream>>>(
                xc, xc, 256, wq, (float*)kc, qc, (float*)vc, 768, 256, 3, minfo, 0);
            lft_kv_kernel<<<dim3(KV_NCH, 8, 128), blk, 0, stream>>>(kc, vc, cmeta, kvb, ksb, 0);
            lft_msg_kernel<<<dim3(MSG_NCH, 8, 16), blk, 0, stream>>>(qc, kvb, ksb, cmeta, msgc, 0, 0);
            lft_gemm_ln<<<dim3(384, 1, 2), blkL, 0, stream>>>(
                msgc, msgc, 256, wm, 256, g1p, b1p,
                nullptr, nullptr, gl, minfo, nullptr, msgc, 0);
            lft_mfma_gemm<<<dim3(4, 192, 2), blk, 0, stream>>>(
                xc, msgc, 256, w1, nullptr, hid, nullptr, 512, 512, 2, minfo, 0);
            lft_gemm_ln<<<dim3(384, 1, 2), blkL, 0, stream>>>(
                hid, hid, 512, w2, 512, g2p, b2p,
                rc, rc, gl, minfo, nullptr, xc, 0);
        } else {
            // ---- cross-self: q for both sides from OLD features ----
            lft_mfma_gemm<<<dim3(2, 192, 2), blk, 0, stream>>>(
                xc, xc, 256, wq, nullptr, qc, nullptr, 256, 256, 1, minfo, 0);
            // k|v from side1 (old) -> kc/vc side1
            lft_mfma_gemm<<<dim3(4, 192, 1), blk, 0, stream>>>(
                xc, xc, 256, wk, (float*)kc, nullptr, (float*)vc, 512, 256, 4, minfo, 1);
            lft_kv_kernel<<<dim3(KV_NCH, 8, 64), blk, 0, stream>>>(kc, vc, cmeta, kvb, ksb, 1);
            lft_msg_kernel<<<dim3(MSG_NCH, 8, 8), blk, 0, stream>>>(qc, kvb, ksb, cmeta, msgc, 0, 1);
            lft_gemm_ln<<<dim3(384, 1, 1), blkL, 0, stream>>>(
                msgc, msgc, 256, wm, 256, g1p, b1p,
                nullptr, nullptr, gl, minfo, nullptr, msgc, 0);
            lft_mfma_gemm<<<dim3(4, 192, 1), blk, 0, stream>>>(
                xc, msgc, 256, w1, nullptr, hid, nullptr, 512, 512, 2, minfo, 0);
            lft_gemm_ln<<<dim3(384, 1, 1), blkL, 0, stream>>>(
                hid, hid, 512, w2, 512, g2p, b2p,
                rc, last ? nullptr : rc, gl, minfo, last ? out : nullptr, xc, 0);
            // ---- side1 attends UPDATED side0 ----
            lft_mfma_gemm<<<dim3(4, 192, 1), blk, 0, stream>>>(
                xc, xc, 256, wk, (float*)kc, nullptr, (float*)vc, 512, 256, 4, minfo, 0);
            lft_kv_kernel<<<dim3(KV_NCH, 8, 64), blk, 0, stream>>>(kc, vc, cmeta, kvb, ksb, 0);
            lft_msg_kernel<<<dim3(MSG_NCH, 8, 8), blk, 0, stream>>>(qc, kvb, ksb, cmeta, msgc, 1, 0);
            lft_gemm_ln<<<dim3(384, 1, 1), blkL, 0, stream>>>(
                msgc, msgc, 256, wm, 256, g1p, b1p,
                nullptr, nullptr, gl, minfo, nullptr, msgc, 1);
            lft_mfma_gemm<<<dim3(4, 192, 1), blk, 0, stream>>>(
                xc, msgc, 256, w1, nullptr, hid, nullptr, 512, 512, 2, minfo, 1);
            lft_gemm_ln<<<dim3(384, 1, 1), blkL, 0, stream>>>(
                hid, hid, 512, w2, 512, g2p, b2p,
                rc, last ? nullptr : rc, gl, minfo, last ? out : nullptr,
                last ? nullptr : xc, 1);
        }
    }
}

// Round 22
// 1111.157 us; speedup vs baseline: 1.4838x; 1.0876x over previous
//
#include <hip/hip_runtime.h>
#include <math.h>

#define NPROTO 8
#define KV_NCH 4
#define MSG_NCH 8
#define CAP 24576L            // compact rows per side (Mv ~= 19200 +- ~200)

typedef __attribute__((ext_vector_type(8))) short short8;
typedef __attribute__((ext_vector_type(4))) float floatx4;

static __device__ __forceinline__ ushort f2b(float f) {
    unsigned u = __builtin_bit_cast(unsigned, f);
    unsigned r = (u + 0x7fffu + ((u >> 16) & 1u)) >> 16;
    return (ushort)r;
}

static __device__ __forceinline__ float b2f(ushort u) {
    return __builtin_bit_cast(float, (unsigned)u << 16);
}

static __device__ __forceinline__ float elu1(float v) {
    return v > 0.f ? v + 1.f : __expf(v);
}

// async 16B global -> LDS (linear dest: wave base + lane*16B)
#define GLOAD16(gp, lp) __builtin_amdgcn_global_load_lds( \
    (const __attribute__((address_space(1))) void*)(gp),  \
    (__attribute__((address_space(3))) void*)(lp), 16, 0, 0)

// full drain + barrier (gemm_ln's proven 2-phase structure)
#define WAIT_BAR() asm volatile("s_waitcnt vmcnt(0) lgkmcnt(0)\n\ts_barrier" ::: "memory")
// counted waits (mfma_gemm 3-buffer pipeline; 4 loads/thread/tile)
#define VMWAIT(N) asm volatile("s_waitcnt vmcnt(" #N ")" ::: "memory")
#define BAR() __builtin_amdgcn_s_barrier()

// swizzle of the 16B-group index within a 32-col bf16 row (4 groups/row)
static __device__ __forceinline__ int swz(int r) { return (r >> 1) & 3; }

// ---------------- prototype projection / argmax-class kernel ----------------
__global__ __launch_bounds__(256) void lft_class_kernel(
    const float* __restrict__ f0wo, const float* __restrict__ f1wo,
    const int* __restrict__ mask0, const int* __restrict__ mask1,
    const float* __restrict__ proto,
    float* out, int* cls0, int* cls1)
{
    __shared__ float pr[2048];          // proto [8][256]
    __shared__ float tile[128][68];     // [token][ch chunk], stride 68
    __shared__ float sm[128][8];
    int t = threadIdx.x;
    *(float4*)&pr[t * 4]        = *(const float4*)&proto[t * 4];
    *(float4*)&pr[1024 + t * 4] = *(const float4*)&proto[1024 + t * 4];
    long tok0 = (long)blockIdx.x * 128;
    const float* fsrc; const int* msrc; float* fpout; float* clsout; int* clsarr; long tbase;
    if (tok0 < 38400) {
        tbase = tok0; fsrc = f0wo; msrc = mask0;
        fpout = out + 19737600L; clsout = out + 19660800L; clsarr = cls0;
    } else {
        tbase = tok0 - 38400; fsrc = f1wo; msrc = mask1;
        fpout = out + 20044800L; clsout = out + 19699200L; clsarr = cls1;
    }
    int tok = t & 127, half = t >> 7;
    float s[4] = {};
    int r0 = t >> 4;            // 0..15
    int c4 = (t & 15) << 2;     // 0..60
    for (int ct = 0; ct < 4; ct++) {
        __syncthreads();
#pragma unroll
        for (int rr = 0; rr < 8; rr++) {
            int row = rr * 16 + r0;
            float4 v = *(const float4*)&fsrc[(tbase + row) * 256 + ct * 64 + c4];
            *(float4*)&tile[row][c4] = v;
        }
        __syncthreads();
#pragma unroll
        for (int cc = 0; cc < 16; cc++) {
            float4 f = *(const float4*)&tile[tok][cc << 2];
#pragma unroll
            for (int p = 0; p < 4; p++) {
                float4 pv = *(const float4*)&pr[(half * 4 + p) * 256 + ct * 64 + (cc << 2)];
                s[p] += f.x * pv.x + f.y * pv.y + f.z * pv.z + f.w * pv.w;
            }
        }
    }
#pragma unroll
    for (int p = 0; p < 4; p++) {
        fpout[(tbase + tok) * 8 + half * 4 + p] = s[p];
        sm[tok][half * 4 + p] = s[p];
    }
    __syncthreads();
    if (t < 128) {
        int best = 0; float bv = sm[t][0];
#pragma unroll
        for (int p = 1; p < 8; p++) { if (sm[t][p] > bv) { bv = sm[t][p]; best = p; } }
        clsout[tbase + t] = (float)best;
        clsarr[tbase + t] = msrc[tbase + t] ? best : -1;
    }
}

// ---------------- copy ONLY invalid-token rows of feat into out --------------
__global__ __launch_bounds__(256) void lft_invcopy_kernel(
    const float* __restrict__ f0, const float* __restrict__ f1,
    const int* __restrict__ cls0, const int* __restrict__ cls1,
    float* out)
{
    int w = blockIdx.x * 4 + (threadIdx.x >> 6);   // 0..4799
    int lane = threadIdx.x & 63;
    for (long row = w; row < 76800; row += 4800) {
        int side = row >= 38400;
        long r = row - (long)side * 38400;
        int c = side ? cls1[r] : cls0[r];
        if (c < 0) {
            const float* src = side ? f1 : f0;
            float4 v = *(const float4*)&src[r * 256 + lane * 4];
            *(float4*)&out[(long)side * 9830400L + r * 256 + lane * 4] = v;
        }
    }
}

// ---------------- per-(L,b) class counts -> meta {base,cnt} ------------------
__global__ __launch_bounds__(256) void lft_count_kernel(
    const int* __restrict__ cls0, const int* __restrict__ cls1, int* meta)
{
    int g = blockIdx.x; int L = g >> 3, b = g & 7;
    const int* cls = (L ? cls1 : cls0) + b * 4800;
    int* mt = meta + (L * 8 + b) * 16;
    __shared__ int cnt[8];
    int t = threadIdx.x;
    if (t < 8) cnt[t] = 0;
    __syncthreads();
    for (int tok = t; tok < 4800; tok += 256) {
        int c = cls[tok];
        if (c >= 0) atomicAdd(&cnt[c], 1);
    }
    __syncthreads();
    if (t == 0) {
        int s = 0;
        for (int c = 0; c < 8; c++) { mt[c * 2] = s; mt[c * 2 + 1] = cnt[c]; s += cnt[c]; }
    }
}

// ---------------- cross-batch scan: minfo (Mv, boff) + compact cmeta ---------
__global__ __launch_bounds__(256) void lft_scan_kernel(
    const int* __restrict__ meta, int* minfo, int* cmeta)
{
    int t = threadIdx.x;
    __shared__ int nb[16];
    if (t < 16) {
        int s = 0;
        for (int c = 0; c < 8; c++) s += meta[t * 16 + c * 2 + 1];
        nb[t] = s;
    }
    __syncthreads();
    if (t == 0) {
        int off = 0;
        for (int b = 0; b < 8; b++) { minfo[4 + b] = off; off += nb[b]; }
        minfo[2] = off; minfo[0] = (off + 127) & ~127;
        off = 0;
        for (int b = 0; b < 8; b++) { minfo[12 + b] = off; off += nb[8 + b]; }
        minfo[3] = off; minfo[1] = (off + 127) & ~127;
    }
    __syncthreads();
    if (t < 128) {
        int L = t >> 6, b = (t >> 3) & 7, c = t & 7;
        cmeta[t * 2]     = minfo[4 + L * 8 + b] + meta[(L * 8 + b) * 16 + c * 2];
        cmeta[t * 2 + 1] = meta[(L * 8 + b) * 16 + c * 2 + 1];
    }
}

// ---------------- place valid tokens into compact gather lists ---------------
__global__ __launch_bounds__(256) void lft_place_kernel(
    const int* __restrict__ cls0, const int* __restrict__ cls1,
    const int* __restrict__ cmeta, int* gl)
{
    int g = blockIdx.x; int L = g >> 3, b = g & 7;
    const int* cls = (L ? cls1 : cls0) + b * 4800;
    int* glp = gl + L * CAP;
    __shared__ int pos[8];
    int t = threadIdx.x;
    if (t < 8) pos[t] = cmeta[(L * 64 + b * 8 + t) * 2];
    __syncthreads();
    for (int tok = t; tok < 4800; tok += 256) {
        int c = cls[tok];
        if (c >= 0) { int p = atomicAdd(&pos[c], 1); glp[p] = b * 4800 + tok; }
    }
}

// ---------------- gather-cast: compact bf16 x + compact fp32 resid -----------
__global__ __launch_bounds__(256) void lft_gcast_kernel(
    const float* __restrict__ f0, const float* __restrict__ f1,
    const int* __restrict__ gl, const int* __restrict__ minfo,
    ushort* xc, float* rc)
{
    int blk = blockIdx.x;
    int side = blk >= 600 ? 1 : 0;
    int i0 = (blk - side * 600) * 4 + (threadIdx.x >> 6);
    int mv = minfo[2 + side];
    const int* glp = gl + side * CAP;
    const float* f = side ? f1 : f0;
    ushort* xcp = xc + side * CAP * 256;
    float* rcp = rc + side * CAP * 256;
    int lane = threadIdx.x & 63;
    for (int i = i0; i < mv; i += 2400) {
        long src = (long)glp[i] * 256 + lane * 4;
        float4 v = *(const float4*)&f[src];
        long dst = (long)i * 256 + lane * 4;
        *(float4*)&rcp[dst] = v;
        ushort4 u; u.x = f2b(v.x); u.y = f2b(v.y); u.z = f2b(v.z); u.w = f2b(v.w);
        *(ushort4*)&xcp[dst] = u;
    }
}

// ---------------- weight convert + transpose: Wt[n*K+k] = bf16(W[k*N+n]) ----
__global__ __launch_bounds__(256) void lft_wconv_kernel(
    const float* W0, const float* W1p, const float* W2p, const float* W3p,
    int K, int N, int nTypes, ushort* dst)
{
    int z = blockIdx.z;
    int li = z / nTypes, mi = z % nTypes;
    const float* srcs[4] = {W0, W1p, W2p, W3p};
    const float* src = srcs[mi] + (size_t)li * K * N;
    ushort* outp = dst + (size_t)z * K * N;
    __shared__ float tile[32][33];
    int k0 = blockIdx.x * 32, n0 = blockIdx.y * 32;
    int t = threadIdx.x;
    int r = t >> 3, c4 = (t & 7) << 2;
    float4 v = *(const float4*)&src[(size_t)(k0 + r) * N + n0 + c4];
    tile[r][c4] = v.x; tile[r][c4 + 1] = v.y; tile[r][c4 + 2] = v.z; tile[r][c4 + 3] = v.w;
    __syncthreads();
    ushort4 o;
    o.x = f2b(tile[c4 + 0][r]);
    o.y = f2b(tile[c4 + 1][r]);
    o.z = f2b(tile[c4 + 2][r]);
    o.w = f2b(tile[c4 + 3][r]);
    *(ushort4*)&outp[(size_t)(n0 + r) * K + k0 + c4] = o;
}

// ---------------- bf16 MFMA GEMM over COMPACT rows ---------------------------
// XCD-aware block swizzle (T1). 3-buffer counted-vmcnt pipeline. 128x128 tile.
// Epilogue: LDS-transposed coalesced bf16 stores, tile stride 136.
// act: 1 elu+1 (q); 2 relu (hid, ldc=512); act 3 qkv N=768; act 4 kv N=512.
__global__ __launch_bounds__(256) void lft_mfma_gemm(
    const ushort* __restrict__ A0b, const ushort* __restrict__ A1b, int kSplit,
    const ushort* __restrict__ Wt,
    float* Cf, ushort* Cb, float* Cv, int N, int K, int act,
    const int* __restrict__ minfo, int side0)
{
    __shared__ ushort As[3][128 * 32];
    __shared__ ushort Bs[3][128 * 32];
    int gx = gridDim.x, gy = gridDim.y;
    int G = gx * gy * gridDim.z;
    int orig = (blockIdx.z * gy + blockIdx.y) * gx + blockIdx.x;
    int wid = ((orig & 7) * (G >> 3)) + (orig >> 3);   // G % 8 == 0 (all grids)
    int bx = wid % gx; int rest = wid / gx;
    int by = rest % gy; int bz = rest / gy;
    int side = side0 + bz;
    int m0 = by << 7;
    if (m0 >= minfo[side]) return;
    int n0 = bx << 7;
    const ushort* A0 = A0b + (long)side * CAP * kSplit;
    const ushort* A1 = A1b + (long)side * CAP * (K - kSplit);
    long so256 = (long)side * CAP * 256;
    long soN = (long)side * CAP * N;
    int t = threadIdx.x;
    int wv = t >> 6, lane = t & 63;
    int wm = wv >> 1, wn = wv & 1;
    int l16 = lane & 15, quad = lane >> 4;
    floatx4 acc[4][4] = {};

    int lrow = lane >> 2;
    int lcg = lane & 3;

    auto stage = [&](int buf, int k0) {
        const ushort* Asrc; int kcol, ldA;
        if (k0 < kSplit) { Asrc = A0; kcol = k0;          ldA = kSplit; }
        else             { Asrc = A1; kcol = k0 - kSplit; ldA = K - kSplit; }
        ushort* Ab = &As[buf][0];
        ushort* Bb = &Bs[buf][0];
#pragma unroll
        for (int s = 0; s < 2; s++) {
            int r = s * 64 + wv * 16 + lrow;
            int cgA = (lcg ^ swz(r)) << 3;
            GLOAD16(&Asrc[(size_t)(m0 + r) * ldA + kcol + cgA], &Ab[(s * 64 + wv * 16) * 32]);
            GLOAD16(&Wt[(size_t)(n0 + r) * K + k0 + cgA], &Bb[(s * 64 + wv * 16) * 32]);
        }
    };

    auto compute = [&](int buf) {
        const ushort* Ab = &As[buf][0];
        const ushort* Bb = &Bs[buf][0];
        short8 af[4], bfr[4];
#pragma unroll
        for (int i = 0; i < 4; i++) {
            int rA = wm * 64 + i * 16 + l16;
            int rB = wn * 64 + i * 16 + l16;
            af[i]  = *(const short8*)&Ab[rA * 32 + ((quad ^ swz(rA)) << 3)];
            bfr[i] = *(const short8*)&Bb[rB * 32 + ((quad ^ swz(rB)) << 3)];
        }
        __builtin_amdgcn_s_setprio(1);
#pragma unroll
        for (int i = 0; i < 4; i++)
#pragma unroll
            for (int j = 0; j < 4; j++)
                acc[i][j] = __builtin_amdgcn_mfma_f32_16x16x32_bf16(af[i], bfr[j], acc[i][j], 0, 0, 0);
        __builtin_amdgcn_s_setprio(0);
    };

    int nt = K >> 5;               // 8 or 16
    stage(0, 0);
    stage(1, 32);
    int cur = 0;
    for (int tt = 0; tt < nt; ++tt) {
        if (tt + 2 < nt) {
            int nb = cur + 2; if (nb >= 3) nb -= 3;
            stage(nb, (tt + 2) << 5);
            VMWAIT(8);             // tile tt done; tt+1, tt+2 in flight
        } else if (tt + 2 == nt) {
            VMWAIT(4);
        } else {
            VMWAIT(0);
        }
        BAR();
        compute(cur);
        if (tt + 1 < nt) BAR();
        cur = cur + 1 == 3 ? 0 : cur + 1;
    }

    // ---- LDS-transposed coalesced bf16 epilogue (stride 136) ----
    ushort* dst; int ncol0; int amode; long base; int ldc;
    if (act == 3) {
        base = so256; ldc = 256;
        if (n0 < 256)      { dst = Cb;          ncol0 = n0;       amode = 1; }
        else if (n0 < 512) { dst = (ushort*)Cf; ncol0 = n0 - 256; amode = 1; }
        else               { dst = (ushort*)Cv; ncol0 = n0 - 512; amode = 0; }
    } else if (act == 4) {
        base = so256; ldc = 256;
        if (n0 < 256) { dst = (ushort*)Cf; ncol0 = n0;       amode = 1; }
        else          { dst = (ushort*)Cv; ncol0 = n0 - 256; amode = 0; }
    } else {  // act 1 (q, elu) or act 2 (hid, relu)
        base = soN; ldc = N;
        dst = Cb; ncol0 = n0; amode = (act == 1) ? 1 : 2;
    }
    ushort* tb = &As[0][0];        // 32 x 136 transpose tile (8.7KB, in As[0..1])
    int lr = t >> 3;               // 0..31 (8 threads/row)
    int cs = (t & 7) << 4;         // element offset 0,16,..,112 (16 elems = 32B)
    int wmr = lr >> 4, rloc = lr & 15;
#pragma unroll
    for (int i = 0; i < 4; i++) {
        __syncthreads();           // prior LDS reads (compute / tb) complete
#pragma unroll
        for (int j = 0; j < 4; j++) {
#pragma unroll
            for (int r = 0; r < 4; r++) {
                float v = acc[i][j][r];
                if (amode == 1)      v = elu1(v);
                else if (amode == 2) v = fmaxf(v, 0.f);
                tb[(wm * 16 + quad * 4 + r) * 136 + wn * 64 + j * 16 + l16] = f2b(v);
            }
        }
        __syncthreads();
        long row = m0 + wmr * 64 + i * 16 + rloc;
        short8 v0 = *(const short8*)&tb[lr * 136 + cs];
        short8 v1 = *(const short8*)&tb[lr * 136 + cs + 8];
        *(short8*)&dst[base + row * ldc + ncol0 + cs] = v0;
        *(short8*)&dst[base + row * ldc + ncol0 + cs + 8] = v1;
    }
}

// ---------------- fused GEMM (N=256) + row-LN over COMPACT rows -------------
// 512 threads, M=64 tile (grid.x=384 per side, early-exit), 8 waves (2m x 4n).
// Epilogue: per i-stripe LDS fp32 transpose -> linear coalesced phase.
__global__ __launch_bounds__(512) void lft_gemm_ln(
    const ushort* __restrict__ A0b, const ushort* __restrict__ A1b, int kSplit,
    const ushort* __restrict__ Wt, int K,
    const float* __restrict__ g, const float* __restrict__ bb,
    const float* __restrict__ rcInB, float* rcOutB,
    const int* __restrict__ glB, const int* __restrict__ minfo,
    float* outScB, ushort* __restrict__ outBB, int side0)
{
    __shared__ union {
        struct { ushort As[2][64 * 32]; ushort Bs[2][256 * 32]; } s;  // 40KB
        float tile[32][260];                                          // 33.3KB
    } u;
    __shared__ float gs[256], bs[256];
    __shared__ float psum[4][64], psq[4][64];
    int side = side0 + blockIdx.z;
    long m0 = (long)blockIdx.x << 6;
    if (m0 >= minfo[side]) return;
    const ushort* A0 = A0b + (long)side * CAP * kSplit;
    const ushort* A1 = A1b + (long)side * CAP * (K - kSplit);
    long so = (long)side * CAP * 256;
    int t = threadIdx.x;
    int wv = t >> 6, lane = t & 63;
    int wm = wv >> 2, wn = wv & 3;
    int l16 = lane & 15, quad = lane >> 4;
    if (t < 256) { gs[t] = g[t]; bs[t] = bb[t]; }
    floatx4 acc[2][4] = {};

    int lrow = lane >> 2;
    int lcg = lane & 3;

    auto stage = [&](int buf, int k0) {
        const ushort* Asrc; int kcol, ldA;
        if (k0 < kSplit) { Asrc = A0; kcol = k0;          ldA = kSplit; }
        else             { Asrc = A1; kcol = k0 - kSplit; ldA = K - kSplit; }
        if (wv < 4) {                                      // A rows 0..63
            int r = wv * 16 + lrow;
            int cgA = (lcg ^ swz(r)) << 3;
            GLOAD16(&Asrc[(m0 + r) * ldA + kcol + cgA], &u.s.As[buf][(wv * 16) * 32]);
        }
#pragma unroll
        for (int s = 0; s < 2; s++) {                      // B rows 0..255
            int r = s * 128 + wv * 16 + lrow;
            int cgB = (lcg ^ swz(r)) << 3;
            GLOAD16(&Wt[(size_t)r * K + k0 + cgB], &u.s.Bs[buf][(s * 128 + wv * 16) * 32]);
        }
    };

    int nt = K >> 5;
    stage(0, 0);
    WAIT_BAR();
    int cur = 0;
    for (int tt = 0; tt < nt; ++tt) {
        if (tt + 1 < nt) stage(cur ^ 1, (tt + 1) << 5);
        const ushort* Ab = &u.s.As[cur][0];
        const ushort* Bb = &u.s.Bs[cur][0];
        short8 af[2], bfr[4];
#pragma unroll
        for (int i = 0; i < 2; i++) {
            int rA = wm * 32 + i * 16 + l16;
            af[i] = *(const short8*)&Ab[rA * 32 + ((quad ^ swz(rA)) << 3)];
        }
#pragma unroll
        for (int j = 0; j < 4; j++) {
            int rB = wn * 64 + j * 16 + l16;
            bfr[j] = *(const short8*)&Bb[rB * 32 + ((quad ^ swz(rB)) << 3)];
        }
#pragma unroll
        for (int i = 0; i < 2; i++)
#pragma unroll
            for (int j = 0; j < 4; j++)
                acc[i][j] = __builtin_amdgcn_mfma_f32_16x16x32_bf16(af[i], bfr[j], acc[i][j], 0, 0, 0);
        if (tt + 1 < nt) { WAIT_BAR(); cur ^= 1; }
    }
    // per-row partial sums (this wave's 64 cols) -> LDS
#pragma unroll
    for (int i = 0; i < 2; i++) {
#pragma unroll
        for (int r = 0; r < 4; r++) {
            float s = 0.f, q = 0.f;
#pragma unroll
            for (int j = 0; j < 4; j++) { float v = acc[i][j][r]; s += v; q += v * v; }
#pragma unroll
            for (int o = 8; o >= 1; o >>= 1) {
                s += __shfl_xor(s, o, 64);
                q += __shfl_xor(q, o, 64);
            }
            if (l16 == 0) {
                int row = wm * 32 + i * 16 + quad * 4 + r;
                psum[wn][row] = s; psq[wn][row] = q;
            }
        }
    }
    __syncthreads();
    if (t < 64) {
        float s = psum[0][t] + psum[1][t] + psum[2][t] + psum[3][t];
        float q = psq[0][t] + psq[1][t] + psq[2][t] + psq[3][t];
        float mean = s * (1.0f / 256.0f);
        float var = q * (1.0f / 256.0f) - mean * mean;
        psum[0][t] = mean;
        psq[0][t] = rsqrtf(var + 1e-5f);
    }
    __syncthreads();
    int mvE = minfo[2 + side];
    const float* rcIn = rcInB ? rcInB + so : nullptr;
    float* rcOut = rcOutB ? rcOutB + so : nullptr;
    const int* glp = glB + side * CAP;
    float* outSc = outScB ? outScB + (long)side * 9830400L : nullptr;
    ushort* outB = outBB ? outBB + so : nullptr;
    // ---- coalesced epilogue: 2 stripes of 32 tile-rows ----
#pragma unroll
    for (int i = 0; i < 2; i++) {
        // phase A: LN (no resid) into fp32 tile
#pragma unroll
        for (int r = 0; r < 4; r++) {
            int rloc = wm * 32 + i * 16 + quad * 4 + r;
            int tr = wm * 16 + quad * 4 + r;
            float mean = psum[0][rloc], rstd = psq[0][rloc];
#pragma unroll
            for (int j = 0; j < 4; j++) {
                int col = wn * 64 + j * 16 + l16;
                u.tile[tr][col] = (acc[i][j][r] - mean) * rstd * gs[col] + bs[col];
            }
        }
        __syncthreads();
        // phase B: linear coalesced residual-add + stores
#pragma unroll
        for (int e = 0; e < 4; e++) {
            int idx = e * 512 + t;          // 0..2047
            int tr = idx >> 6;              // tile row 0..31
            int c4 = (idx & 63) << 2;       // col 0..252 step 4
            long arow = m0 + (long)((tr >> 4) * 32 + i * 16 + (tr & 15));
            float4 v = *(float4*)&u.tile[tr][c4];
            if (rcIn) {
                float4 rv = *(const float4*)&rcIn[arow * 256 + c4];
                v.x += rv.x; v.y += rv.y; v.z += rv.z; v.w += rv.w;
            }
            if (rcOut) *(float4*)&rcOut[arow * 256 + c4] = v;
            if (outSc && arow < mvE)
                *(float4*)&outSc[(long)glp[arow] * 256 + c4] = v;
            if (outB) {
                ushort4 uo; uo.x = f2b(v.x); uo.y = f2b(v.y);
                uo.z = f2b(v.z); uo.w = f2b(v.w);
                *(ushort4*)&outB[arow * 256 + c4] = uo;
            }
        }
        if (i == 0) __syncthreads();
    }
}

// ---------------- per-class KV / Ksum reduction (compact, bf16 inputs) -------
// Per-chunk private slots (plain stores, no memset/atomics).
__global__ __launch_bounds__(256) void lft_kv_kernel(
    const ushort* __restrict__ kcB, const ushort* __restrict__ vcB,
    const int* __restrict__ cmetaB,
    float* kvbB, float* ksbB, int sideSrc0)
{
    int side = sideSrc0 + (blockIdx.z >> 6);
    int zz = blockIdx.z & 63;
    int chunk = blockIdx.x, c = blockIdx.y;
    int b = zz >> 3, h = zz & 7;
    const int* cmeta = cmetaB + side * 128;
    int cstart = cmeta[(b * 8 + c) * 2], n = cmeta[(b * 8 + c) * 2 + 1];
    int per = (n + KV_NCH - 1) / KV_NCH;
    int s0 = chunk * per;
    int s1 = min(s0 + per, n);
    const ushort* phik = kcB + (long)side * CAP * 256;
    const ushort* vmat = vcB + (long)side * CAP * 256;
    int slot = side * KV_NCH + chunk;
    float* kv = kvbB + (long)slot * 524288;
    float* ksum = ksbB + (long)slot * 16384;
    int t = threadIdx.x;
    __shared__ float kb[8][32];
    __shared__ float vb[8][32];
    int od = t >> 3, oe = (t & 7) << 2;
    int lt = t >> 5, ld = t & 31;
    float a0 = 0.f, a1 = 0.f, a2 = 0.f, a3 = 0.f, ak = 0.f;
    for (int s = s0; s < s1; s += 8) {
        float kval = 0.f, vval = 0.f;
        if (s + lt < s1) {
            long bse = (long)(cstart + s + lt) * 256 + h * 32 + ld;
            kval = b2f(phik[bse]);
            vval = b2f(vmat[bse]);
        }
        __syncthreads();
        kb[lt][ld] = kval;
        vb[lt][ld] = vval;
        __syncthreads();
#pragma unroll
        for (int j = 0; j < 8; j++) {
            float kd = kb[j][od];
            float4 vv = *(const float4*)&vb[j][oe];
            a0 += kd * vv.x; a1 += kd * vv.y; a2 += kd * vv.z; a3 += kd * vv.w;
            ak += kd;
        }
    }
    float* dst = kv + (((long)(b * NPROTO + c) * 8 + h) << 10) + od * 32 + oe;
    dst[0] = a0; dst[1] = a1; dst[2] = a2; dst[3] = a3;
    if ((t & 7) == 0)
        ksum[(((long)(b * NPROTO + c) * 8 + h) << 5) + od] = ak;
}

// ---------------- kv chunk-slot pre-sum -> bf16 B-layout kvt -----------------
// kvt[(side*64+bc)*8+h][e*32+d]: e<32 = sum_ch kv[d][e]; e=32 ksum; 33..47 = 0.
// 1.5MB/side -> L2-resident for the msg kernel (kills its ~97MB HBM re-fetch).
__global__ __launch_bounds__(256) void lft_kvconv_kernel(
    const float* __restrict__ kvbB, const float* __restrict__ ksbB,
    ushort* __restrict__ kvtB, int sideSrc0)
{
    int side = sideSrc0 + blockIdx.z;
    int bc = blockIdx.x;          // 0..63
    int t = threadIdx.x;
    int h = t >> 5, d = t & 31;
    long kvoff = ((long)bc * 8 + h) * 1024;
    long ksoff = ((long)bc * 8 + h) * 32;
    ushort* dst = kvtB + ((long)(side * 64 + bc) * 8 + h) * 1536;
#pragma unroll
    for (int e = 0; e < 32; e++) {
        float v = 0.f;
#pragma unroll
        for (int ch = 0; ch < KV_NCH; ch++)
            v += kvbB[(long)(side * KV_NCH + ch) * 524288 + kvoff + d * 32 + e];
        dst[e * 32 + d] = f2b(v);
    }
    float vs = 0.f;
#pragma unroll
    for (int ch = 0; ch < KV_NCH; ch++)
        vs += ksbB[(long)(side * KV_NCH + ch) * 16384 + ksoff + d];
    dst[32 * 32 + d] = f2b(vs);
#pragma unroll
    for (int e = 33; e < 48; e++) dst[e * 32 + d] = 0;
}

// ---------------- msg via MFMA; LDS row-tiled q + bf16 kvt fragments ---------
// qt/ot stride 264 (row shift 4 words -> 2-way = free).
__global__ __launch_bounds__(256) void lft_msg_kernel(
    const ushort* __restrict__ qcB, const ushort* __restrict__ kvtB,
    const int* __restrict__ cmetaB,
    ushort* __restrict__ msgcB, int sideX0, int sideKV0)
{
    int add = blockIdx.z >> 3, b = blockIdx.z & 7;
    int sideX = sideX0 + add, sideKV = sideKV0 + add;
    int chunk = blockIdx.x, c = blockIdx.y;
    const int* cmeta = cmetaB + sideX * 128;
    int cstart = cmeta[(b * 8 + c) * 2], n = cmeta[(b * 8 + c) * 2 + 1];
    int per = (n + MSG_NCH - 1) / MSG_NCH;
    int s0 = chunk * per, s1 = min(s0 + per, n);
    if (s0 >= s1) return;
    const ushort* pq = qcB + (long)sideX * CAP * 256;
    ushort* msg = msgcB + (long)sideX * CAP * 256;
    __shared__ ushort qt[16][264];
    __shared__ ushort ot[16][264];
    int t = threadIdx.x;
    int wave = t >> 6, lane = t & 63;
    int l16 = lane & 15, quad = lane >> 4;
    int bc = b * 8 + c;
    short8 bfr[2][3];
#pragma unroll
    for (int hh = 0; hh < 2; hh++) {
        int h = wave * 2 + hh;
        const ushort* kb = kvtB + ((long)(sideKV * 64 + bc) * 8 + h) * 1536;
#pragma unroll
        for (int nt = 0; nt < 3; nt++)
            bfr[hh][nt] = *(const short8*)&kb[(nt * 16 + l16) * 32 + quad * 8];
    }
    int srow = t >> 5;              // staging row 0..7 (x2 iters -> 0..15)
    int scol = (t & 31) << 3;       // 8-elem group 0..248
    for (int s = s0; s < s1; s += 16) {
        // stage 16 q rows (clamped) coalesced
#pragma unroll
        for (int it = 0; it < 2; it++) {
            int sr = it * 8 + srow;
            int rr = min(s + sr, s1 - 1);
            *(short8*)&qt[sr][scol] = *(const short8*)&pq[(long)(cstart + rr) * 256 + scol];
        }
        __syncthreads();
#pragma unroll
        for (int hh = 0; hh < 2; hh++) {
            int h = wave * 2 + hh;
            short8 a = *(const short8*)&qt[l16][h * 32 + quad * 8];
            floatx4 n0 = {}, n1 = {}, dd = {};
            n0 = __builtin_amdgcn_mfma_f32_16x16x32_bf16(a, bfr[hh][0], n0, 0, 0, 0);
            n1 = __builtin_amdgcn_mfma_f32_16x16x32_bf16(a, bfr[hh][1], n1, 0, 0, 0);
            dd = __builtin_amdgcn_mfma_f32_16x16x32_bf16(a, bfr[hh][2], dd, 0, 0, 0);
#pragma unroll
            for (int r = 0; r < 4; r++) {
                float den = __shfl(dd[r], lane & 48, 64);
                float inv = 1.f / (den + 1e-6f);
                ot[quad * 4 + r][h * 32 + l16]      = f2b(n0[r] * inv);
                ot[quad * 4 + r][h * 32 + 16 + l16] = f2b(n1[r] * inv);
            }
        }
        __syncthreads();
        // coalesced write-out with tail guard
#pragma unroll
        for (int it = 0; it < 2; it++) {
            int sr = it * 8 + srow;
            if (s + sr < s1)
                *(short8*)&msg[(long)(cstart + s + sr) * 256 + scol] =
                    *(const short8*)&ot[sr][scol];
        }
        __syncthreads();
    }
}

extern "C" void kernel_launch(void* const* d_in, const int* in_sizes, int n_in,
                              void* d_out, int out_size, void* d_ws, size_t ws_size,
                              hipStream_t stream)
{
    (void)in_sizes; (void)n_in; (void)out_size; (void)ws_size;
    const float* feat0 = (const float*)d_in[0];
    const float* feat1 = (const float*)d_in[1];
    const int*   mask0 = (const int*)d_in[2];
    const int*   mask1 = (const int*)d_in[3];
    const float* f0wo  = (const float*)d_in[4];
    const float* f1wo  = (const float*)d_in[5];
    const float* proto = (const float*)d_in[6];
    const float* Wq = (const float*)d_in[7];
    const float* Wk = (const float*)d_in[8];
    const float* Wv = (const float*)d_in[9];
    const float* Wm = (const float*)d_in[10];
    const float* W1 = (const float*)d_in[11];
    const float* W2 = (const float*)d_in[12];
    const float* g1 = (const float*)d_in[13];
    const float* b1 = (const float*)d_in[14];
    const float* g2 = (const float*)d_in[15];
    const float* b2 = (const float*)d_in[16];
    float* out = (float*)d_out;
    float* ws = (float*)d_ws;

    // ---- workspace layout (side-strided compact buffers, CAP rows/side) ----
    const long FSZ = 9830400L;
    float* rc = ws;                               // 2*CAP*256 f
    ushort* kc = (ushort*)(rc + 2 * CAP * 256);   // 2*CAP*256 us  bf16
    ushort* vc = kc + 2 * CAP * 256;              // 2*CAP*256 us  bf16
    ushort* hid = vc + 2 * CAP * 256;             // 2*CAP*512 us
    ushort* xc   = hid + 2 * CAP * 512;
    ushort* msgc = xc + 2 * CAP * 256;
    ushort* qc   = msgc + 2 * CAP * 256;
    ushort* wb   = qc + 2 * CAP * 256;
    ushort* wb1  = wb + 16 * 65536;
    ushort* wb2  = wb1 + 4 * 262144;
    ushort* kvt  = wb2 + 4 * 131072;              // 2*786432 us (3MB)
    float* ksb = (float*)(kvt + 2 * 786432);      // 2*KV_NCH*16384 f
    int* cls0 = (int*)(ksb + 2 * KV_NCH * 16384);
    int* cls1 = cls0 + 38400;
    int* gl   = cls1 + 38400;                     // 2*CAP ints
    int* meta = gl + 2 * CAP;
    int* minfo = meta + 256;
    int* cmeta = minfo + 20;
    // kvb aliases hid (dead between kv_kernel and w1-GEMM)
    float* kvb = (float*)hid;

    lft_wconv_kernel<<<dim3(8, 8, 16), 256, 0, stream>>>(Wq, Wk, Wv, Wm, 256, 256, 4, wb);
    lft_wconv_kernel<<<dim3(16, 16, 4), 256, 0, stream>>>(W1, W1, W1, W1, 512, 512, 1, wb1);
    lft_wconv_kernel<<<dim3(16, 8, 4), 256, 0, stream>>>(W2, W2, W2, W2, 512, 256, 1, wb2);
    hipMemcpyAsync(out + 20352000L, proto, 2048 * 4, hipMemcpyDeviceToDevice, stream);
    lft_class_kernel<<<600, 256, 0, stream>>>(f0wo, f1wo, mask0, mask1, proto,
                                              out, cls0, cls1);
    lft_invcopy_kernel<<<1200, 256, 0, stream>>>(feat0, feat1, cls0, cls1, out);
    lft_count_kernel<<<16, 256, 0, stream>>>(cls0, cls1, meta);
    lft_scan_kernel<<<1, 256, 0, stream>>>(meta, minfo, cmeta);
    lft_place_kernel<<<16, 256, 0, stream>>>(cls0, cls1, cmeta, gl);
    lft_gcast_kernel<<<1200, 256, 0, stream>>>(feat0, feat1, gl, minfo, xc, rc);

    dim3 blk(256);
    dim3 blkL(512);
    for (int li = 0; li < 4; li++) {
        const ushort* wq = wb + (size_t)(li * 4 + 0) * 65536;   // [wq|wk|wv|wm]
        const ushort* wk = wb + (size_t)(li * 4 + 1) * 65536;
        const ushort* wm = wb + (size_t)(li * 4 + 3) * 65536;
        const ushort* w1 = wb1 + (size_t)li * 262144;
        const ushort* w2 = wb2 + (size_t)li * 131072;
        const float* g1p = g1 + li * 256; const float* b1p = b1 + li * 256;
        const float* g2p = g2 + li * 256; const float* b2p = b2 + li * 256;
        bool last = (li == 3);

        if ((li & 1) == 0) {
            // ---- self-self, both sides combined (z=2) ----
            lft_mfma_gemm<<<dim3(6, 192, 2), blk, 0, stream>>>(
                xc, xc, 256, wq, (float*)kc, qc, (float*)vc, 768, 256, 3, minfo, 0);
            lft_kv_kernel<<<dim3(KV_NCH, 8, 128), blk, 0, stream>>>(kc, vc, cmeta, kvb, ksb, 0);
            lft_kvconv_kernel<<<dim3(64, 1, 2), blk, 0, stream>>>(kvb, ksb, kvt, 0);
            lft_msg_kernel<<<dim3(MSG_NCH, 8, 16), blk, 0, stream>>>(qc, kvt, cmeta, msgc, 0, 0);
            lft_gemm_ln<<<dim3(384, 1, 2), blkL, 0, stream>>>(
                msgc, msgc, 256, wm, 256, g1p, b1p,
                nullptr, nullptr, gl, minfo, nullptr, msgc, 0);
            lft_mfma_gemm<<<dim3(4, 192, 2), blk, 0, stream>>>(
                xc, msgc, 256, w1, nullptr, hid, nullptr, 512, 512, 2, minfo, 0);
            lft_gemm_ln<<<dim3(384, 1, 2), blkL, 0, stream>>>(
                hid, hid, 512, w2, 512, g2p, b2p,
                rc, rc, gl, minfo, nullptr, xc, 0);
        } else {
            // ---- cross-self: q for both sides from OLD features ----
            lft_mfma_gemm<<<dim3(2, 192, 2), blk, 0, stream>>>(
                xc, xc, 256, wq, nullptr, qc, nullptr, 256, 256, 1, minfo, 0);
            // k|v from side1 (old) -> kc/vc side1
            lft_mfma_gemm<<<dim3(4, 192, 1), blk, 0, stream>>>(
                xc, xc, 256, wk, (float*)kc, nullptr, (float*)vc, 512, 256, 4, minfo, 1);
            lft_kv_kernel<<<dim3(KV_NCH, 8, 64), blk, 0, stream>>>(kc, vc, cmeta, kvb, ksb, 1);
            lft_kvconv_kernel<<<dim3(64, 1, 1), blk, 0, stream>>>(kvb, ksb, kvt, 1);
            lft_msg_kernel<<<dim3(MSG_NCH, 8, 8), blk, 0, stream>>>(qc, kvt, cmeta, msgc, 0, 1);
            lft_gemm_ln<<<dim3(384, 1, 1), blkL, 0, stream>>>(
                msgc, msgc, 256, wm, 256, g1p, b1p,
                nullptr, nullptr, gl, minfo, nullptr, msgc, 0);
            lft_mfma_gemm<<<dim3(4, 192, 1), blk, 0, stream>>>(
                xc, msgc, 256, w1, nullptr, hid, nullptr, 512, 512, 2, minfo, 0);
            lft_gemm_ln<<<dim3(384, 1, 1), blkL, 0, stream>>>(
                hid, hid, 512, w2, 512, g2p, b2p,
                rc, last ? nullptr : rc, gl, minfo, last ? out : nullptr, xc, 0);
            // ---- side1 attends UPDATED side0 ----
            lft_mfma_gemm<<<dim3(4, 192, 1), blk, 0, stream>>>(
                xc, xc, 256, wk, (float*)kc, nullptr, (float*)vc, 512, 256, 4, minfo, 0);
            lft_kv_kernel<<<dim3(KV_NCH, 8, 64), blk, 0, stream>>>(kc, vc, cmeta, kvb, ksb, 0);
            lft_kvconv_kernel<<<dim3(64, 1, 1), blk, 0, stream>>>(kvb, ksb, kvt, 0);
            lft_msg_kernel<<<dim3(MSG_NCH, 8, 8), blk, 0, stream>>>(qc, kvt, cmeta, msgc, 1, 0);
            lft_gemm_ln<<<dim3(384, 1, 1), blkL, 0, stream>>>(
                msgc, msgc, 256, wm, 256, g1p, b1p,
                nullptr, nullptr, gl, minfo, nullptr, msgc, 1);
            lft_mfma_gemm<<<dim3(4, 192, 1), blk, 0, stream>>>(
                xc, msgc, 256, w1, nullptr, hid, nullptr, 512, 512, 2, minfo, 1);
            lft_gemm_ln<<<dim3(384, 1, 1), blkL, 0, stream>>>(
                hid, hid, 512, w2, 512, g2p, b2p,
                rc, last ? nullptr : rc, gl, minfo, last ? out : nullptr,
                last ? nullptr : xc, 1);
        }
    }
}